// Round 7
// baseline (267.080 us; speedup 1.0000x reference)
//
#include <hip/hip_runtime.h>
#include <hip/hip_bf16.h>
#include <math.h>

#define B_   2
#define T_   2048
#define C_   1024
#define H_   16
#define D_   64
#define NCH  32
#define RD   32
#define TOPB 8

typedef __attribute__((ext_vector_type(8))) short bf16x8;
typedef __attribute__((ext_vector_type(4))) float f32x4;

static __device__ __forceinline__ unsigned short f2b(float f) {
    return __bfloat16_as_ushort(__float2bfloat16(f));
}

// ---------------------------------------------------------------------------
// cast x (f32) -> bf16, 8 elements per thread
// ---------------------------------------------------------------------------
__global__ __launch_bounds__(256) void cast_bf16_kernel(
    const float* __restrict__ in, unsigned short* __restrict__ out, int n8)
{
    const int i = blockIdx.x * blockDim.x + threadIdx.x;
    if (i >= n8) return;
    float4 a = ((const float4*)in)[i * 2];
    float4 b = ((const float4*)in)[i * 2 + 1];
    bf16x8 o;
    o[0] = (short)f2b(a.x); o[1] = (short)f2b(a.y);
    o[2] = (short)f2b(a.z); o[3] = (short)f2b(a.w);
    o[4] = (short)f2b(b.x); o[5] = (short)f2b(b.y);
    o[6] = (short)f2b(b.z); o[7] = (short)f2b(b.w);
    *(bf16x8*)&out[i * 8] = o;
}

// ---------------------------------------------------------------------------
// W [K][N] f32 -> Wt [N][K] bf16, 64x64 tiles via LDS
// ---------------------------------------------------------------------------
__global__ __launch_bounds__(256) void transpose_cast_kernel(
    const float* __restrict__ W, unsigned short* __restrict__ Wt, int K, int N)
{
    __shared__ float t[64][65];
    const int tid = threadIdx.x;
    const int n0 = blockIdx.x * 64, k0 = blockIdx.y * 64;
#pragma unroll
    for (int i = 0; i < 4; i++) {
        const int f = tid + i * 256;
        const int r = f >> 4, c4 = (f & 15) * 4;
        float4 v = *(const float4*)&W[(size_t)(k0 + r) * N + n0 + c4];
        t[r][c4 + 0] = v.x; t[r][c4 + 1] = v.y;
        t[r][c4 + 2] = v.z; t[r][c4 + 3] = v.w;
    }
    __syncthreads();
#pragma unroll
    for (int i = 0; i < 2; i++) {
        const int s = tid + i * 256;
        const int rn = s >> 3, ck8 = (s & 7) * 8;
        bf16x8 o;
#pragma unroll
        for (int j = 0; j < 8; j++) o[j] = (short)f2b(t[ck8 + j][rn]);
        *(bf16x8*)&Wt[(size_t)(n0 + rn) * K + k0 + ck8] = o;
    }
}

// ---------------------------------------------------------------------------
// Wq_rt [1024][32] f32 -> WtQ [32][1024] f32 (tiny, L2-absorbed)
// ---------------------------------------------------------------------------
__global__ __launch_bounds__(256) void transpose_f32_kernel(
    const float* __restrict__ W, float* __restrict__ Wt)
{
    const int idx = blockIdx.x * 256 + threadIdx.x;   // 0..32767
    const int n = idx >> 10, k = idx & 1023;
    Wt[n * 1024 + k] = W[k * 32 + n];
}

// ---------------------------------------------------------------------------
// bf16 MFMA GEMM (m97 structure): C = A[M,K] @ Bt[N,K]^T + bias
// ---------------------------------------------------------------------------
template <int MODE>
__global__ __launch_bounds__(256) void gemm_mfma(
    const unsigned short* __restrict__ A, const unsigned short* __restrict__ Bt,
    const float* __restrict__ bias, float* __restrict__ out,
    unsigned short* __restrict__ qp, unsigned short* __restrict__ kp,
    unsigned short* __restrict__ vp, int M, int N, int K)
{
    __shared__ unsigned short As[128 * 32];
    __shared__ unsigned short Bs[128 * 32];

    const int tid  = threadIdx.x;
    const int lane = tid & 63;
    const int wave = tid >> 6;
    const int lr = lane & 15, lg = lane >> 4;
    const int wm = wave >> 1, wn = wave & 1;
    const int n0 = blockIdx.x * 128, m0 = blockIdx.y * 128;

    const int srow = tid >> 2;
    const int scol = (tid & 3) * 8;
    const unsigned short* ga = A  + (size_t)(m0 + srow) * K + scol;
    const unsigned short* gb = Bt + (size_t)(n0 + srow) * K + scol;
    const int ldst = (tid & 0xC0) * 8;

    f32x4 acc[4][4];
#pragma unroll
    for (int i = 0; i < 4; i++)
#pragma unroll
        for (int j = 0; j < 4; j++) acc[i][j] = (f32x4){0.f, 0.f, 0.f, 0.f};

    for (int k0 = 0; k0 < K; k0 += 32) {
        __syncthreads();
#pragma unroll
        for (int i = 0; i < 2; i++) {
            __builtin_amdgcn_global_load_lds(
                (const __attribute__((address_space(1))) int*)(ga + k0 + (size_t)i * 64 * K),
                (__attribute__((address_space(3))) int*)&As[i * 2048 + ldst], 16, 0, 0);
            __builtin_amdgcn_global_load_lds(
                (const __attribute__((address_space(1))) int*)(gb + k0 + (size_t)i * 64 * K),
                (__attribute__((address_space(3))) int*)&Bs[i * 2048 + ldst], 16, 0, 0);
        }
        __syncthreads();

        bf16x8 af[4], bfr[4];
#pragma unroll
        for (int mi = 0; mi < 4; mi++)
            af[mi] = *(const bf16x8*)&As[(wm * 64 + mi * 16 + lr) * 32 + lg * 8];
#pragma unroll
        for (int ni = 0; ni < 4; ni++)
            bfr[ni] = *(const bf16x8*)&Bs[(wn * 64 + ni * 16 + lr) * 32 + lg * 8];
#pragma unroll
        for (int mi = 0; mi < 4; mi++)
#pragma unroll
            for (int ni = 0; ni < 4; ni++)
                acc[mi][ni] = __builtin_amdgcn_mfma_f32_16x16x32_bf16(
                    af[mi], bfr[ni], acc[mi][ni], 0, 0, 0);
    }

#pragma unroll
    for (int ni = 0; ni < 4; ni++) {
        const int col = n0 + wn * 64 + ni * 16 + lr;
        const float bv = bias[col];
        if (MODE == 0) {
#pragma unroll
            for (int mi = 0; mi < 4; mi++) {
#pragma unroll
                for (int r = 0; r < 4; r++) {
                    const int row = m0 + wm * 64 + mi * 16 + lg * 4 + r;
                    out[(size_t)row * N + col] = acc[mi][ni][r] + bv;
                }
            }
        } else {
            const int which = col >> 10;
            const int c  = col & 1023;
            const int hh = c >> 6;
            const int dd = c & 63;
            unsigned short* dst = (which == 0) ? qp : (which == 1) ? kp : vp;
#pragma unroll
            for (int mi = 0; mi < 4; mi++) {
#pragma unroll
                for (int r = 0; r < 4; r++) {
                    const int row = m0 + wm * 64 + mi * 16 + lg * 4 + r;
                    const int bb = row >> 11, tt = row & 2047;
                    dst[(((size_t)bb * H_ + hh) * T_ + tt) * D_ + dd] =
                        f2b(acc[mi][ni][r] + bv);
                }
            }
        }
    }
}

// ---------------------------------------------------------------------------
// chunk means: grid (64, 4) — 256 blocks, one column per thread
// ---------------------------------------------------------------------------
__global__ void chunk_mean_kernel(const float* __restrict__ x, float* __restrict__ cm)
{
    const int bc = blockIdx.x;
    const int b = bc >> 5, n = bc & 31;
    const int c = blockIdx.y * 256 + threadIdx.x;
    const float* xp = x + ((size_t)b * T_ + n * 64) * C_;
    float s = 0.f;
    for (int i = 0; i < 64; i++) s += xp[(size_t)i * C_ + c];
    cm[(size_t)bc * C_ + c] = s * (1.0f / 64.0f);
}

// ---------------------------------------------------------------------------
// rowgemm32 (W in [K][32] layout) — used for the 64-row routing embeds
// ---------------------------------------------------------------------------
__global__ void rowgemm32(const float* __restrict__ A, const float* __restrict__ W,
                          const float* __restrict__ bias, float* __restrict__ dst,
                          int M, int normalize)
{
    const int row  = blockIdx.x * 8 + (threadIdx.x >> 5);
    const int lane = threadIdx.x & 31;
    if (row >= M) return;
    const float* a = A + (size_t)row * C_;
    float acc = 0.f;
    for (int k = 0; k < C_; k += 4) {
        float4 a4 = *(const float4*)&a[k];
        acc += a4.x * W[(k + 0) * RD + lane];
        acc += a4.y * W[(k + 1) * RD + lane];
        acc += a4.z * W[(k + 2) * RD + lane];
        acc += a4.w * W[(k + 3) * RD + lane];
    }
    acc += bias[lane];
    if (normalize) {
        float ss = acc * acc;
#pragma unroll
        for (int off = 16; off >= 1; off >>= 1) ss += __shfl_xor(ss, off, 32);
        acc = acc / fmaxf(sqrtf(ss), 1e-12f);
    }
    dst[(size_t)row * RD + lane] = acc;
}

// rowgemm for q_rt: W^T [32][1024] f32 -> float4 loads; same FP add order
__global__ void rowgemm_qrt(const float* __restrict__ A, const float* __restrict__ Wt,
                            const float* __restrict__ bias, float* __restrict__ dst,
                            int M)
{
    const int row  = blockIdx.x * 8 + (threadIdx.x >> 5);
    const int lane = threadIdx.x & 31;
    if (row >= M) return;
    const float* a = A + (size_t)row * C_;
    const float* w = Wt + (size_t)lane * C_;
    float acc = 0.f;
    for (int k = 0; k < C_; k += 4) {
        float4 a4 = *(const float4*)&a[k];
        float4 w4 = *(const float4*)&w[k];
        acc += a4.x * w4.x;
        acc += a4.y * w4.y;
        acc += a4.z * w4.z;
        acc += a4.w * w4.w;
    }
    acc += bias[lane];
    float ss = acc * acc;
#pragma unroll
    for (int off = 16; off >= 1; off >>= 1) ss += __shfl_xor(ss, off, 32);
    acc = acc / fmaxf(sqrtf(ss), 1e-12f);
    dst[(size_t)row * RD + lane] = acc;
}

__global__ void l2norm_rows(const float* __restrict__ src, float* __restrict__ dst, int M)
{
    const int row  = blockIdx.x * 8 + (threadIdx.x >> 5);
    const int lane = threadIdx.x & 31;
    if (row >= M) return;
    float v = src[(size_t)row * RD + lane];
    float ss = v * v;
#pragma unroll
    for (int off = 16; off >= 1; off >>= 1) ss += __shfl_xor(ss, off, 32);
    dst[(size_t)row * RD + lane] = v / fmaxf(sqrtf(ss), 1e-12f);
}

// ---------------------------------------------------------------------------
// routing scores + top-8 (64 blocks x 64 threads)
// ---------------------------------------------------------------------------
__global__ void scores_topk(const float* __restrict__ qrt, const float* __restrict__ ren,
                            float* __restrict__ sc_out, float* __restrict__ idx_out)
{
    const int row = blockIdx.x * 64 + threadIdx.x;
    if (row >= B_ * T_) return;
    const int b = row / T_;
    float q[RD];
#pragma unroll
    for (int i = 0; i < RD; i++) q[i] = qrt[(size_t)row * RD + i];
    const float* rb = ren + (size_t)b * NCH * RD;
    float s[NCH];
#pragma unroll 4
    for (int n = 0; n < NCH; n++) {
        float acc = 0.f;
#pragma unroll
        for (int i = 0; i < RD; i++) acc += q[i] * rb[n * RD + i];
        s[n] = acc;
        sc_out[(size_t)row * NCH + n] = acc;
    }
    unsigned mask = 0;
    for (int t = 0; t < TOPB; t++) {
        float best = -INFINITY;
        int bi = 0;
#pragma unroll
        for (int n = 0; n < NCH; n++) {
            const bool ok = !((mask >> n) & 1u) && (s[n] > best);
            if (ok) { best = s[n]; bi = n; }
        }
        mask |= (1u << bi);
        idx_out[(size_t)row * TOPB + t] = (float)bi;
    }
}

// ---------------------------------------------------------------------------
// MFMA bf16 flash attention, v5: swapped QK^T + fully in-register softmax.
//  - S^T = mfma(K_frag, Q_frag): lane holds 16 scores for ONE q-row (lr)
//    -> row reduce = 2 shuffles; m/l are scalars
//  - PV A-fragment = lane's own p[] registers via permuted MFMA k-slots
//    sigma(lg,j)=lg*4+(j&3)+16*(j>>2); V^T staged in matching slot order
//    (Ps LDS deleted entirely; V ds_read_b128 unchanged)
//  - K/V double-buffered, one barrier/tile; reg-staged prefetch 2 tiles deep
//  - defer-max (log2 THR=8), exp2 softmax, s_setprio around MFMA clusters
// ---------------------------------------------------------------------------
#define LSTR 68
#define SCALE2 0.18033688f   /* 0.125 * 1.44269504 */

__global__ __launch_bounds__(256) void attn_mfma(
    const unsigned short* __restrict__ qg, const unsigned short* __restrict__ kg,
    const unsigned short* __restrict__ vg, unsigned short* __restrict__ y)
{
    const int bid = blockIdx.x;
    const int xcd = bid & 7;
    const int j   = bid >> 3;                 // 0..127
    const int h   = xcd + 8 * (j & 1);
    const int b   = (j >> 1) & 1;
    const int qt  = 31 - (j >> 2);            // long blocks dispatch first

    const int tid  = threadIdx.x;
    const int wave = tid >> 6;
    const int lane = tid & 63;
    const int lg = lane >> 4;
    const int lr = lane & 15;

    __shared__ short Ks[2][64][LSTR];
    __shared__ short Vt[2][64][LSTR];     // Vt[buf][d][slot] (permuted kv order)

    const size_t base = ((size_t)(b * H_ + h) * T_) * D_;

    // Q fragments, hoisted
    bf16x8 qf0, qf1;
    {
        const short* qp = (const short*)qg + base + (size_t)(qt * 64 + wave * 16 + lr) * D_;
        qf0 = *(const bf16x8*)&qp[lg * 8];
        qf1 = *(const bf16x8*)&qp[32 + lg * 8];
    }

    // staging indices
    const int srr = tid >> 2;            // K row 0..63
    const int sc0 = (tid & 3) * 16;      // K col base
    const int vrp = tid & 31;            // V row-pair 0..31
    const int vcg = tid >> 5;            // V col-group 0..7
    // permuted slot for kv0 = 2*vrp (kv1 = kv0+1 lands at slot+1)
    const int kv0   = 2 * vrp;
    const int vslot = ((kv0 >> 5) << 5) + (((kv0 >> 2) & 3) << 3) +
                      (((kv0 >> 4) & 1) << 2) + (kv0 & 3);

    bf16x8 kreg0, kreg1, vreg0, vreg1;

    float m_run = -INFINITY, l_run = 0.f;
    f32x4 oacc[4];
#pragma unroll
    for (int r = 0; r < 4; r++) oacc[r] = (f32x4){0.f, 0.f, 0.f, 0.f};
    const int qrow_g = qt * 64 + wave * 16 + lr;

    // prologue: load tile 0, stage to buf0; prefetch tile 1
    {
        const short* kp = (const short*)kg + base + (size_t)srr * D_ + sc0;
        kreg0 = *(const bf16x8*)kp;
        kreg1 = *(const bf16x8*)(kp + 8);
        const short* vp = (const short*)vg + base + (size_t)kv0 * D_ + vcg * 8;
        vreg0 = *(const bf16x8*)vp;
        vreg1 = *(const bf16x8*)(vp + D_);
    }
    {
        *(bf16x8*)&Ks[0][srr][sc0]     = kreg0;
        *(bf16x8*)&Ks[0][srr][sc0 + 8] = kreg1;
#pragma unroll
        for (int jj = 0; jj < 8; jj++) {
            const unsigned int dw = ((unsigned int)(unsigned short)vreg0[jj]) |
                                    (((unsigned int)(unsigned short)vreg1[jj]) << 16);
            *(unsigned int*)&Vt[0][vcg * 8 + jj][vslot] = dw;
        }
    }
    if (qt >= 1) {
        const short* kp = (const short*)kg + base + (size_t)(64 + srr) * D_ + sc0;
        kreg0 = *(const bf16x8*)kp;
        kreg1 = *(const bf16x8*)(kp + 8);
        const short* vp = (const short*)vg + base + (size_t)(64 + kv0) * D_ + vcg * 8;
        vreg0 = *(const bf16x8*)vp;
        vreg1 = *(const bf16x8*)(vp + D_);
    }
    __syncthreads();

    for (int kt = 0; kt <= qt; ++kt) {
        const int cur = kt & 1;

        if (kt < qt) {
            *(bf16x8*)&Ks[cur ^ 1][srr][sc0]     = kreg0;
            *(bf16x8*)&Ks[cur ^ 1][srr][sc0 + 8] = kreg1;
#pragma unroll
            for (int jj = 0; jj < 8; jj++) {
                const unsigned int dw = ((unsigned int)(unsigned short)vreg0[jj]) |
                                        (((unsigned int)(unsigned short)vreg1[jj]) << 16);
                *(unsigned int*)&Vt[cur ^ 1][vcg * 8 + jj][vslot] = dw;
            }
        }
        if (kt + 2 <= qt) {
            const short* kp = (const short*)kg + base + (size_t)((kt + 2) * 64 + srr) * D_ + sc0;
            kreg0 = *(const bf16x8*)kp;
            kreg1 = *(const bf16x8*)(kp + 8);
            const short* vp = (const short*)vg + base + (size_t)((kt + 2) * 64 + kv0) * D_ + vcg * 8;
            vreg0 = *(const bf16x8*)vp;
            vreg1 = *(const bf16x8*)(vp + D_);
        }

        // S^T = K @ Q^T : lane (lg,lr) gets s[cb][r] = S[kv=cb*16+lg*4+r][qrow=lr]
        f32x4 s[4];
        __builtin_amdgcn_s_setprio(1);
#pragma unroll
        for (int cb = 0; cb < 4; cb++) {
            bf16x8 kf0 = *(const bf16x8*)&Ks[cur][cb * 16 + lr][lg * 8];
            bf16x8 kf1 = *(const bf16x8*)&Ks[cur][cb * 16 + lr][32 + lg * 8];
            f32x4 acc = (f32x4){0.f, 0.f, 0.f, 0.f};
            acc = __builtin_amdgcn_mfma_f32_16x16x32_bf16(kf0, qf0, acc, 0, 0, 0);
            acc = __builtin_amdgcn_mfma_f32_16x16x32_bf16(kf1, qf1, acc, 0, 0, 0);
            s[cb] = acc;
        }
        __builtin_amdgcn_s_setprio(0);

        // scale (log2 domain) + causal mask on diagonal tile
        if (kt == qt) {
#pragma unroll
            for (int cb = 0; cb < 4; cb++) {
#pragma unroll
                for (int r = 0; r < 4; r++) {
                    float sv = s[cb][r] * SCALE2;
                    if (kt * 64 + cb * 16 + lg * 4 + r > qrow_g) sv = -INFINITY;
                    s[cb][r] = sv;
                }
            }
        } else {
#pragma unroll
            for (int cb = 0; cb < 4; cb++)
#pragma unroll
                for (int r = 0; r < 4; r++) s[cb][r] *= SCALE2;
        }

        // row max: per-lane over 16, then across the 4 lg copies
        float rm = -INFINITY;
#pragma unroll
        for (int cb = 0; cb < 4; cb++)
#pragma unroll
            for (int r = 0; r < 4; r++) rm = fmaxf(rm, s[cb][r]);
        rm = fmaxf(rm, __shfl_xor(rm, 16));
        rm = fmaxf(rm, __shfl_xor(rm, 32));

        // defer-max (THR=8 in log2 units)
        if (!__all(rm <= m_run + 8.0f)) {
            const float mnew = fmaxf(m_run, rm);
            const float fsc  = exp2f(m_run - mnew);
            m_run = mnew;
            l_run *= fsc;
            float fr[4];
#pragma unroll
            for (int r = 0; r < 4; r++) fr[r] = __shfl(fsc, lg * 4 + r);
#pragma unroll
            for (int db = 0; db < 4; db++)
#pragma unroll
                for (int r = 0; r < 4; r++) oacc[db][r] *= fr[r];
        }

        // P = exp2(S - m), fully in-register; row sum via 2 shuffles
        float p[4][4];
        float rs = 0.f;
#pragma unroll
        for (int cb = 0; cb < 4; cb++)
#pragma unroll
            for (int r = 0; r < 4; r++) {
                const float pv = exp2f(s[cb][r] - m_run);
                p[cb][r] = pv;
                rs += pv;
            }
        rs += __shfl_xor(rs, 16);
        rs += __shfl_xor(rs, 32);
        l_run += rs;

        // P fragments are lane-local under slot map sigma(lg,j)=lg*4+(j&3)+16*(j>>2)
        bf16x8 pf0, pf1;
#pragma unroll
        for (int r = 0; r < 4; r++) {
            pf0[r]     = (short)f2b(p[0][r]);
            pf0[4 + r] = (short)f2b(p[1][r]);
            pf1[r]     = (short)f2b(p[2][r]);
            pf1[4 + r] = (short)f2b(p[3][r]);
        }

        // PV (V read in matching slot order — layout identical to before)
        __builtin_amdgcn_s_setprio(1);
#pragma unroll
        for (int db = 0; db < 4; db++) {
            bf16x8 vf0 = *(const bf16x8*)&Vt[cur][db * 16 + lr][lg * 8];
            bf16x8 vf1 = *(const bf16x8*)&Vt[cur][db * 16 + lr][32 + lg * 8];
            oacc[db] = __builtin_amdgcn_mfma_f32_16x16x32_bf16(pf0, vf0, oacc[db], 0, 0, 0);
            oacc[db] = __builtin_amdgcn_mfma_f32_16x16x32_bf16(pf1, vf1, oacc[db], 0, 0, 0);
        }
        __builtin_amdgcn_s_setprio(0);

        __syncthreads();
    }

    // epilogue: O / l -> bf16 y[B,T,C]
#pragma unroll
    for (int r = 0; r < 4; r++) {
        const float lrow = __shfl(l_run, lg * 4 + r);
        const float inv = 1.0f / lrow;
        const int trow = qt * 64 + wave * 16 + lg * 4 + r;
        unsigned short* yp = y + (size_t)(b * T_ + trow) * C_ + h * D_;
#pragma unroll
        for (int db = 0; db < 4; db++)
            yp[db * 16 + lr] = f2b(oacc[db][r] * inv);
    }
}

// ---------------------------------------------------------------------------
extern "C" void kernel_launch(void* const* d_in, const int* in_sizes, int n_in,
                              void* d_out, int out_size, void* d_ws, size_t ws_size,
                              hipStream_t stream)
{
    const float* x       = (const float*)d_in[0];
    const float* Wqkv    = (const float*)d_in[1];
    const float* bqkv    = (const float*)d_in[2];
    const float* Wproj   = (const float*)d_in[3];
    const float* bproj   = (const float*)d_in[4];
    const float* Wrouter = (const float*)d_in[5];
    const float* brouter = (const float*)d_in[6];
    const float* Wq_rt   = (const float*)d_in[7];
    const float* bq_rt   = (const float*)d_in[8];

    float* out = (float*)d_out;
    char*  ws  = (char*)d_ws;

    const size_t MT  = (size_t)B_ * T_;
    const size_t QKV = MT * C_;

    unsigned short* xb   = (unsigned short*)ws;
    unsigned short* Wqt  = xb  + QKV;
    unsigned short* Wpt  = Wqt + (size_t)3 * C_ * C_;
    unsigned short* q    = Wpt + (size_t)C_ * C_;
    unsigned short* k    = q + QKV;
    unsigned short* v    = k + QKV;
    unsigned short* yab  = v + QKV;
    float* cm   = (float*)(yab + QKV);
    float* qrt  = cm  + (size_t)B_ * NCH * C_;
    float* ren  = qrt + MT * RD;
    float* WtQ  = ren + (size_t)B_ * NCH * RD;    // [32][1024] f32

    float* y_out   = out;
    float* idx_out = out + QKV;
    float* sc_out  = idx_out + MT * TOPB;
    float* emb_out = sc_out + MT * NCH;

    // 0) casts / transposes
    cast_bf16_kernel<<<(int)(QKV / 8 / 256), 256, 0, stream>>>(x, xb, (int)(QKV / 8));
    transpose_cast_kernel<<<dim3(3 * C_ / 64, C_ / 64), 256, 0, stream>>>(Wqkv, Wqt, C_, 3 * C_);
    transpose_cast_kernel<<<dim3(C_ / 64, C_ / 64), 256, 0, stream>>>(Wproj, Wpt, C_, C_);
    transpose_f32_kernel<<<128, 256, 0, stream>>>(Wq_rt, WtQ);

    // 1) qkv projection (MFMA) -> bf16 q,k,v [B,H,T,D]
    gemm_mfma<1><<<dim3(3 * C_ / 128, MT / 128), 256, 0, stream>>>(
        xb, Wqt, bqkv, nullptr, q, k, v, (int)MT, 3 * C_, C_);

    // 2) routing path (fp32, bit-stable vs R6)
    chunk_mean_kernel<<<dim3(B_ * NCH, 4), 256, 0, stream>>>(x, cm);
    rowgemm32<<<(B_ * NCH + 7) / 8, 256, 0, stream>>>(cm, Wrouter, brouter, emb_out, B_ * NCH, 0);
    l2norm_rows<<<(B_ * NCH + 7) / 8, 256, 0, stream>>>(emb_out, ren, B_ * NCH);
    rowgemm_qrt<<<((int)MT + 7) / 8, 256, 0, stream>>>(x, WtQ, bq_rt, qrt, (int)MT);
    scores_topk<<<(int)(MT / 64), 64, 0, stream>>>(qrt, ren, sc_out, idx_out);

    // 3) MFMA flash attention -> bf16 ya [B,T,C]
    attn_mfma<<<dim3(1024), 256, 0, stream>>>(q, k, v, yab);

    // 4) output projection (MFMA) -> f32 y
    gemm_mfma<0><<<dim3(C_ / 128, MT / 128), 256, 0, stream>>>(
        yab, Wpt, bproj, y_out, nullptr, nullptr, nullptr, (int)MT, C_, C_);
}

// Round 8
// 214.063 us; speedup vs baseline: 1.2477x; 1.2477x over previous
//
#include <hip/hip_runtime.h>
#include <hip/hip_bf16.h>
#include <math.h>

#define B_   2
#define T_   2048
#define C_   1024
#define H_   16
#define D_   64
#define NCH  32
#define RD   32
#define TOPB 8

typedef __attribute__((ext_vector_type(8))) short bf16x8;
typedef __attribute__((ext_vector_type(4))) float f32x4;

static __device__ __forceinline__ unsigned short f2b(float f) {
    return __bfloat16_as_ushort(__float2bfloat16(f));
}

// ---------------------------------------------------------------------------
// cast x (f32) -> bf16, 8 elements per thread
// ---------------------------------------------------------------------------
__global__ __launch_bounds__(256) void cast_bf16_kernel(
    const float* __restrict__ in, unsigned short* __restrict__ out, int n8)
{
    const int i = blockIdx.x * blockDim.x + threadIdx.x;
    if (i >= n8) return;
    float4 a = ((const float4*)in)[i * 2];
    float4 b = ((const float4*)in)[i * 2 + 1];
    bf16x8 o;
    o[0] = (short)f2b(a.x); o[1] = (short)f2b(a.y);
    o[2] = (short)f2b(a.z); o[3] = (short)f2b(a.w);
    o[4] = (short)f2b(b.x); o[5] = (short)f2b(b.y);
    o[6] = (short)f2b(b.z); o[7] = (short)f2b(b.w);
    *(bf16x8*)&out[i * 8] = o;
}

// ---------------------------------------------------------------------------
// W [K][N] f32 -> Wt [N][K] bf16, 64x64 tiles via LDS
// ---------------------------------------------------------------------------
__global__ __launch_bounds__(256) void transpose_cast_kernel(
    const float* __restrict__ W, unsigned short* __restrict__ Wt, int K, int N)
{
    __shared__ float t[64][65];
    const int tid = threadIdx.x;
    const int n0 = blockIdx.x * 64, k0 = blockIdx.y * 64;
#pragma unroll
    for (int i = 0; i < 4; i++) {
        const int f = tid + i * 256;
        const int r = f >> 4, c4 = (f & 15) * 4;
        float4 v = *(const float4*)&W[(size_t)(k0 + r) * N + n0 + c4];
        t[r][c4 + 0] = v.x; t[r][c4 + 1] = v.y;
        t[r][c4 + 2] = v.z; t[r][c4 + 3] = v.w;
    }
    __syncthreads();
#pragma unroll
    for (int i = 0; i < 2; i++) {
        const int s = tid + i * 256;
        const int rn = s >> 3, ck8 = (s & 7) * 8;
        bf16x8 o;
#pragma unroll
        for (int j = 0; j < 8; j++) o[j] = (short)f2b(t[ck8 + j][rn]);
        *(bf16x8*)&Wt[(size_t)(n0 + rn) * K + k0 + ck8] = o;
    }
}

// ---------------------------------------------------------------------------
// bf16 MFMA GEMM (m97 structure): C = A[M,K] @ Bt[N,K]^T + bias
// ---------------------------------------------------------------------------
template <int MODE>
__global__ __launch_bounds__(256) void gemm_mfma(
    const unsigned short* __restrict__ A, const unsigned short* __restrict__ Bt,
    const float* __restrict__ bias, float* __restrict__ out,
    unsigned short* __restrict__ qp, unsigned short* __restrict__ kp,
    unsigned short* __restrict__ vp, int M, int N, int K)
{
    __shared__ unsigned short As[128 * 32];
    __shared__ unsigned short Bs[128 * 32];

    const int tid  = threadIdx.x;
    const int lane = tid & 63;
    const int wave = tid >> 6;
    const int lr = lane & 15, lg = lane >> 4;
    const int wm = wave >> 1, wn = wave & 1;
    const int n0 = blockIdx.x * 128, m0 = blockIdx.y * 128;

    const int srow = tid >> 2;
    const int scol = (tid & 3) * 8;
    const unsigned short* ga = A  + (size_t)(m0 + srow) * K + scol;
    const unsigned short* gb = Bt + (size_t)(n0 + srow) * K + scol;
    const int ldst = (tid & 0xC0) * 8;

    f32x4 acc[4][4];
#pragma unroll
    for (int i = 0; i < 4; i++)
#pragma unroll
        for (int j = 0; j < 4; j++) acc[i][j] = (f32x4){0.f, 0.f, 0.f, 0.f};

    for (int k0 = 0; k0 < K; k0 += 32) {
        __syncthreads();
#pragma unroll
        for (int i = 0; i < 2; i++) {
            __builtin_amdgcn_global_load_lds(
                (const __attribute__((address_space(1))) int*)(ga + k0 + (size_t)i * 64 * K),
                (__attribute__((address_space(3))) int*)&As[i * 2048 + ldst], 16, 0, 0);
            __builtin_amdgcn_global_load_lds(
                (const __attribute__((address_space(1))) int*)(gb + k0 + (size_t)i * 64 * K),
                (__attribute__((address_space(3))) int*)&Bs[i * 2048 + ldst], 16, 0, 0);
        }
        __syncthreads();

        bf16x8 af[4], bfr[4];
#pragma unroll
        for (int mi = 0; mi < 4; mi++)
            af[mi] = *(const bf16x8*)&As[(wm * 64 + mi * 16 + lr) * 32 + lg * 8];
#pragma unroll
        for (int ni = 0; ni < 4; ni++)
            bfr[ni] = *(const bf16x8*)&Bs[(wn * 64 + ni * 16 + lr) * 32 + lg * 8];
#pragma unroll
        for (int mi = 0; mi < 4; mi++)
#pragma unroll
            for (int ni = 0; ni < 4; ni++)
                acc[mi][ni] = __builtin_amdgcn_mfma_f32_16x16x32_bf16(
                    af[mi], bfr[ni], acc[mi][ni], 0, 0, 0);
    }

#pragma unroll
    for (int ni = 0; ni < 4; ni++) {
        const int col = n0 + wn * 64 + ni * 16 + lr;
        const float bv = bias[col];
        if (MODE == 0) {
#pragma unroll
            for (int mi = 0; mi < 4; mi++) {
#pragma unroll
                for (int r = 0; r < 4; r++) {
                    const int row = m0 + wm * 64 + mi * 16 + lg * 4 + r;
                    out[(size_t)row * N + col] = acc[mi][ni][r] + bv;
                }
            }
        } else {
            const int which = col >> 10;
            const int c  = col & 1023;
            const int hh = c >> 6;
            const int dd = c & 63;
            unsigned short* dst = (which == 0) ? qp : (which == 1) ? kp : vp;
#pragma unroll
            for (int mi = 0; mi < 4; mi++) {
#pragma unroll
                for (int r = 0; r < 4; r++) {
                    const int row = m0 + wm * 64 + mi * 16 + lg * 4 + r;
                    const int bb = row >> 11, tt = row & 2047;
                    dst[(((size_t)bb * H_ + hh) * T_ + tt) * D_ + dd] =
                        f2b(acc[mi][ni][r] + bv);
                }
            }
        }
    }
}

// ---------------------------------------------------------------------------
// chunk means: grid (64, 4) — one column per thread
// ---------------------------------------------------------------------------
__global__ void chunk_mean_kernel(const float* __restrict__ x, float* __restrict__ cm)
{
    const int bc = blockIdx.x;
    const int b = bc >> 5, n = bc & 31;
    const int c = blockIdx.y * 256 + threadIdx.x;
    const float* xp = x + ((size_t)b * T_ + n * 64) * C_;
    float s = 0.f;
    for (int i = 0; i < 64; i++) s += xp[(size_t)i * C_ + c];
    cm[(size_t)bc * C_ + c] = s * (1.0f / 64.0f);
}

// ---------------------------------------------------------------------------
// rowgemm32 (W in [K][32] layout) — 64-row routing-embeds path
// ---------------------------------------------------------------------------
__global__ void rowgemm32(const float* __restrict__ A, const float* __restrict__ W,
                          const float* __restrict__ bias, float* __restrict__ dst,
                          int M, int normalize)
{
    const int row  = blockIdx.x * 8 + (threadIdx.x >> 5);
    const int lane = threadIdx.x & 31;
    if (row >= M) return;
    const float* a = A + (size_t)row * C_;
    float acc = 0.f;
    for (int k = 0; k < C_; k += 4) {
        float4 a4 = *(const float4*)&a[k];
        acc += a4.x * W[(k + 0) * RD + lane];
        acc += a4.y * W[(k + 1) * RD + lane];
        acc += a4.z * W[(k + 2) * RD + lane];
        acc += a4.w * W[(k + 3) * RD + lane];
    }
    acc += bias[lane];
    if (normalize) {
        float ss = acc * acc;
#pragma unroll
        for (int off = 16; off >= 1; off >>= 1) ss += __shfl_xor(ss, off, 32);
        acc = acc / fmaxf(sqrtf(ss), 1e-12f);
    }
    dst[(size_t)row * RD + lane] = acc;
}

__global__ void l2norm_rows(const float* __restrict__ src, float* __restrict__ dst, int M)
{
    const int row  = blockIdx.x * 8 + (threadIdx.x >> 5);
    const int lane = threadIdx.x & 31;
    if (row >= M) return;
    float v = src[(size_t)row * RD + lane];
    float ss = v * v;
#pragma unroll
    for (int off = 16; off >= 1; off >>= 1) ss += __shfl_xor(ss, off, 32);
    dst[(size_t)row * RD + lane] = v / fmaxf(sqrtf(ss), 1e-12f);
}

// ---------------------------------------------------------------------------
// q_rt projection + l2norm: tall-skinny GEMM [4096,1024]x[1024,32].
// Block = 4 rows, 256 thr = 8 k-groups x 32 n-lanes; each thread a 128-deep
// K-slice for 4 rows (W reused 4x in regs); LDS partial reduce; shuffle l2norm.
// 1024 blocks -> 4096 waves (16/CU): latency fully hidden by TLP.
// ---------------------------------------------------------------------------
__global__ __launch_bounds__(256) void qrt_kernel(
    const float* __restrict__ x, const float* __restrict__ W,
    const float* __restrict__ bias, float* __restrict__ dst)
{
    __shared__ float part[8][4][32];
    const int r0 = blockIdx.x * 4;
    const int g = threadIdx.x >> 5;       // k-group 0..7
    const int n = threadIdx.x & 31;       // output col

    const float* w  = W + (size_t)(g * 128) * RD + n;
    const float* a0 = x + (size_t)(r0 + 0) * C_ + g * 128;
    const float* a1 = x + (size_t)(r0 + 1) * C_ + g * 128;
    const float* a2 = x + (size_t)(r0 + 2) * C_ + g * 128;
    const float* a3 = x + (size_t)(r0 + 3) * C_ + g * 128;

    float acc0 = 0.f, acc1 = 0.f, acc2 = 0.f, acc3 = 0.f;
#pragma unroll 8
    for (int i = 0; i < 128; i += 4) {
        const float w0 = w[(i + 0) * RD];
        const float w1 = w[(i + 1) * RD];
        const float w2 = w[(i + 2) * RD];
        const float w3 = w[(i + 3) * RD];
        float4 x0 = *(const float4*)&a0[i];
        float4 x1 = *(const float4*)&a1[i];
        float4 x2 = *(const float4*)&a2[i];
        float4 x3 = *(const float4*)&a3[i];
        acc0 += x0.x * w0; acc0 += x0.y * w1; acc0 += x0.z * w2; acc0 += x0.w * w3;
        acc1 += x1.x * w0; acc1 += x1.y * w1; acc1 += x1.z * w2; acc1 += x1.w * w3;
        acc2 += x2.x * w0; acc2 += x2.y * w1; acc2 += x2.z * w2; acc2 += x2.w * w3;
        acc3 += x3.x * w0; acc3 += x3.y * w1; acc3 += x3.z * w2; acc3 += x3.w * w3;
    }
    part[g][0][n] = acc0;
    part[g][1][n] = acc1;
    part[g][2][n] = acc2;
    part[g][3][n] = acc3;
    __syncthreads();

    if (g < 4) {   // thread handles row r0+g, col n
        float s = part[0][g][n];
#pragma unroll
        for (int gg = 1; gg < 8; gg++) s += part[gg][g][n];
        s += bias[n];
        float ss = s * s;
#pragma unroll
        for (int off = 16; off >= 1; off >>= 1) ss += __shfl_xor(ss, off, 32);
        dst[(size_t)(r0 + g) * RD + n] = s / fmaxf(sqrtf(ss), 1e-12f);
    }
}

// ---------------------------------------------------------------------------
// routing scores + top-8 (64 blocks x 64 threads)
// ---------------------------------------------------------------------------
__global__ void scores_topk(const float* __restrict__ qrt, const float* __restrict__ ren,
                            float* __restrict__ sc_out, float* __restrict__ idx_out)
{
    const int row = blockIdx.x * 64 + threadIdx.x;
    if (row >= B_ * T_) return;
    const int b = row / T_;
    float q[RD];
#pragma unroll
    for (int i = 0; i < RD; i++) q[i] = qrt[(size_t)row * RD + i];
    const float* rb = ren + (size_t)b * NCH * RD;
    float s[NCH];
#pragma unroll 4
    for (int n = 0; n < NCH; n++) {
        float acc = 0.f;
#pragma unroll
        for (int i = 0; i < RD; i++) acc += q[i] * rb[n * RD + i];
        s[n] = acc;
        sc_out[(size_t)row * NCH + n] = acc;
    }
    unsigned mask = 0;
    for (int t = 0; t < TOPB; t++) {
        float best = -INFINITY;
        int bi = 0;
#pragma unroll
        for (int n = 0; n < NCH; n++) {
            const bool ok = !((mask >> n) & 1u) && (s[n] > best);
            if (ok) { best = s[n]; bi = n; }
        }
        mask |= (1u << bi);
        idx_out[(size_t)row * TOPB + t] = (float)bi;
    }
}

// ---------------------------------------------------------------------------
// MFMA bf16 flash attention, v5: swapped QK^T + fully in-register softmax.
// ---------------------------------------------------------------------------
#define LSTR 68
#define SCALE2 0.18033688f   /* 0.125 * 1.44269504 */

__global__ __launch_bounds__(256) void attn_mfma(
    const unsigned short* __restrict__ qg, const unsigned short* __restrict__ kg,
    const unsigned short* __restrict__ vg, unsigned short* __restrict__ y)
{
    const int bid = blockIdx.x;
    const int xcd = bid & 7;
    const int j   = bid >> 3;                 // 0..127
    const int h   = xcd + 8 * (j & 1);
    const int b   = (j >> 1) & 1;
    const int qt  = 31 - (j >> 2);            // long blocks dispatch first

    const int tid  = threadIdx.x;
    const int wave = tid >> 6;
    const int lane = tid & 63;
    const int lg = lane >> 4;
    const int lr = lane & 15;

    __shared__ short Ks[2][64][LSTR];
    __shared__ short Vt[2][64][LSTR];     // Vt[buf][d][slot] (permuted kv order)

    const size_t base = ((size_t)(b * H_ + h) * T_) * D_;

    bf16x8 qf0, qf1;
    {
        const short* qp = (const short*)qg + base + (size_t)(qt * 64 + wave * 16 + lr) * D_;
        qf0 = *(const bf16x8*)&qp[lg * 8];
        qf1 = *(const bf16x8*)&qp[32 + lg * 8];
    }

    const int srr = tid >> 2;
    const int sc0 = (tid & 3) * 16;
    const int vrp = tid & 31;
    const int vcg = tid >> 5;
    const int kv0   = 2 * vrp;
    const int vslot = ((kv0 >> 5) << 5) + (((kv0 >> 2) & 3) << 3) +
                      (((kv0 >> 4) & 1) << 2) + (kv0 & 3);

    bf16x8 kreg0, kreg1, vreg0, vreg1;

    float m_run = -INFINITY, l_run = 0.f;
    f32x4 oacc[4];
#pragma unroll
    for (int r = 0; r < 4; r++) oacc[r] = (f32x4){0.f, 0.f, 0.f, 0.f};
    const int qrow_g = qt * 64 + wave * 16 + lr;

    {
        const short* kp = (const short*)kg + base + (size_t)srr * D_ + sc0;
        kreg0 = *(const bf16x8*)kp;
        kreg1 = *(const bf16x8*)(kp + 8);
        const short* vp = (const short*)vg + base + (size_t)kv0 * D_ + vcg * 8;
        vreg0 = *(const bf16x8*)vp;
        vreg1 = *(const bf16x8*)(vp + D_);
    }
    {
        *(bf16x8*)&Ks[0][srr][sc0]     = kreg0;
        *(bf16x8*)&Ks[0][srr][sc0 + 8] = kreg1;
#pragma unroll
        for (int jj = 0; jj < 8; jj++) {
            const unsigned int dw = ((unsigned int)(unsigned short)vreg0[jj]) |
                                    (((unsigned int)(unsigned short)vreg1[jj]) << 16);
            *(unsigned int*)&Vt[0][vcg * 8 + jj][vslot] = dw;
        }
    }
    if (qt >= 1) {
        const short* kp = (const short*)kg + base + (size_t)(64 + srr) * D_ + sc0;
        kreg0 = *(const bf16x8*)kp;
        kreg1 = *(const bf16x8*)(kp + 8);
        const short* vp = (const short*)vg + base + (size_t)(64 + kv0) * D_ + vcg * 8;
        vreg0 = *(const bf16x8*)vp;
        vreg1 = *(const bf16x8*)(vp + D_);
    }
    __syncthreads();

    for (int kt = 0; kt <= qt; ++kt) {
        const int cur = kt & 1;

        if (kt < qt) {
            *(bf16x8*)&Ks[cur ^ 1][srr][sc0]     = kreg0;
            *(bf16x8*)&Ks[cur ^ 1][srr][sc0 + 8] = kreg1;
#pragma unroll
            for (int jj = 0; jj < 8; jj++) {
                const unsigned int dw = ((unsigned int)(unsigned short)vreg0[jj]) |
                                        (((unsigned int)(unsigned short)vreg1[jj]) << 16);
                *(unsigned int*)&Vt[cur ^ 1][vcg * 8 + jj][vslot] = dw;
            }
        }
        if (kt + 2 <= qt) {
            const short* kp = (const short*)kg + base + (size_t)((kt + 2) * 64 + srr) * D_ + sc0;
            kreg0 = *(const bf16x8*)kp;
            kreg1 = *(const bf16x8*)(kp + 8);
            const short* vp = (const short*)vg + base + (size_t)((kt + 2) * 64 + kv0) * D_ + vcg * 8;
            vreg0 = *(const bf16x8*)vp;
            vreg1 = *(const bf16x8*)(vp + D_);
        }

        f32x4 s[4];
        __builtin_amdgcn_s_setprio(1);
#pragma unroll
        for (int cb = 0; cb < 4; cb++) {
            bf16x8 kf0 = *(const bf16x8*)&Ks[cur][cb * 16 + lr][lg * 8];
            bf16x8 kf1 = *(const bf16x8*)&Ks[cur][cb * 16 + lr][32 + lg * 8];
            f32x4 acc = (f32x4){0.f, 0.f, 0.f, 0.f};
            acc = __builtin_amdgcn_mfma_f32_16x16x32_bf16(kf0, qf0, acc, 0, 0, 0);
            acc = __builtin_amdgcn_mfma_f32_16x16x32_bf16(kf1, qf1, acc, 0, 0, 0);
            s[cb] = acc;
        }
        __builtin_amdgcn_s_setprio(0);

        if (kt == qt) {
#pragma unroll
            for (int cb = 0; cb < 4; cb++) {
#pragma unroll
                for (int r = 0; r < 4; r++) {
                    float sv = s[cb][r] * SCALE2;
                    if (kt * 64 + cb * 16 + lg * 4 + r > qrow_g) sv = -INFINITY;
                    s[cb][r] = sv;
                }
            }
        } else {
#pragma unroll
            for (int cb = 0; cb < 4; cb++)
#pragma unroll
                for (int r = 0; r < 4; r++) s[cb][r] *= SCALE2;
        }

        float rm = -INFINITY;
#pragma unroll
        for (int cb = 0; cb < 4; cb++)
#pragma unroll
            for (int r = 0; r < 4; r++) rm = fmaxf(rm, s[cb][r]);
        rm = fmaxf(rm, __shfl_xor(rm, 16));
        rm = fmaxf(rm, __shfl_xor(rm, 32));

        if (!__all(rm <= m_run + 8.0f)) {
            const float mnew = fmaxf(m_run, rm);
            const float fsc  = exp2f(m_run - mnew);
            m_run = mnew;
            l_run *= fsc;
            float fr[4];
#pragma unroll
            for (int r = 0; r < 4; r++) fr[r] = __shfl(fsc, lg * 4 + r);
#pragma unroll
            for (int db = 0; db < 4; db++)
#pragma unroll
                for (int r = 0; r < 4; r++) oacc[db][r] *= fr[r];
        }

        float p[4][4];
        float rs = 0.f;
#pragma unroll
        for (int cb = 0; cb < 4; cb++)
#pragma unroll
            for (int r = 0; r < 4; r++) {
                const float pv = exp2f(s[cb][r] - m_run);
                p[cb][r] = pv;
                rs += pv;
            }
        rs += __shfl_xor(rs, 16);
        rs += __shfl_xor(rs, 32);
        l_run += rs;

        bf16x8 pf0, pf1;
#pragma unroll
        for (int r = 0; r < 4; r++) {
            pf0[r]     = (short)f2b(p[0][r]);
            pf0[4 + r] = (short)f2b(p[1][r]);
            pf1[r]     = (short)f2b(p[2][r]);
            pf1[4 + r] = (short)f2b(p[3][r]);
        }

        __builtin_amdgcn_s_setprio(1);
#pragma unroll
        for (int db = 0; db < 4; db++) {
            bf16x8 vf0 = *(const bf16x8*)&Vt[cur][db * 16 + lr][lg * 8];
            bf16x8 vf1 = *(const bf16x8*)&Vt[cur][db * 16 + lr][32 + lg * 8];
            oacc[db] = __builtin_amdgcn_mfma_f32_16x16x32_bf16(pf0, vf0, oacc[db], 0, 0, 0);
            oacc[db] = __builtin_amdgcn_mfma_f32_16x16x32_bf16(pf1, vf1, oacc[db], 0, 0, 0);
        }
        __builtin_amdgcn_s_setprio(0);

        __syncthreads();
    }

#pragma unroll
    for (int r = 0; r < 4; r++) {
        const float lrow = __shfl(l_run, lg * 4 + r);
        const float inv = 1.0f / lrow;
        const int trow = qt * 64 + wave * 16 + lg * 4 + r;
        unsigned short* yp = y + (size_t)(b * T_ + trow) * C_ + h * D_;
#pragma unroll
        for (int db = 0; db < 4; db++)
            yp[db * 16 + lr] = f2b(oacc[db][r] * inv);
    }
}

// ---------------------------------------------------------------------------
extern "C" void kernel_launch(void* const* d_in, const int* in_sizes, int n_in,
                              void* d_out, int out_size, void* d_ws, size_t ws_size,
                              hipStream_t stream)
{
    const float* x       = (const float*)d_in[0];
    const float* Wqkv    = (const float*)d_in[1];
    const float* bqkv    = (const float*)d_in[2];
    const float* Wproj   = (const float*)d_in[3];
    const float* bproj   = (const float*)d_in[4];
    const float* Wrouter = (const float*)d_in[5];
    const float* brouter = (const float*)d_in[6];
    const float* Wq_rt   = (const float*)d_in[7];
    const float* bq_rt   = (const float*)d_in[8];

    float* out = (float*)d_out;
    char*  ws  = (char*)d_ws;

    const size_t MT  = (size_t)B_ * T_;
    const size_t QKV = MT * C_;

    unsigned short* xb   = (unsigned short*)ws;
    unsigned short* Wqt  = xb  + QKV;
    unsigned short* Wpt  = Wqt + (size_t)3 * C_ * C_;
    unsigned short* q    = Wpt + (size_t)C_ * C_;
    unsigned short* k    = q + QKV;
    unsigned short* v    = k + QKV;
    unsigned short* yab  = v + QKV;
    float* cm   = (float*)(yab + QKV);
    float* qrt  = cm  + (size_t)B_ * NCH * C_;
    float* ren  = qrt + MT * RD;

    float* y_out   = out;
    float* idx_out = out + QKV;
    float* sc_out  = idx_out + MT * TOPB;
    float* emb_out = sc_out + MT * NCH;

    // 0) casts / transposes
    cast_bf16_kernel<<<(int)(QKV / 8 / 256), 256, 0, stream>>>(x, xb, (int)(QKV / 8));
    transpose_cast_kernel<<<dim3(3 * C_ / 64, C_ / 64), 256, 0, stream>>>(Wqkv, Wqt, C_, 3 * C_);
    transpose_cast_kernel<<<dim3(C_ / 64, C_ / 64), 256, 0, stream>>>(Wproj, Wpt, C_, C_);

    // 1) qkv projection (MFMA) -> bf16 q,k,v [B,H,T,D]
    gemm_mfma<1><<<dim3(3 * C_ / 128, MT / 128), 256, 0, stream>>>(
        xb, Wqt, bqkv, nullptr, q, k, v, (int)MT, 3 * C_, C_);

    // 2) routing path (fp32)
    chunk_mean_kernel<<<dim3(B_ * NCH, 4), 256, 0, stream>>>(x, cm);
    rowgemm32<<<(B_ * NCH + 7) / 8, 256, 0, stream>>>(cm, Wrouter, brouter, emb_out, B_ * NCH, 0);
    l2norm_rows<<<(B_ * NCH + 7) / 8, 256, 0, stream>>>(emb_out, ren, B_ * NCH);
    qrt_kernel<<<(int)(MT / 4), 256, 0, stream>>>(x, Wq_rt, bq_rt, qrt);
    scores_topk<<<(int)(MT / 64), 64, 0, stream>>>(qrt, ren, sc_out, idx_out);

    // 3) MFMA flash attention -> bf16 ya [B,T,C]
    attn_mfma<<<dim3(1024), 256, 0, stream>>>(q, k, v, yab);

    // 4) output projection (MFMA) -> f32 y
    gemm_mfma<0><<<dim3(C_ / 128, MT / 128), 256, 0, stream>>>(
        yab, Wpt, bproj, y_out, nullptr, nullptr, nullptr, (int)MT, C_, C_);
}

// Round 9
// 209.497 us; speedup vs baseline: 1.2749x; 1.0218x over previous
//
#include <hip/hip_runtime.h>
#include <hip/hip_bf16.h>
#include <math.h>

#define B_   2
#define T_   2048
#define C_   1024
#define H_   16
#define D_   64
#define NCH  32
#define RD   32
#define TOPB 8

typedef __attribute__((ext_vector_type(8))) short bf16x8;
typedef __attribute__((ext_vector_type(4))) float f32x4;

static __device__ __forceinline__ unsigned short f2b(float f) {
    return __bfloat16_as_ushort(__float2bfloat16(f));
}

// ---------------------------------------------------------------------------
// cast x (f32) -> bf16, 8 elements per thread
// ---------------------------------------------------------------------------
__global__ __launch_bounds__(256) void cast_bf16_kernel(
    const float* __restrict__ in, unsigned short* __restrict__ out, int n8)
{
    const int i = blockIdx.x * blockDim.x + threadIdx.x;
    if (i >= n8) return;
    float4 a = ((const float4*)in)[i * 2];
    float4 b = ((const float4*)in)[i * 2 + 1];
    bf16x8 o;
    o[0] = (short)f2b(a.x); o[1] = (short)f2b(a.y);
    o[2] = (short)f2b(a.z); o[3] = (short)f2b(a.w);
    o[4] = (short)f2b(b.x); o[5] = (short)f2b(b.y);
    o[6] = (short)f2b(b.z); o[7] = (short)f2b(b.w);
    *(bf16x8*)&out[i * 8] = o;
}

// ---------------------------------------------------------------------------
// W [K][N] f32 -> Wt [N][K] bf16, 64x64 tiles via LDS
// ---------------------------------------------------------------------------
__global__ __launch_bounds__(256) void transpose_cast_kernel(
    const float* __restrict__ W, unsigned short* __restrict__ Wt, int K, int N)
{
    __shared__ float t[64][65];
    const int tid = threadIdx.x;
    const int n0 = blockIdx.x * 64, k0 = blockIdx.y * 64;
#pragma unroll
    for (int i = 0; i < 4; i++) {
        const int f = tid + i * 256;
        const int r = f >> 4, c4 = (f & 15) * 4;
        float4 v = *(const float4*)&W[(size_t)(k0 + r) * N + n0 + c4];
        t[r][c4 + 0] = v.x; t[r][c4 + 1] = v.y;
        t[r][c4 + 2] = v.z; t[r][c4 + 3] = v.w;
    }
    __syncthreads();
#pragma unroll
    for (int i = 0; i < 2; i++) {
        const int s = tid + i * 256;
        const int rn = s >> 3, ck8 = (s & 7) * 8;
        bf16x8 o;
#pragma unroll
        for (int j = 0; j < 8; j++) o[j] = (short)f2b(t[ck8 + j][rn]);
        *(bf16x8*)&Wt[(size_t)(n0 + rn) * K + k0 + ck8] = o;
    }
}

// ---------------------------------------------------------------------------
// bf16 MFMA GEMM, 2-phase pipelined (T3-minimum): C = A[M,K] @ Bt[N,K]^T + bias
// 128x128 tile, BK=32, double-buffered LDS; loads for tile t+1 issued before
// compute of tile t; ONE barrier per tile (its vmcnt drain lands after the
// loads had the whole compute phase in flight).
// MODE 0: f32 out[M,N].  MODE 1: qkv scatter -> bf16 [B,H,T,D].
// ---------------------------------------------------------------------------
template <int MODE>
__global__ __launch_bounds__(256) void gemm_mfma(
    const unsigned short* __restrict__ A, const unsigned short* __restrict__ Bt,
    const float* __restrict__ bias, float* __restrict__ out,
    unsigned short* __restrict__ qp, unsigned short* __restrict__ kp,
    unsigned short* __restrict__ vp, int M, int N, int K)
{
    __shared__ unsigned short As[2][128 * 32];
    __shared__ unsigned short Bs[2][128 * 32];

    const int tid  = threadIdx.x;
    const int lane = tid & 63;
    const int wave = tid >> 6;
    const int lr = lane & 15, lg = lane >> 4;
    const int wm = wave >> 1, wn = wave & 1;
    const int n0 = blockIdx.x * 128, m0 = blockIdx.y * 128;

    const int srow = tid >> 2;
    const int scol = (tid & 3) * 8;
    const unsigned short* ga = A  + (size_t)(m0 + srow) * K + scol;
    const unsigned short* gb = Bt + (size_t)(n0 + srow) * K + scol;
    const int ldst = (tid & 0xC0) * 8;

    f32x4 acc[4][4];
#pragma unroll
    for (int i = 0; i < 4; i++)
#pragma unroll
        for (int j = 0; j < 4; j++) acc[i][j] = (f32x4){0.f, 0.f, 0.f, 0.f};

#define GSTAGE(buf, k0)                                                        \
    _Pragma("unroll")                                                          \
    for (int i = 0; i < 2; i++) {                                              \
        __builtin_amdgcn_global_load_lds(                                      \
            (const __attribute__((address_space(1))) int*)(ga + (k0) + (size_t)i * 64 * K), \
            (__attribute__((address_space(3))) int*)&As[buf][i * 2048 + ldst], 16, 0, 0);   \
        __builtin_amdgcn_global_load_lds(                                      \
            (const __attribute__((address_space(1))) int*)(gb + (k0) + (size_t)i * 64 * K), \
            (__attribute__((address_space(3))) int*)&Bs[buf][i * 2048 + ldst], 16, 0, 0);   \
    }

    const int nt = K >> 5;
    GSTAGE(0, 0);
    __syncthreads();                 // drains vmcnt -> buf0 ready

    int cur = 0;
    for (int t = 0; t < nt; ++t) {
        if (t + 1 < nt) {            // issue next tile's loads FIRST (overlap)
            GSTAGE(cur ^ 1, (t + 1) << 5);
        }

        bf16x8 af[4], bfr[4];
#pragma unroll
        for (int mi = 0; mi < 4; mi++)
            af[mi] = *(const bf16x8*)&As[cur][(wm * 64 + mi * 16 + lr) * 32 + lg * 8];
#pragma unroll
        for (int ni = 0; ni < 4; ni++)
            bfr[ni] = *(const bf16x8*)&Bs[cur][(wn * 64 + ni * 16 + lr) * 32 + lg * 8];
#pragma unroll
        for (int mi = 0; mi < 4; mi++)
#pragma unroll
            for (int ni = 0; ni < 4; ni++)
                acc[mi][ni] = __builtin_amdgcn_mfma_f32_16x16x32_bf16(
                    af[mi], bfr[ni], acc[mi][ni], 0, 0, 0);

        __syncthreads();             // buf[cur] reads done; buf[cur^1] loaded
        cur ^= 1;
    }
#undef GSTAGE

#pragma unroll
    for (int ni = 0; ni < 4; ni++) {
        const int col = n0 + wn * 64 + ni * 16 + lr;
        const float bv = bias[col];
        if (MODE == 0) {
#pragma unroll
            for (int mi = 0; mi < 4; mi++) {
#pragma unroll
                for (int r = 0; r < 4; r++) {
                    const int row = m0 + wm * 64 + mi * 16 + lg * 4 + r;
                    out[(size_t)row * N + col] = acc[mi][ni][r] + bv;
                }
            }
        } else {
            const int which = col >> 10;
            const int c  = col & 1023;
            const int hh = c >> 6;
            const int dd = c & 63;
            unsigned short* dst = (which == 0) ? qp : (which == 1) ? kp : vp;
#pragma unroll
            for (int mi = 0; mi < 4; mi++) {
#pragma unroll
                for (int r = 0; r < 4; r++) {
                    const int row = m0 + wm * 64 + mi * 16 + lg * 4 + r;
                    const int bb = row >> 11, tt = row & 2047;
                    dst[(((size_t)bb * H_ + hh) * T_ + tt) * D_ + dd] =
                        f2b(acc[mi][ni][r] + bv);
                }
            }
        }
    }
}

// ---------------------------------------------------------------------------
// chunk means: grid (64, 4) — one column per thread
// ---------------------------------------------------------------------------
__global__ void chunk_mean_kernel(const float* __restrict__ x, float* __restrict__ cm)
{
    const int bc = blockIdx.x;
    const int b = bc >> 5, n = bc & 31;
    const int c = blockIdx.y * 256 + threadIdx.x;
    const float* xp = x + ((size_t)b * T_ + n * 64) * C_;
    float s = 0.f;
    for (int i = 0; i < 64; i++) s += xp[(size_t)i * C_ + c];
    cm[(size_t)bc * C_ + c] = s * (1.0f / 64.0f);
}

// ---------------------------------------------------------------------------
// rowgemm32 (W in [K][32] layout) — 64-row routing-embeds path
// ---------------------------------------------------------------------------
__global__ void rowgemm32(const float* __restrict__ A, const float* __restrict__ W,
                          const float* __restrict__ bias, float* __restrict__ dst,
                          int M, int normalize)
{
    const int row  = blockIdx.x * 8 + (threadIdx.x >> 5);
    const int lane = threadIdx.x & 31;
    if (row >= M) return;
    const float* a = A + (size_t)row * C_;
    float acc = 0.f;
    for (int k = 0; k < C_; k += 4) {
        float4 a4 = *(const float4*)&a[k];
        acc += a4.x * W[(k + 0) * RD + lane];
        acc += a4.y * W[(k + 1) * RD + lane];
        acc += a4.z * W[(k + 2) * RD + lane];
        acc += a4.w * W[(k + 3) * RD + lane];
    }
    acc += bias[lane];
    if (normalize) {
        float ss = acc * acc;
#pragma unroll
        for (int off = 16; off >= 1; off >>= 1) ss += __shfl_xor(ss, off, 32);
        acc = acc / fmaxf(sqrtf(ss), 1e-12f);
    }
    dst[(size_t)row * RD + lane] = acc;
}

__global__ void l2norm_rows(const float* __restrict__ src, float* __restrict__ dst, int M)
{
    const int row  = blockIdx.x * 8 + (threadIdx.x >> 5);
    const int lane = threadIdx.x & 31;
    if (row >= M) return;
    float v = src[(size_t)row * RD + lane];
    float ss = v * v;
#pragma unroll
    for (int off = 16; off >= 1; off >>= 1) ss += __shfl_xor(ss, off, 32);
    dst[(size_t)row * RD + lane] = v / fmaxf(sqrtf(ss), 1e-12f);
}

// ---------------------------------------------------------------------------
// q_rt projection + l2norm (tall-skinny GEMM, latency-optimized)
// ---------------------------------------------------------------------------
__global__ __launch_bounds__(256) void qrt_kernel(
    const float* __restrict__ x, const float* __restrict__ W,
    const float* __restrict__ bias, float* __restrict__ dst)
{
    __shared__ float part[8][4][32];
    const int r0 = blockIdx.x * 4;
    const int g = threadIdx.x >> 5;       // k-group 0..7
    const int n = threadIdx.x & 31;       // output col

    const float* w  = W + (size_t)(g * 128) * RD + n;
    const float* a0 = x + (size_t)(r0 + 0) * C_ + g * 128;
    const float* a1 = x + (size_t)(r0 + 1) * C_ + g * 128;
    const float* a2 = x + (size_t)(r0 + 2) * C_ + g * 128;
    const float* a3 = x + (size_t)(r0 + 3) * C_ + g * 128;

    float acc0 = 0.f, acc1 = 0.f, acc2 = 0.f, acc3 = 0.f;
#pragma unroll 8
    for (int i = 0; i < 128; i += 4) {
        const float w0 = w[(i + 0) * RD];
        const float w1 = w[(i + 1) * RD];
        const float w2 = w[(i + 2) * RD];
        const float w3 = w[(i + 3) * RD];
        float4 x0 = *(const float4*)&a0[i];
        float4 x1 = *(const float4*)&a1[i];
        float4 x2 = *(const float4*)&a2[i];
        float4 x3 = *(const float4*)&a3[i];
        acc0 += x0.x * w0; acc0 += x0.y * w1; acc0 += x0.z * w2; acc0 += x0.w * w3;
        acc1 += x1.x * w0; acc1 += x1.y * w1; acc1 += x1.z * w2; acc1 += x1.w * w3;
        acc2 += x2.x * w0; acc2 += x2.y * w1; acc2 += x2.z * w2; acc2 += x2.w * w3;
        acc3 += x3.x * w0; acc3 += x3.y * w1; acc3 += x3.z * w2; acc3 += x3.w * w3;
    }
    part[g][0][n] = acc0;
    part[g][1][n] = acc1;
    part[g][2][n] = acc2;
    part[g][3][n] = acc3;
    __syncthreads();

    if (g < 4) {
        float s = part[0][g][n];
#pragma unroll
        for (int gg = 1; gg < 8; gg++) s += part[gg][g][n];
        s += bias[n];
        float ss = s * s;
#pragma unroll
        for (int off = 16; off >= 1; off >>= 1) ss += __shfl_xor(ss, off, 32);
        dst[(size_t)(r0 + g) * RD + n] = s / fmaxf(sqrtf(ss), 1e-12f);
    }
}

// ---------------------------------------------------------------------------
// routing scores + top-8 (64 blocks x 64 threads)
// ---------------------------------------------------------------------------
__global__ void scores_topk(const float* __restrict__ qrt, const float* __restrict__ ren,
                            float* __restrict__ sc_out, float* __restrict__ idx_out)
{
    const int row = blockIdx.x * 64 + threadIdx.x;
    if (row >= B_ * T_) return;
    const int b = row / T_;
    float q[RD];
#pragma unroll
    for (int i = 0; i < RD; i++) q[i] = qrt[(size_t)row * RD + i];
    const float* rb = ren + (size_t)b * NCH * RD;
    float s[NCH];
#pragma unroll 4
    for (int n = 0; n < NCH; n++) {
        float acc = 0.f;
#pragma unroll
        for (int i = 0; i < RD; i++) acc += q[i] * rb[n * RD + i];
        s[n] = acc;
        sc_out[(size_t)row * NCH + n] = acc;
    }
    unsigned mask = 0;
    for (int t = 0; t < TOPB; t++) {
        float best = -INFINITY;
        int bi = 0;
#pragma unroll
        for (int n = 0; n < NCH; n++) {
            const bool ok = !((mask >> n) & 1u) && (s[n] > best);
            if (ok) { best = s[n]; bi = n; }
        }
        mask |= (1u << bi);
        idx_out[(size_t)row * TOPB + t] = (float)bi;
    }
}

// ---------------------------------------------------------------------------
// MFMA bf16 flash attention, v5: swapped QK^T + fully in-register softmax.
// ---------------------------------------------------------------------------
#define LSTR 68
#define SCALE2 0.18033688f   /* 0.125 * 1.44269504 */

__global__ __launch_bounds__(256) void attn_mfma(
    const unsigned short* __restrict__ qg, const unsigned short* __restrict__ kg,
    const unsigned short* __restrict__ vg, unsigned short* __restrict__ y)
{
    const int bid = blockIdx.x;
    const int xcd = bid & 7;
    const int j   = bid >> 3;                 // 0..127
    const int h   = xcd + 8 * (j & 1);
    const int b   = (j >> 1) & 1;
    const int qt  = 31 - (j >> 2);            // long blocks dispatch first

    const int tid  = threadIdx.x;
    const int wave = tid >> 6;
    const int lane = tid & 63;
    const int lg = lane >> 4;
    const int lr = lane & 15;

    __shared__ short Ks[2][64][LSTR];
    __shared__ short Vt[2][64][LSTR];     // Vt[buf][d][slot] (permuted kv order)

    const size_t base = ((size_t)(b * H_ + h) * T_) * D_;

    bf16x8 qf0, qf1;
    {
        const short* qp = (const short*)qg + base + (size_t)(qt * 64 + wave * 16 + lr) * D_;
        qf0 = *(const bf16x8*)&qp[lg * 8];
        qf1 = *(const bf16x8*)&qp[32 + lg * 8];
    }

    const int srr = tid >> 2;
    const int sc0 = (tid & 3) * 16;
    const int vrp = tid & 31;
    const int vcg = tid >> 5;
    const int kv0   = 2 * vrp;
    const int vslot = ((kv0 >> 5) << 5) + (((kv0 >> 2) & 3) << 3) +
                      (((kv0 >> 4) & 1) << 2) + (kv0 & 3);

    bf16x8 kreg0, kreg1, vreg0, vreg1;

    float m_run = -INFINITY, l_run = 0.f;
    f32x4 oacc[4];
#pragma unroll
    for (int r = 0; r < 4; r++) oacc[r] = (f32x4){0.f, 0.f, 0.f, 0.f};
    const int qrow_g = qt * 64 + wave * 16 + lr;

    {
        const short* kp = (const short*)kg + base + (size_t)srr * D_ + sc0;
        kreg0 = *(const bf16x8*)kp;
        kreg1 = *(const bf16x8*)(kp + 8);
        const short* vp = (const short*)vg + base + (size_t)kv0 * D_ + vcg * 8;
        vreg0 = *(const bf16x8*)vp;
        vreg1 = *(const bf16x8*)(vp + D_);
    }
    {
        *(bf16x8*)&Ks[0][srr][sc0]     = kreg0;
        *(bf16x8*)&Ks[0][srr][sc0 + 8] = kreg1;
#pragma unroll
        for (int jj = 0; jj < 8; jj++) {
            const unsigned int dw = ((unsigned int)(unsigned short)vreg0[jj]) |
                                    (((unsigned int)(unsigned short)vreg1[jj]) << 16);
            *(unsigned int*)&Vt[0][vcg * 8 + jj][vslot] = dw;
        }
    }
    if (qt >= 1) {
        const short* kp = (const short*)kg + base + (size_t)(64 + srr) * D_ + sc0;
        kreg0 = *(const bf16x8*)kp;
        kreg1 = *(const bf16x8*)(kp + 8);
        const short* vp = (const short*)vg + base + (size_t)(64 + kv0) * D_ + vcg * 8;
        vreg0 = *(const bf16x8*)vp;
        vreg1 = *(const bf16x8*)(vp + D_);
    }
    __syncthreads();

    for (int kt = 0; kt <= qt; ++kt) {
        const int cur = kt & 1;

        if (kt < qt) {
            *(bf16x8*)&Ks[cur ^ 1][srr][sc0]     = kreg0;
            *(bf16x8*)&Ks[cur ^ 1][srr][sc0 + 8] = kreg1;
#pragma unroll
            for (int jj = 0; jj < 8; jj++) {
                const unsigned int dw = ((unsigned int)(unsigned short)vreg0[jj]) |
                                        (((unsigned int)(unsigned short)vreg1[jj]) << 16);
                *(unsigned int*)&Vt[cur ^ 1][vcg * 8 + jj][vslot] = dw;
            }
        }
        if (kt + 2 <= qt) {
            const short* kp = (const short*)kg + base + (size_t)((kt + 2) * 64 + srr) * D_ + sc0;
            kreg0 = *(const bf16x8*)kp;
            kreg1 = *(const bf16x8*)(kp + 8);
            const short* vp = (const short*)vg + base + (size_t)((kt + 2) * 64 + kv0) * D_ + vcg * 8;
            vreg0 = *(const bf16x8*)vp;
            vreg1 = *(const bf16x8*)(vp + D_);
        }

        f32x4 s[4];
        __builtin_amdgcn_s_setprio(1);
#pragma unroll
        for (int cb = 0; cb < 4; cb++) {
            bf16x8 kf0 = *(const bf16x8*)&Ks[cur][cb * 16 + lr][lg * 8];
            bf16x8 kf1 = *(const bf16x8*)&Ks[cur][cb * 16 + lr][32 + lg * 8];
            f32x4 acc = (f32x4){0.f, 0.f, 0.f, 0.f};
            acc = __builtin_amdgcn_mfma_f32_16x16x32_bf16(kf0, qf0, acc, 0, 0, 0);
            acc = __builtin_amdgcn_mfma_f32_16x16x32_bf16(kf1, qf1, acc, 0, 0, 0);
            s[cb] = acc;
        }
        __builtin_amdgcn_s_setprio(0);

        if (kt == qt) {
#pragma unroll
            for (int cb = 0; cb < 4; cb++) {
#pragma unroll
                for (int r = 0; r < 4; r++) {
                    float sv = s[cb][r] * SCALE2;
                    if (kt * 64 + cb * 16 + lg * 4 + r > qrow_g) sv = -INFINITY;
                    s[cb][r] = sv;
                }
            }
        } else {
#pragma unroll
            for (int cb = 0; cb < 4; cb++)
#pragma unroll
                for (int r = 0; r < 4; r++) s[cb][r] *= SCALE2;
        }

        float rm = -INFINITY;
#pragma unroll
        for (int cb = 0; cb < 4; cb++)
#pragma unroll
            for (int r = 0; r < 4; r++) rm = fmaxf(rm, s[cb][r]);
        rm = fmaxf(rm, __shfl_xor(rm, 16));
        rm = fmaxf(rm, __shfl_xor(rm, 32));

        if (!__all(rm <= m_run + 8.0f)) {
            const float mnew = fmaxf(m_run, rm);
            const float fsc  = exp2f(m_run - mnew);
            m_run = mnew;
            l_run *= fsc;
            float fr[4];
#pragma unroll
            for (int r = 0; r < 4; r++) fr[r] = __shfl(fsc, lg * 4 + r);
#pragma unroll
            for (int db = 0; db < 4; db++)
#pragma unroll
                for (int r = 0; r < 4; r++) oacc[db][r] *= fr[r];
        }

        float p[4][4];
        float rs = 0.f;
#pragma unroll
        for (int cb = 0; cb < 4; cb++)
#pragma unroll
            for (int r = 0; r < 4; r++) {
                const float pv = exp2f(s[cb][r] - m_run);
                p[cb][r] = pv;
                rs += pv;
            }
        rs += __shfl_xor(rs, 16);
        rs += __shfl_xor(rs, 32);
        l_run += rs;

        bf16x8 pf0, pf1;
#pragma unroll
        for (int r = 0; r < 4; r++) {
            pf0[r]     = (short)f2b(p[0][r]);
            pf0[4 + r] = (short)f2b(p[1][r]);
            pf1[r]     = (short)f2b(p[2][r]);
            pf1[4 + r] = (short)f2b(p[3][r]);
        }

        __builtin_amdgcn_s_setprio(1);
#pragma unroll
        for (int db = 0; db < 4; db++) {
            bf16x8 vf0 = *(const bf16x8*)&Vt[cur][db * 16 + lr][lg * 8];
            bf16x8 vf1 = *(const bf16x8*)&Vt[cur][db * 16 + lr][32 + lg * 8];
            oacc[db] = __builtin_amdgcn_mfma_f32_16x16x32_bf16(pf0, vf0, oacc[db], 0, 0, 0);
            oacc[db] = __builtin_amdgcn_mfma_f32_16x16x32_bf16(pf1, vf1, oacc[db], 0, 0, 0);
        }
        __builtin_amdgcn_s_setprio(0);

        __syncthreads();
    }

#pragma unroll
    for (int r = 0; r < 4; r++) {
        const float lrow = __shfl(l_run, lg * 4 + r);
        const float inv = 1.0f / lrow;
        const int trow = qt * 64 + wave * 16 + lg * 4 + r;
        unsigned short* yp = y + (size_t)(b * T_ + trow) * C_ + h * D_;
#pragma unroll
        for (int db = 0; db < 4; db++)
            yp[db * 16 + lr] = f2b(oacc[db][r] * inv);
    }
}

// ---------------------------------------------------------------------------
extern "C" void kernel_launch(void* const* d_in, const int* in_sizes, int n_in,
                              void* d_out, int out_size, void* d_ws, size_t ws_size,
                              hipStream_t stream)
{
    const float* x       = (const float*)d_in[0];
    const float* Wqkv    = (const float*)d_in[1];
    const float* bqkv    = (const float*)d_in[2];
    const float* Wproj   = (const float*)d_in[3];
    const float* bproj   = (const float*)d_in[4];
    const float* Wrouter = (const float*)d_in[5];
    const float* brouter = (const float*)d_in[6];
    const float* Wq_rt   = (const float*)d_in[7];
    const float* bq_rt   = (const float*)d_in[8];

    float* out = (float*)d_out;
    char*  ws  = (char*)d_ws;

    const size_t MT  = (size_t)B_ * T_;
    const size_t QKV = MT * C_;

    unsigned short* xb   = (unsigned short*)ws;
    unsigned short* Wqt  = xb  + QKV;
    unsigned short* Wpt  = Wqt + (size_t)3 * C_ * C_;
    unsigned short* q    = Wpt + (size_t)C_ * C_;
    unsigned short* k    = q + QKV;
    unsigned short* v    = k + QKV;
    unsigned short* yab  = v + QKV;
    float* cm   = (float*)(yab + QKV);
    float* qrt  = cm  + (size_t)B_ * NCH * C_;
    float* ren  = qrt + MT * RD;

    float* y_out   = out;
    float* idx_out = out + QKV;
    float* sc_out  = idx_out + MT * TOPB;
    float* emb_out = sc_out + MT * NCH;

    // 0) casts / transposes
    cast_bf16_kernel<<<(int)(QKV / 8 / 256), 256, 0, stream>>>(x, xb, (int)(QKV / 8));
    transpose_cast_kernel<<<dim3(3 * C_ / 64, C_ / 64), 256, 0, stream>>>(Wqkv, Wqt, C_, 3 * C_);
    transpose_cast_kernel<<<dim3(C_ / 64, C_ / 64), 256, 0, stream>>>(Wproj, Wpt, C_, C_);

    // 1) qkv projection (MFMA, 2-phase) -> bf16 q,k,v [B,H,T,D]
    gemm_mfma<1><<<dim3(3 * C_ / 128, MT / 128), 256, 0, stream>>>(
        xb, Wqt, bqkv, nullptr, q, k, v, (int)MT, 3 * C_, C_);

    // 2) routing path (fp32)
    chunk_mean_kernel<<<dim3(B_ * NCH, 4), 256, 0, stream>>>(x, cm);
    rowgemm32<<<(B_ * NCH + 7) / 8, 256, 0, stream>>>(cm, Wrouter, brouter, emb_out, B_ * NCH, 0);
    l2norm_rows<<<(B_ * NCH + 7) / 8, 256, 0, stream>>>(emb_out, ren, B_ * NCH);
    qrt_kernel<<<(int)(MT / 4), 256, 0, stream>>>(x, Wq_rt, bq_rt, qrt);
    scores_topk<<<(int)(MT / 64), 64, 0, stream>>>(qrt, ren, sc_out, idx_out);

    // 3) MFMA flash attention -> bf16 ya [B,T,C]
    attn_mfma<<<dim3(1024), 256, 0, stream>>>(q, k, v, yab);

    // 4) output projection (MFMA, 2-phase) -> f32 y
    gemm_mfma<0><<<dim3(C_ / 128, MT / 128), 256, 0, stream>>>(
        yab, Wpt, bproj, y_out, nullptr, nullptr, nullptr, (int)MT, C_, C_);
}

// Round 10
// 197.917 us; speedup vs baseline: 1.3495x; 1.0585x over previous
//
#include <hip/hip_runtime.h>
#include <hip/hip_bf16.h>
#include <math.h>

#define B_   2
#define T_   2048
#define C_   1024
#define H_   16
#define D_   64
#define NCH  32
#define RD   32
#define TOPB 8

typedef __attribute__((ext_vector_type(8))) short bf16x8;
typedef __attribute__((ext_vector_type(4))) float f32x4;

static __device__ __forceinline__ unsigned short f2b(float f) {
    return __bfloat16_as_ushort(__float2bfloat16(f));
}

// ---------------------------------------------------------------------------
// cast x (f32) -> bf16, 8 elements per thread
// ---------------------------------------------------------------------------
__global__ __launch_bounds__(256) void cast_bf16_kernel(
    const float* __restrict__ in, unsigned short* __restrict__ out, int n8)
{
    const int i = blockIdx.x * blockDim.x + threadIdx.x;
    if (i >= n8) return;
    float4 a = ((const float4*)in)[i * 2];
    float4 b = ((const float4*)in)[i * 2 + 1];
    bf16x8 o;
    o[0] = (short)f2b(a.x); o[1] = (short)f2b(a.y);
    o[2] = (short)f2b(a.z); o[3] = (short)f2b(a.w);
    o[4] = (short)f2b(b.x); o[5] = (short)f2b(b.y);
    o[6] = (short)f2b(b.z); o[7] = (short)f2b(b.w);
    *(bf16x8*)&out[i * 8] = o;
}

// ---------------------------------------------------------------------------
// W [K][N] f32 -> Wt [N][K] bf16, 64x64 tiles via LDS
// ---------------------------------------------------------------------------
__global__ __launch_bounds__(256) void transpose_cast_kernel(
    const float* __restrict__ W, unsigned short* __restrict__ Wt, int K, int N)
{
    __shared__ float t[64][65];
    const int tid = threadIdx.x;
    const int n0 = blockIdx.x * 64, k0 = blockIdx.y * 64;
#pragma unroll
    for (int i = 0; i < 4; i++) {
        const int f = tid + i * 256;
        const int r = f >> 4, c4 = (f & 15) * 4;
        float4 v = *(const float4*)&W[(size_t)(k0 + r) * N + n0 + c4];
        t[r][c4 + 0] = v.x; t[r][c4 + 1] = v.y;
        t[r][c4 + 2] = v.z; t[r][c4 + 3] = v.w;
    }
    __syncthreads();
#pragma unroll
    for (int i = 0; i < 2; i++) {
        const int s = tid + i * 256;
        const int rn = s >> 3, ck8 = (s & 7) * 8;
        bf16x8 o;
#pragma unroll
        for (int j = 0; j < 8; j++) o[j] = (short)f2b(t[ck8 + j][rn]);
        *(bf16x8*)&Wt[(size_t)(n0 + rn) * K + k0 + ck8] = o;
    }
}

// ---------------------------------------------------------------------------
// qkv GEMM, 256x256 tile, BK=32, 8 waves, TRI-buffered LDS + counted vmcnt.
//  - stage t+2 while computing t; boundary = s_waitcnt vmcnt(4) + raw barrier
//    (loads get a full K-tile of flight; never drained to 0 mid-loop)
//  - LDS swizzle: byte ^= (((row&3)^((row>>2)&3))<<4)  [involution, bits 4-5,
//    inputs bits 6-9 untouched, 16B granule] -> frag reads 2 lanes/bank
//    applied as: linear gload_lds dest + pre-swizzled SOURCE + swizzled READ
//  - epilogue scatters to bf16 q/k/v [B,H,T,D]
// ---------------------------------------------------------------------------
__global__ __launch_bounds__(512, 1) void gemm_qkv_256(
    const unsigned short* __restrict__ A, const unsigned short* __restrict__ Bt,
    const float* __restrict__ bias,
    unsigned short* __restrict__ qp, unsigned short* __restrict__ kp,
    unsigned short* __restrict__ vp, int M, int N, int K)
{
    __shared__ unsigned short lds[3][2][8192];   // [slot][A|B][256 rows x 32 k]

    const int tid  = threadIdx.x;
    const int wid  = tid >> 6;
    const int lane = tid & 63;
    const int lr = lane & 15, lg = lane >> 4;
    const int wm = wid >> 2, wn = wid & 3;

    // XCD-bijective swizzle (192 blocks, 192 % 8 == 0), n-major grouping
    const int bid = blockIdx.x;
    const int swz = (bid & 7) * 24 + (bid >> 3);
    const int m0 = (swz & 15) << 8;
    const int n0 = (swz >> 4) << 8;

    // ---- staging addresses (per-lane source, wave-uniform LDS base) ----
    const int srow = tid >> 2;                                   // 0..127
    const int sswz = (((srow & 3) ^ ((srow >> 2) & 3)) << 4);
    const int skel = (((tid & 3) << 4) ^ sswz) >> 1;             // element k-ofs
    const unsigned short* gA0 = A  + (size_t)(m0 + srow) * K + skel;
    const unsigned short* gA1 = A  + (size_t)(m0 + srow + 128) * K + skel;
    const unsigned short* gB0 = Bt + (size_t)(n0 + srow) * K + skel;
    const unsigned short* gB1 = Bt + (size_t)(n0 + srow + 128) * K + skel;
    const int lb0 = (wid * 64) * 8;          // wave-uniform, elements
    const int lb1 = (wid * 64 + 512) * 8;

#define QSTAGE(sl, kofs)                                                          \
    __builtin_amdgcn_global_load_lds(                                             \
        (const __attribute__((address_space(1))) int*)(gA0 + (kofs)),             \
        (__attribute__((address_space(3))) int*)&lds[sl][0][lb0], 16, 0, 0);      \
    __builtin_amdgcn_global_load_lds(                                             \
        (const __attribute__((address_space(1))) int*)(gA1 + (kofs)),             \
        (__attribute__((address_space(3))) int*)&lds[sl][0][lb1], 16, 0, 0);      \
    __builtin_amdgcn_global_load_lds(                                             \
        (const __attribute__((address_space(1))) int*)(gB0 + (kofs)),             \
        (__attribute__((address_space(3))) int*)&lds[sl][1][lb0], 16, 0, 0);      \
    __builtin_amdgcn_global_load_lds(                                             \
        (const __attribute__((address_space(1))) int*)(gB1 + (kofs)),             \
        (__attribute__((address_space(3))) int*)&lds[sl][1][lb1], 16, 0, 0);

    // ---- fragment-read swizzle (row bits 0-1 = lr&3, bits 2-3 = (lr>>2)&3) ----
    const int rswz = (((lr & 3) ^ ((lr >> 2) & 3)) << 4);
    const int acol = (((lg << 4) ^ rswz) >> 1);                  // element k-ofs

    f32x4 acc[8][4];
#pragma unroll
    for (int i = 0; i < 8; i++)
#pragma unroll
        for (int j = 0; j < 4; j++) acc[i][j] = (f32x4){0.f, 0.f, 0.f, 0.f};

    const int nt = K >> 5;    // 32 K-tiles

    // prologue: stage tiles 0,1; wait tile 0 (vmcnt(4) leaves tile 1 in flight)
    QSTAGE(0, 0)
    QSTAGE(1, 32)
    asm volatile("s_waitcnt vmcnt(4)" ::: "memory");
    __builtin_amdgcn_s_barrier();

    int cur = 0;
    for (int t = 0; t < nt; ++t) {
        int s2 = cur + 2; if (s2 >= 3) s2 -= 3;
        if (t + 2 < nt) { QSTAGE(s2, (t + 2) << 5) }

        const unsigned short* sA = &lds[cur][0][0];
        const unsigned short* sB = &lds[cur][1][0];

        bf16x8 bfr[4];
#pragma unroll
        for (int ni = 0; ni < 4; ni++)
            bfr[ni] = *(const bf16x8*)&sB[(wn * 64 + ni * 16 + lr) * 32 + acol];

        __builtin_amdgcn_s_setprio(1);
#pragma unroll
        for (int mi = 0; mi < 8; mi++) {
            bf16x8 af = *(const bf16x8*)&sA[(wm * 128 + mi * 16 + lr) * 32 + acol];
#pragma unroll
            for (int ni = 0; ni < 4; ni++)
                acc[mi][ni] = __builtin_amdgcn_mfma_f32_16x16x32_bf16(
                    af, bfr[ni], acc[mi][ni], 0, 0, 0);
        }
        __builtin_amdgcn_s_setprio(0);

        if (t + 1 < nt) {
            if (t + 2 < nt) { asm volatile("s_waitcnt vmcnt(4)" ::: "memory"); }
            else            { asm volatile("s_waitcnt vmcnt(0)" ::: "memory"); }
            __builtin_amdgcn_s_barrier();
        }
        cur += 1; if (cur == 3) cur = 0;
    }
#undef QSTAGE

    // epilogue: scatter to q/k/v [B,H,T,D]
#pragma unroll
    for (int ni = 0; ni < 4; ni++) {
        const int col = n0 + wn * 64 + ni * 16 + lr;
        const float bv = bias[col];
        const int which = col >> 10;
        const int c  = col & 1023;
        const int hh = c >> 6;
        const int dd = c & 63;
        unsigned short* dst = (which == 0) ? qp : (which == 1) ? kp : vp;
#pragma unroll
        for (int mi = 0; mi < 8; mi++) {
#pragma unroll
            for (int r = 0; r < 4; r++) {
                const int row = m0 + wm * 128 + mi * 16 + lg * 4 + r;
                const int bb = row >> 11, tt = row & 2047;
                dst[(((size_t)bb * H_ + hh) * T_ + tt) * D_ + dd] =
                    f2b(acc[mi][ni][r] + bv);
            }
        }
    }
}

// ---------------------------------------------------------------------------
// bf16 MFMA GEMM, 2-phase pipelined 128x128 (proj path)
// ---------------------------------------------------------------------------
__global__ __launch_bounds__(256) void gemm_mfma_f32out(
    const unsigned short* __restrict__ A, const unsigned short* __restrict__ Bt,
    const float* __restrict__ bias, float* __restrict__ out, int M, int N, int K)
{
    __shared__ unsigned short As[2][128 * 32];
    __shared__ unsigned short Bs[2][128 * 32];

    const int tid  = threadIdx.x;
    const int lane = tid & 63;
    const int wave = tid >> 6;
    const int lr = lane & 15, lg = lane >> 4;
    const int wm = wave >> 1, wn = wave & 1;
    const int n0 = blockIdx.x * 128, m0 = blockIdx.y * 128;

    const int srow = tid >> 2;
    const int scol = (tid & 3) * 8;
    const unsigned short* ga = A  + (size_t)(m0 + srow) * K + scol;
    const unsigned short* gb = Bt + (size_t)(n0 + srow) * K + scol;
    const int ldst = (tid & 0xC0) * 8;

    f32x4 acc[4][4];
#pragma unroll
    for (int i = 0; i < 4; i++)
#pragma unroll
        for (int j = 0; j < 4; j++) acc[i][j] = (f32x4){0.f, 0.f, 0.f, 0.f};

#define GSTAGE(buf, k0)                                                        \
    _Pragma("unroll")                                                          \
    for (int i = 0; i < 2; i++) {                                              \
        __builtin_amdgcn_global_load_lds(                                      \
            (const __attribute__((address_space(1))) int*)(ga + (k0) + (size_t)i * 64 * K), \
            (__attribute__((address_space(3))) int*)&As[buf][i * 2048 + ldst], 16, 0, 0);   \
        __builtin_amdgcn_global_load_lds(                                      \
            (const __attribute__((address_space(1))) int*)(gb + (k0) + (size_t)i * 64 * K), \
            (__attribute__((address_space(3))) int*)&Bs[buf][i * 2048 + ldst], 16, 0, 0);   \
    }

    const int nt = K >> 5;
    GSTAGE(0, 0);
    __syncthreads();

    int cur = 0;
    for (int t = 0; t < nt; ++t) {
        if (t + 1 < nt) { GSTAGE(cur ^ 1, (t + 1) << 5); }

        bf16x8 af[4], bfr[4];
#pragma unroll
        for (int mi = 0; mi < 4; mi++)
            af[mi] = *(const bf16x8*)&As[cur][(wm * 64 + mi * 16 + lr) * 32 + lg * 8];
#pragma unroll
        for (int ni = 0; ni < 4; ni++)
            bfr[ni] = *(const bf16x8*)&Bs[cur][(wn * 64 + ni * 16 + lr) * 32 + lg * 8];
#pragma unroll
        for (int mi = 0; mi < 4; mi++)
#pragma unroll
            for (int ni = 0; ni < 4; ni++)
                acc[mi][ni] = __builtin_amdgcn_mfma_f32_16x16x32_bf16(
                    af[mi], bfr[ni], acc[mi][ni], 0, 0, 0);

        __syncthreads();
        cur ^= 1;
    }
#undef GSTAGE

#pragma unroll
    for (int ni = 0; ni < 4; ni++) {
        const int col = n0 + wn * 64 + ni * 16 + lr;
        const float bv = bias[col];
#pragma unroll
        for (int mi = 0; mi < 4; mi++) {
#pragma unroll
            for (int r = 0; r < 4; r++) {
                const int row = m0 + wm * 64 + mi * 16 + lg * 4 + r;
                out[(size_t)row * N + col] = acc[mi][ni][r] + bv;
            }
        }
    }
}

// ---------------------------------------------------------------------------
// chunk means: grid (64, 4) — one column per thread
// ---------------------------------------------------------------------------
__global__ void chunk_mean_kernel(const float* __restrict__ x, float* __restrict__ cm)
{
    const int bc = blockIdx.x;
    const int b = bc >> 5, n = bc & 31;
    const int c = blockIdx.y * 256 + threadIdx.x;
    const float* xp = x + ((size_t)b * T_ + n * 64) * C_;
    float s = 0.f;
    for (int i = 0; i < 64; i++) s += xp[(size_t)i * C_ + c];
    cm[(size_t)bc * C_ + c] = s * (1.0f / 64.0f);
}

// ---------------------------------------------------------------------------
// rowgemm32 / l2norm (64-row routing-embeds path)
// ---------------------------------------------------------------------------
__global__ void rowgemm32(const float* __restrict__ A, const float* __restrict__ W,
                          const float* __restrict__ bias, float* __restrict__ dst,
                          int M, int normalize)
{
    const int row  = blockIdx.x * 8 + (threadIdx.x >> 5);
    const int lane = threadIdx.x & 31;
    if (row >= M) return;
    const float* a = A + (size_t)row * C_;
    float acc = 0.f;
    for (int k = 0; k < C_; k += 4) {
        float4 a4 = *(const float4*)&a[k];
        acc += a4.x * W[(k + 0) * RD + lane];
        acc += a4.y * W[(k + 1) * RD + lane];
        acc += a4.z * W[(k + 2) * RD + lane];
        acc += a4.w * W[(k + 3) * RD + lane];
    }
    acc += bias[lane];
    if (normalize) {
        float ss = acc * acc;
#pragma unroll
        for (int off = 16; off >= 1; off >>= 1) ss += __shfl_xor(ss, off, 32);
        acc = acc / fmaxf(sqrtf(ss), 1e-12f);
    }
    dst[(size_t)row * RD + lane] = acc;
}

__global__ void l2norm_rows(const float* __restrict__ src, float* __restrict__ dst, int M)
{
    const int row  = blockIdx.x * 8 + (threadIdx.x >> 5);
    const int lane = threadIdx.x & 31;
    if (row >= M) return;
    float v = src[(size_t)row * RD + lane];
    float ss = v * v;
#pragma unroll
    for (int off = 16; off >= 1; off >>= 1) ss += __shfl_xor(ss, off, 32);
    dst[(size_t)row * RD + lane] = v / fmaxf(sqrtf(ss), 1e-12f);
}

// ---------------------------------------------------------------------------
// q_rt projection + l2norm (tall-skinny GEMM, latency-optimized)
// ---------------------------------------------------------------------------
__global__ __launch_bounds__(256) void qrt_kernel(
    const float* __restrict__ x, const float* __restrict__ W,
    const float* __restrict__ bias, float* __restrict__ dst)
{
    __shared__ float part[8][4][32];
    const int r0 = blockIdx.x * 4;
    const int g = threadIdx.x >> 5;
    const int n = threadIdx.x & 31;

    const float* w  = W + (size_t)(g * 128) * RD + n;
    const float* a0 = x + (size_t)(r0 + 0) * C_ + g * 128;
    const float* a1 = x + (size_t)(r0 + 1) * C_ + g * 128;
    const float* a2 = x + (size_t)(r0 + 2) * C_ + g * 128;
    const float* a3 = x + (size_t)(r0 + 3) * C_ + g * 128;

    float acc0 = 0.f, acc1 = 0.f, acc2 = 0.f, acc3 = 0.f;
#pragma unroll 8
    for (int i = 0; i < 128; i += 4) {
        const float w0 = w[(i + 0) * RD];
        const float w1 = w[(i + 1) * RD];
        const float w2 = w[(i + 2) * RD];
        const float w3 = w[(i + 3) * RD];
        float4 x0 = *(const float4*)&a0[i];
        float4 x1 = *(const float4*)&a1[i];
        float4 x2 = *(const float4*)&a2[i];
        float4 x3 = *(const float4*)&a3[i];
        acc0 += x0.x * w0; acc0 += x0.y * w1; acc0 += x0.z * w2; acc0 += x0.w * w3;
        acc1 += x1.x * w0; acc1 += x1.y * w1; acc1 += x1.z * w2; acc1 += x1.w * w3;
        acc2 += x2.x * w0; acc2 += x2.y * w1; acc2 += x2.z * w2; acc2 += x2.w * w3;
        acc3 += x3.x * w0; acc3 += x3.y * w1; acc3 += x3.z * w2; acc3 += x3.w * w3;
    }
    part[g][0][n] = acc0;
    part[g][1][n] = acc1;
    part[g][2][n] = acc2;
    part[g][3][n] = acc3;
    __syncthreads();

    if (g < 4) {
        float s = part[0][g][n];
#pragma unroll
        for (int gg = 1; gg < 8; gg++) s += part[gg][g][n];
        s += bias[n];
        float ss = s * s;
#pragma unroll
        for (int off = 16; off >= 1; off >>= 1) ss += __shfl_xor(ss, off, 32);
        dst[(size_t)(r0 + g) * RD + n] = s / fmaxf(sqrtf(ss), 1e-12f);
    }
}

// ---------------------------------------------------------------------------
// routing scores + top-8 (64 blocks x 64 threads)
// ---------------------------------------------------------------------------
__global__ void scores_topk(const float* __restrict__ qrt, const float* __restrict__ ren,
                            float* __restrict__ sc_out, float* __restrict__ idx_out)
{
    const int row = blockIdx.x * 64 + threadIdx.x;
    if (row >= B_ * T_) return;
    const int b = row / T_;
    float q[RD];
#pragma unroll
    for (int i = 0; i < RD; i++) q[i] = qrt[(size_t)row * RD + i];
    const float* rb = ren + (size_t)b * NCH * RD;
    float s[NCH];
#pragma unroll 4
    for (int n = 0; n < NCH; n++) {
        float acc = 0.f;
#pragma unroll
        for (int i = 0; i < RD; i++) acc += q[i] * rb[n * RD + i];
        s[n] = acc;
        sc_out[(size_t)row * NCH + n] = acc;
    }
    unsigned mask = 0;
    for (int t = 0; t < TOPB; t++) {
        float best = -INFINITY;
        int bi = 0;
#pragma unroll
        for (int n = 0; n < NCH; n++) {
            const bool ok = !((mask >> n) & 1u) && (s[n] > best);
            if (ok) { best = s[n]; bi = n; }
        }
        mask |= (1u << bi);
        idx_out[(size_t)row * TOPB + t] = (float)bi;
    }
}

// ---------------------------------------------------------------------------
// MFMA bf16 flash attention, v5: swapped QK^T + fully in-register softmax.
// ---------------------------------------------------------------------------
#define LSTR 68
#define SCALE2 0.18033688f   /* 0.125 * 1.44269504 */

__global__ __launch_bounds__(256) void attn_mfma(
    const unsigned short* __restrict__ qg, const unsigned short* __restrict__ kg,
    const unsigned short* __restrict__ vg, unsigned short* __restrict__ y)
{
    const int bid = blockIdx.x;
    const int xcd = bid & 7;
    const int j   = bid >> 3;
    const int h   = xcd + 8 * (j & 1);
    const int b   = (j >> 1) & 1;
    const int qt  = 31 - (j >> 2);

    const int tid  = threadIdx.x;
    const int wave = tid >> 6;
    const int lane = tid & 63;
    const int lg = lane >> 4;
    const int lr = lane & 15;

    __shared__ short Ks[2][64][LSTR];
    __shared__ short Vt[2][64][LSTR];

    const size_t base = ((size_t)(b * H_ + h) * T_) * D_;

    bf16x8 qf0, qf1;
    {
        const short* qp = (const short*)qg + base + (size_t)(qt * 64 + wave * 16 + lr) * D_;
        qf0 = *(const bf16x8*)&qp[lg * 8];
        qf1 = *(const bf16x8*)&qp[32 + lg * 8];
    }

    const int srr = tid >> 2;
    const int sc0 = (tid & 3) * 16;
    const int vrp = tid & 31;
    const int vcg = tid >> 5;
    const int kv0   = 2 * vrp;
    const int vslot = ((kv0 >> 5) << 5) + (((kv0 >> 2) & 3) << 3) +
                      (((kv0 >> 4) & 1) << 2) + (kv0 & 3);

    bf16x8 kreg0, kreg1, vreg0, vreg1;

    float m_run = -INFINITY, l_run = 0.f;
    f32x4 oacc[4];
#pragma unroll
    for (int r = 0; r < 4; r++) oacc[r] = (f32x4){0.f, 0.f, 0.f, 0.f};
    const int qrow_g = qt * 64 + wave * 16 + lr;

    {
        const short* kp = (const short*)kg + base + (size_t)srr * D_ + sc0;
        kreg0 = *(const bf16x8*)kp;
        kreg1 = *(const bf16x8*)(kp + 8);
        const short* vp = (const short*)vg + base + (size_t)kv0 * D_ + vcg * 8;
        vreg0 = *(const bf16x8*)vp;
        vreg1 = *(const bf16x8*)(vp + D_);
    }
    {
        *(bf16x8*)&Ks[0][srr][sc0]     = kreg0;
        *(bf16x8*)&Ks[0][srr][sc0 + 8] = kreg1;
#pragma unroll
        for (int jj = 0; jj < 8; jj++) {
            const unsigned int dw = ((unsigned int)(unsigned short)vreg0[jj]) |
                                    (((unsigned int)(unsigned short)vreg1[jj]) << 16);
            *(unsigned int*)&Vt[0][vcg * 8 + jj][vslot] = dw;
        }
    }
    if (qt >= 1) {
        const short* kp = (const short*)kg + base + (size_t)(64 + srr) * D_ + sc0;
        kreg0 = *(const bf16x8*)kp;
        kreg1 = *(const bf16x8*)(kp + 8);
        const short* vp = (const short*)vg + base + (size_t)(64 + kv0) * D_ + vcg * 8;
        vreg0 = *(const bf16x8*)vp;
        vreg1 = *(const bf16x8*)(vp + D_);
    }
    __syncthreads();

    for (int kt = 0; kt <= qt; ++kt) {
        const int cur = kt & 1;

        if (kt < qt) {
            *(bf16x8*)&Ks[cur ^ 1][srr][sc0]     = kreg0;
            *(bf16x8*)&Ks[cur ^ 1][srr][sc0 + 8] = kreg1;
#pragma unroll
            for (int jj = 0; jj < 8; jj++) {
                const unsigned int dw = ((unsigned int)(unsigned short)vreg0[jj]) |
                                        (((unsigned int)(unsigned short)vreg1[jj]) << 16);
                *(unsigned int*)&Vt[cur ^ 1][vcg * 8 + jj][vslot] = dw;
            }
        }
        if (kt + 2 <= qt) {
            const short* kp = (const short*)kg + base + (size_t)((kt + 2) * 64 + srr) * D_ + sc0;
            kreg0 = *(const bf16x8*)kp;
            kreg1 = *(const bf16x8*)(kp + 8);
            const short* vp = (const short*)vg + base + (size_t)((kt + 2) * 64 + kv0) * D_ + vcg * 8;
            vreg0 = *(const bf16x8*)vp;
            vreg1 = *(const bf16x8*)(vp + D_);
        }

        f32x4 s[4];
        __builtin_amdgcn_s_setprio(1);
#pragma unroll
        for (int cb = 0; cb < 4; cb++) {
            bf16x8 kf0 = *(const bf16x8*)&Ks[cur][cb * 16 + lr][lg * 8];
            bf16x8 kf1 = *(const bf16x8*)&Ks[cur][cb * 16 + lr][32 + lg * 8];
            f32x4 acc = (f32x4){0.f, 0.f, 0.f, 0.f};
            acc = __builtin_amdgcn_mfma_f32_16x16x32_bf16(kf0, qf0, acc, 0, 0, 0);
            acc = __builtin_amdgcn_mfma_f32_16x16x32_bf16(kf1, qf1, acc, 0, 0, 0);
            s[cb] = acc;
        }
        __builtin_amdgcn_s_setprio(0);

        if (kt == qt) {
#pragma unroll
            for (int cb = 0; cb < 4; cb++) {
#pragma unroll
                for (int r = 0; r < 4; r++) {
                    float sv = s[cb][r] * SCALE2;
                    if (kt * 64 + cb * 16 + lg * 4 + r > qrow_g) sv = -INFINITY;
                    s[cb][r] = sv;
                }
            }
        } else {
#pragma unroll
            for (int cb = 0; cb < 4; cb++)
#pragma unroll
                for (int r = 0; r < 4; r++) s[cb][r] *= SCALE2;
        }

        float rm = -INFINITY;
#pragma unroll
        for (int cb = 0; cb < 4; cb++)
#pragma unroll
            for (int r = 0; r < 4; r++) rm = fmaxf(rm, s[cb][r]);
        rm = fmaxf(rm, __shfl_xor(rm, 16));
        rm = fmaxf(rm, __shfl_xor(rm, 32));

        if (!__all(rm <= m_run + 8.0f)) {
            const float mnew = fmaxf(m_run, rm);
            const float fsc  = exp2f(m_run - mnew);
            m_run = mnew;
            l_run *= fsc;
            float fr[4];
#pragma unroll
            for (int r = 0; r < 4; r++) fr[r] = __shfl(fsc, lg * 4 + r);
#pragma unroll
            for (int db = 0; db < 4; db++)
#pragma unroll
                for (int r = 0; r < 4; r++) oacc[db][r] *= fr[r];
        }

        float p[4][4];
        float rs = 0.f;
#pragma unroll
        for (int cb = 0; cb < 4; cb++)
#pragma unroll
            for (int r = 0; r < 4; r++) {
                const float pv = exp2f(s[cb][r] - m_run);
                p[cb][r] = pv;
                rs += pv;
            }
        rs += __shfl_xor(rs, 16);
        rs += __shfl_xor(rs, 32);
        l_run += rs;

        bf16x8 pf0, pf1;
#pragma unroll
        for (int r = 0; r < 4; r++) {
            pf0[r]     = (short)f2b(p[0][r]);
            pf0[4 + r] = (short)f2b(p[1][r]);
            pf1[r]     = (short)f2b(p[2][r]);
            pf1[4 + r] = (short)f2b(p[3][r]);
        }

        __builtin_amdgcn_s_setprio(1);
#pragma unroll
        for (int db = 0; db < 4; db++) {
            bf16x8 vf0 = *(const bf16x8*)&Vt[cur][db * 16 + lr][lg * 8];
            bf16x8 vf1 = *(const bf16x8*)&Vt[cur][db * 16 + lr][32 + lg * 8];
            oacc[db] = __builtin_amdgcn_mfma_f32_16x16x32_bf16(pf0, vf0, oacc[db], 0, 0, 0);
            oacc[db] = __builtin_amdgcn_mfma_f32_16x16x32_bf16(pf1, vf1, oacc[db], 0, 0, 0);
        }
        __builtin_amdgcn_s_setprio(0);

        __syncthreads();
    }

#pragma unroll
    for (int r = 0; r < 4; r++) {
        const float lrow = __shfl(l_run, lg * 4 + r);
        const float inv = 1.0f / lrow;
        const int trow = qt * 64 + wave * 16 + lg * 4 + r;
        unsigned short* yp = y + (size_t)(b * T_ + trow) * C_ + h * D_;
#pragma unroll
        for (int db = 0; db < 4; db++)
            yp[db * 16 + lr] = f2b(oacc[db][r] * inv);
    }
}

// ---------------------------------------------------------------------------
extern "C" void kernel_launch(void* const* d_in, const int* in_sizes, int n_in,
                              void* d_out, int out_size, void* d_ws, size_t ws_size,
                              hipStream_t stream)
{
    const float* x       = (const float*)d_in[0];
    const float* Wqkv    = (const float*)d_in[1];
    const float* bqkv    = (const float*)d_in[2];
    const float* Wproj   = (const float*)d_in[3];
    const float* bproj   = (const float*)d_in[4];
    const float* Wrouter = (const float*)d_in[5];
    const float* brouter = (const float*)d_in[6];
    const float* Wq_rt   = (const float*)d_in[7];
    const float* bq_rt   = (const float*)d_in[8];

    float* out = (float*)d_out;
    char*  ws  = (char*)d_ws;

    const size_t MT  = (size_t)B_ * T_;
    const size_t QKV = MT * C_;

    unsigned short* xb   = (unsigned short*)ws;
    unsigned short* Wqt  = xb  + QKV;
    unsigned short* Wpt  = Wqt + (size_t)3 * C_ * C_;
    unsigned short* q    = Wpt + (size_t)C_ * C_;
    unsigned short* k    = q + QKV;
    unsigned short* v    = k + QKV;
    unsigned short* yab  = v + QKV;
    float* cm   = (float*)(yab + QKV);
    float* qrt  = cm  + (size_t)B_ * NCH * C_;
    float* ren  = qrt + MT * RD;

    float* y_out   = out;
    float* idx_out = out + QKV;
    float* sc_out  = idx_out + MT * TOPB;
    float* emb_out = sc_out + MT * NCH;

    // 0) casts / transposes
    cast_bf16_kernel<<<(int)(QKV / 8 / 256), 256, 0, stream>>>(x, xb, (int)(QKV / 8));
    transpose_cast_kernel<<<dim3(3 * C_ / 64, C_ / 64), 256, 0, stream>>>(Wqkv, Wqt, C_, 3 * C_);
    transpose_cast_kernel<<<dim3(C_ / 64, C_ / 64), 256, 0, stream>>>(Wproj, Wpt, C_, C_);

    // 1) qkv projection: 256^2 tri-buffered counted-vmcnt MFMA GEMM
    gemm_qkv_256<<<dim3(192), 512, 0, stream>>>(
        xb, Wqt, bqkv, q, k, v, (int)MT, 3 * C_, C_);

    // 2) routing path (fp32)
    chunk_mean_kernel<<<dim3(B_ * NCH, 4), 256, 0, stream>>>(x, cm);
    rowgemm32<<<(B_ * NCH + 7) / 8, 256, 0, stream>>>(cm, Wrouter, brouter, emb_out, B_ * NCH, 0);
    l2norm_rows<<<(B_ * NCH + 7) / 8, 256, 0, stream>>>(emb_out, ren, B_ * NCH);
    qrt_kernel<<<(int)(MT / 4), 256, 0, stream>>>(x, Wq_rt, bq_rt, qrt);
    scores_topk<<<(int)(MT / 64), 64, 0, stream>>>(qrt, ren, sc_out, idx_out);

    // 3) MFMA flash attention -> bf16 ya [B,T,C]
    attn_mfma<<<dim3(1024), 256, 0, stream>>>(q, k, v, yab);

    // 4) output projection (MFMA, 2-phase) -> f32 y
    gemm_mfma_f32out<<<dim3(C_ / 128, MT / 128), 256, 0, stream>>>(
        yab, Wpt, bproj, y_out, (int)MT, C_, C_);
}

// Round 11
// 186.770 us; speedup vs baseline: 1.4300x; 1.0597x over previous
//
#include <hip/hip_runtime.h>
#include <hip/hip_bf16.h>
#include <math.h>

#define B_   2
#define T_   2048
#define C_   1024
#define H_   16
#define D_   64
#define NCH  32
#define RD   32
#define TOPB 8

typedef __attribute__((ext_vector_type(8))) short bf16x8;
typedef __attribute__((ext_vector_type(4))) float f32x4;

static __device__ __forceinline__ unsigned short f2b(float f) {
    return __bfloat16_as_ushort(__float2bfloat16(f));
}

#define SCALE2 0.18033688f   /* 0.125 * 1.44269504 (log2 domain) */

// ---------------------------------------------------------------------------
// prep_fused: all input-only preprocessing in ONE kernel (role by block range)
//   [0,2048)      cast x -> bf16
//   [2048,2816)   Wqkv [K][3072] -> Wqt [3072][K] bf16
//   [2816,3072)   Wproj [K][1024] -> Wpt [1024][K] bf16
//   [3072,4096)   qrt = l2norm(x @ Wq_rt + b)        (routing queries)
//   [4096,4352)   chunk means cm[B*NCH][C]
// ---------------------------------------------------------------------------
__global__ __launch_bounds__(256) void prep_fused(
    const float* __restrict__ x, unsigned short* __restrict__ xb,
    const float* __restrict__ Wqkv, unsigned short* __restrict__ Wqt,
    const float* __restrict__ Wproj, unsigned short* __restrict__ Wpt,
    const float* __restrict__ Wq_rt, const float* __restrict__ bq_rt,
    float* __restrict__ qrt, float* __restrict__ cm)
{
    __shared__ float smem[64 * 65];
    const int bid = blockIdx.x;
    const int tid = threadIdx.x;

    if (bid < 2048) {                      // ---- cast x -> bf16
        const int i = bid * 256 + tid;
        float4 a = ((const float4*)x)[i * 2];
        float4 b = ((const float4*)x)[i * 2 + 1];
        bf16x8 o;
        o[0] = (short)f2b(a.x); o[1] = (short)f2b(a.y);
        o[2] = (short)f2b(a.z); o[3] = (short)f2b(a.w);
        o[4] = (short)f2b(b.x); o[5] = (short)f2b(b.y);
        o[6] = (short)f2b(b.z); o[7] = (short)f2b(b.w);
        *(bf16x8*)&xb[(size_t)i * 8] = o;
    } else if (bid < 3072) {               // ---- weight transpose+cast
        const float* W; unsigned short* Wt; int N, local;
        if (bid < 2816) { W = Wqkv;  Wt = Wqt; N = 3072; local = bid - 2048; }
        else            { W = Wproj; Wt = Wpt; N = 1024; local = bid - 2816; }
        const int nblk = N >> 6;
        const int n0 = (local % nblk) * 64, k0 = (local / nblk) * 64;
        float (*t)[65] = (float(*)[65])smem;
#pragma unroll
        for (int i = 0; i < 4; i++) {
            const int f = tid + i * 256;
            const int r = f >> 4, c4 = (f & 15) * 4;
            float4 v = *(const float4*)&W[(size_t)(k0 + r) * N + n0 + c4];
            t[r][c4 + 0] = v.x; t[r][c4 + 1] = v.y;
            t[r][c4 + 2] = v.z; t[r][c4 + 3] = v.w;
        }
        __syncthreads();
#pragma unroll
        for (int i = 0; i < 2; i++) {
            const int s = tid + i * 256;
            const int rn = s >> 3, ck8 = (s & 7) * 8;
            bf16x8 o;
#pragma unroll
            for (int j = 0; j < 8; j++) o[j] = (short)f2b(t[ck8 + j][rn]);
            *(bf16x8*)&Wt[(size_t)(n0 + rn) * 1024 + k0 + ck8] = o;
        }
    } else if (bid < 4096) {               // ---- qrt projection + l2norm
        float (*part)[4][32] = (float(*)[4][32])smem;
        const int r0 = (bid - 3072) * 4;
        const int g = tid >> 5;
        const int n = tid & 31;
        const float* w  = Wq_rt + (size_t)(g * 128) * RD + n;
        const float* a0 = x + (size_t)(r0 + 0) * C_ + g * 128;
        const float* a1 = x + (size_t)(r0 + 1) * C_ + g * 128;
        const float* a2 = x + (size_t)(r0 + 2) * C_ + g * 128;
        const float* a3 = x + (size_t)(r0 + 3) * C_ + g * 128;
        float acc0 = 0.f, acc1 = 0.f, acc2 = 0.f, acc3 = 0.f;
#pragma unroll 8
        for (int i = 0; i < 128; i += 4) {
            const float w0 = w[(i + 0) * RD];
            const float w1 = w[(i + 1) * RD];
            const float w2 = w[(i + 2) * RD];
            const float w3 = w[(i + 3) * RD];
            float4 x0 = *(const float4*)&a0[i];
            float4 x1 = *(const float4*)&a1[i];
            float4 x2 = *(const float4*)&a2[i];
            float4 x3 = *(const float4*)&a3[i];
            acc0 += x0.x * w0; acc0 += x0.y * w1; acc0 += x0.z * w2; acc0 += x0.w * w3;
            acc1 += x1.x * w0; acc1 += x1.y * w1; acc1 += x1.z * w2; acc1 += x1.w * w3;
            acc2 += x2.x * w0; acc2 += x2.y * w1; acc2 += x2.z * w2; acc2 += x2.w * w3;
            acc3 += x3.x * w0; acc3 += x3.y * w1; acc3 += x3.z * w2; acc3 += x3.w * w3;
        }
        part[g][0][n] = acc0;
        part[g][1][n] = acc1;
        part[g][2][n] = acc2;
        part[g][3][n] = acc3;
        __syncthreads();
        if (g < 4) {
            float s = part[0][g][n];
#pragma unroll
            for (int gg = 1; gg < 8; gg++) s += part[gg][g][n];
            s += bq_rt[n];
            float ss = s * s;
#pragma unroll
            for (int off = 16; off >= 1; off >>= 1) ss += __shfl_xor(ss, off, 32);
            qrt[(size_t)(r0 + g) * RD + n] = s / fmaxf(sqrtf(ss), 1e-12f);
        }
    } else {                               // ---- chunk means
        const int local = bid - 4096;
        const int bc = local & 63;
        const int b = bc >> 5, n = bc & 31;
        const int c = (local >> 6) * 256 + tid;
        const float* xp = x + ((size_t)b * T_ + n * 64) * C_;
        float s = 0.f;
        for (int i = 0; i < 64; i++) s += xp[(size_t)i * C_ + c];
        cm[(size_t)bc * C_ + c] = s * (1.0f / 64.0f);
    }
}

// ---------------------------------------------------------------------------
// routing embeds + l2norm fused: emb_out (raw) and ren (normalized)
// ---------------------------------------------------------------------------
__global__ void embeds_kernel(const float* __restrict__ cm, const float* __restrict__ W,
                              const float* __restrict__ bias,
                              float* __restrict__ emb_out, float* __restrict__ ren)
{
    const int row  = blockIdx.x * 8 + (threadIdx.x >> 5);
    const int lane = threadIdx.x & 31;
    if (row >= B_ * NCH) return;
    const float* a = cm + (size_t)row * C_;
    float acc = 0.f;
    for (int k = 0; k < C_; k += 4) {
        float4 a4 = *(const float4*)&a[k];
        acc += a4.x * W[(k + 0) * RD + lane];
        acc += a4.y * W[(k + 1) * RD + lane];
        acc += a4.z * W[(k + 2) * RD + lane];
        acc += a4.w * W[(k + 3) * RD + lane];
    }
    acc += bias[lane];
    emb_out[(size_t)row * RD + lane] = acc;
    float ss = acc * acc;
#pragma unroll
    for (int off = 16; off >= 1; off >>= 1) ss += __shfl_xor(ss, off, 32);
    ren[(size_t)row * RD + lane] = acc / fmaxf(sqrtf(ss), 1e-12f);
}

// ---------------------------------------------------------------------------
// qkv GEMM, 256x256 tile, tri-buffered LDS + counted vmcnt (R10 structure).
// Q output pre-scaled by SCALE2 (log2-domain attention scale).
// ---------------------------------------------------------------------------
__global__ __launch_bounds__(512, 1) void gemm_qkv_256(
    const unsigned short* __restrict__ A, const unsigned short* __restrict__ Bt,
    const float* __restrict__ bias,
    unsigned short* __restrict__ qp, unsigned short* __restrict__ kp,
    unsigned short* __restrict__ vp, int M, int N, int K)
{
    __shared__ unsigned short lds[3][2][8192];

    const int tid  = threadIdx.x;
    const int wid  = tid >> 6;
    const int lane = tid & 63;
    const int lr = lane & 15, lg = lane >> 4;
    const int wm = wid >> 2, wn = wid & 3;

    const int bid = blockIdx.x;
    const int swz = (bid & 7) * 24 + (bid >> 3);
    const int m0 = (swz & 15) << 8;
    const int n0 = (swz >> 4) << 8;

    const int srow = tid >> 2;
    const int sswz = (((srow & 3) ^ ((srow >> 2) & 3)) << 4);
    const int skel = (((tid & 3) << 4) ^ sswz) >> 1;
    const unsigned short* gA0 = A  + (size_t)(m0 + srow) * K + skel;
    const unsigned short* gA1 = A  + (size_t)(m0 + srow + 128) * K + skel;
    const unsigned short* gB0 = Bt + (size_t)(n0 + srow) * K + skel;
    const unsigned short* gB1 = Bt + (size_t)(n0 + srow + 128) * K + skel;
    const int lb0 = (wid * 64) * 8;
    const int lb1 = (wid * 64 + 512) * 8;

#define QSTAGE(sl, kofs)                                                          \
    __builtin_amdgcn_global_load_lds(                                             \
        (const __attribute__((address_space(1))) int*)(gA0 + (kofs)),             \
        (__attribute__((address_space(3))) int*)&lds[sl][0][lb0], 16, 0, 0);      \
    __builtin_amdgcn_global_load_lds(                                             \
        (const __attribute__((address_space(1))) int*)(gA1 + (kofs)),             \
        (__attribute__((address_space(3))) int*)&lds[sl][0][lb1], 16, 0, 0);      \
    __builtin_amdgcn_global_load_lds(                                             \
        (const __attribute__((address_space(1))) int*)(gB0 + (kofs)),             \
        (__attribute__((address_space(3))) int*)&lds[sl][1][lb0], 16, 0, 0);      \
    __builtin_amdgcn_global_load_lds(                                             \
        (const __attribute__((address_space(1))) int*)(gB1 + (kofs)),             \
        (__attribute__((address_space(3))) int*)&lds[sl][1][lb1], 16, 0, 0);

    const int rswz = (((lr & 3) ^ ((lr >> 2) & 3)) << 4);
    const int acol = (((lg << 4) ^ rswz) >> 1);

    f32x4 acc[8][4];
#pragma unroll
    for (int i = 0; i < 8; i++)
#pragma unroll
        for (int j = 0; j < 4; j++) acc[i][j] = (f32x4){0.f, 0.f, 0.f, 0.f};

    const int nt = K >> 5;

    QSTAGE(0, 0)
    QSTAGE(1, 32)
    asm volatile("s_waitcnt vmcnt(4)" ::: "memory");
    __builtin_amdgcn_s_barrier();

    int cur = 0;
    for (int t = 0; t < nt; ++t) {
        int s2 = cur + 2; if (s2 >= 3) s2 -= 3;
        if (t + 2 < nt) { QSTAGE(s2, (t + 2) << 5) }

        const unsigned short* sA = &lds[cur][0][0];
        const unsigned short* sB = &lds[cur][1][0];

        bf16x8 bfr[4];
#pragma unroll
        for (int ni = 0; ni < 4; ni++)
            bfr[ni] = *(const bf16x8*)&sB[(wn * 64 + ni * 16 + lr) * 32 + acol];

        __builtin_amdgcn_s_setprio(1);
#pragma unroll
        for (int mi = 0; mi < 8; mi++) {
            bf16x8 af = *(const bf16x8*)&sA[(wm * 128 + mi * 16 + lr) * 32 + acol];
#pragma unroll
            for (int ni = 0; ni < 4; ni++)
                acc[mi][ni] = __builtin_amdgcn_mfma_f32_16x16x32_bf16(
                    af, bfr[ni], acc[mi][ni], 0, 0, 0);
        }
        __builtin_amdgcn_s_setprio(0);

        if (t + 1 < nt) {
            if (t + 2 < nt) { asm volatile("s_waitcnt vmcnt(4)" ::: "memory"); }
            else            { asm volatile("s_waitcnt vmcnt(0)" ::: "memory"); }
            __builtin_amdgcn_s_barrier();
        }
        cur += 1; if (cur == 3) cur = 0;
    }
#undef QSTAGE

#pragma unroll
    for (int ni = 0; ni < 4; ni++) {
        const int col = n0 + wn * 64 + ni * 16 + lr;
        const float bv = bias[col];
        const int which = col >> 10;
        const int c  = col & 1023;
        const int hh = c >> 6;
        const int dd = c & 63;
        unsigned short* dst = (which == 0) ? qp : (which == 1) ? kp : vp;
        const float postmul = (which == 0) ? SCALE2 : 1.0f;   // pre-scale Q
#pragma unroll
        for (int mi = 0; mi < 8; mi++) {
#pragma unroll
            for (int r = 0; r < 4; r++) {
                const int row = m0 + wm * 128 + mi * 16 + lg * 4 + r;
                const int bb = row >> 11, tt = row & 2047;
                dst[(((size_t)bb * H_ + hh) * T_ + tt) * D_ + dd] =
                    f2b((acc[mi][ni][r] + bv) * postmul);
            }
        }
    }
}

// ---------------------------------------------------------------------------
// proj GEMM, 128x128 2-phase pipelined
// ---------------------------------------------------------------------------
__global__ __launch_bounds__(256) void gemm_mfma_f32out(
    const unsigned short* __restrict__ A, const unsigned short* __restrict__ Bt,
    const float* __restrict__ bias, float* __restrict__ out, int M, int N, int K)
{
    __shared__ unsigned short As[2][128 * 32];
    __shared__ unsigned short Bs[2][128 * 32];

    const int tid  = threadIdx.x;
    const int lane = tid & 63;
    const int wave = tid >> 6;
    const int lr = lane & 15, lg = lane >> 4;
    const int wm = wave >> 1, wn = wave & 1;
    const int n0 = blockIdx.x * 128, m0 = blockIdx.y * 128;

    const int srow = tid >> 2;
    const int scol = (tid & 3) * 8;
    const unsigned short* ga = A  + (size_t)(m0 + srow) * K + scol;
    const unsigned short* gb = Bt + (size_t)(n0 + srow) * K + scol;
    const int ldst = (tid & 0xC0) * 8;

    f32x4 acc[4][4];
#pragma unroll
    for (int i = 0; i < 4; i++)
#pragma unroll
        for (int j = 0; j < 4; j++) acc[i][j] = (f32x4){0.f, 0.f, 0.f, 0.f};

#define GSTAGE(buf, k0)                                                        \
    _Pragma("unroll")                                                          \
    for (int i = 0; i < 2; i++) {                                              \
        __builtin_amdgcn_global_load_lds(                                      \
            (const __attribute__((address_space(1))) int*)(ga + (k0) + (size_t)i * 64 * K), \
            (__attribute__((address_space(3))) int*)&As[buf][i * 2048 + ldst], 16, 0, 0);   \
        __builtin_amdgcn_global_load_lds(                                      \
            (const __attribute__((address_space(1))) int*)(gb + (k0) + (size_t)i * 64 * K), \
            (__attribute__((address_space(3))) int*)&Bs[buf][i * 2048 + ldst], 16, 0, 0);   \
    }

    const int nt = K >> 5;
    GSTAGE(0, 0);
    __syncthreads();

    int cur = 0;
    for (int t = 0; t < nt; ++t) {
        if (t + 1 < nt) { GSTAGE(cur ^ 1, (t + 1) << 5); }

        bf16x8 af[4], bfr[4];
#pragma unroll
        for (int mi = 0; mi < 4; mi++)
            af[mi] = *(const bf16x8*)&As[cur][(wm * 64 + mi * 16 + lr) * 32 + lg * 8];
#pragma unroll
        for (int ni = 0; ni < 4; ni++)
            bfr[ni] = *(const bf16x8*)&Bs[cur][(wn * 64 + ni * 16 + lr) * 32 + lg * 8];
#pragma unroll
        for (int mi = 0; mi < 4; mi++)
#pragma unroll
            for (int ni = 0; ni < 4; ni++)
                acc[mi][ni] = __builtin_amdgcn_mfma_f32_16x16x32_bf16(
                    af[mi], bfr[ni], acc[mi][ni], 0, 0, 0);

        __syncthreads();
        cur ^= 1;
    }
#undef GSTAGE

#pragma unroll
    for (int ni = 0; ni < 4; ni++) {
        const int col = n0 + wn * 64 + ni * 16 + lr;
        const float bv = bias[col];
#pragma unroll
        for (int mi = 0; mi < 4; mi++) {
#pragma unroll
            for (int r = 0; r < 4; r++) {
                const int row = m0 + wm * 64 + mi * 16 + lg * 4 + r;
                out[(size_t)row * N + col] = acc[mi][ni][r] + bv;
            }
        }
    }
}

// ---------------------------------------------------------------------------
// routing scores + top-8
// ---------------------------------------------------------------------------
__global__ void scores_topk(const float* __restrict__ qrt, const float* __restrict__ ren,
                            float* __restrict__ sc_out, float* __restrict__ idx_out)
{
    const int row = blockIdx.x * 64 + threadIdx.x;
    if (row >= B_ * T_) return;
    const int b = row / T_;
    float q[RD];
#pragma unroll
    for (int i = 0; i < RD; i++) q[i] = qrt[(size_t)row * RD + i];
    const float* rb = ren + (size_t)b * NCH * RD;
    float s[NCH];
#pragma unroll 4
    for (int n = 0; n < NCH; n++) {
        float acc = 0.f;
#pragma unroll
        for (int i = 0; i < RD; i++) acc += q[i] * rb[n * RD + i];
        s[n] = acc;
        sc_out[(size_t)row * NCH + n] = acc;
    }
    unsigned mask = 0;
    for (int t = 0; t < TOPB; t++) {
        float best = -INFINITY;
        int bi = 0;
#pragma unroll
        for (int n = 0; n < NCH; n++) {
            const bool ok = !((mask >> n) & 1u) && (s[n] > best);
            if (ok) { best = s[n]; bi = n; }
        }
        mask |= (1u << bi);
        idx_out[(size_t)row * TOPB + t] = (float)bi;
    }
}

// ---------------------------------------------------------------------------
// MFMA bf16 flash attention v6: VALU diet.
//  - Q pre-scaled (no per-element scale mul)
//  - tree reductions for row max / row sum (depth 4)
//  - V pack via v_perm_b32 (1 op per dword)
// ---------------------------------------------------------------------------
#define LSTR 68

__global__ __launch_bounds__(256) void attn_mfma(
    const unsigned short* __restrict__ qg, const unsigned short* __restrict__ kg,
    const unsigned short* __restrict__ vg, unsigned short* __restrict__ y)
{
    const int bid = blockIdx.x;
    const int xcd = bid & 7;
    const int j   = bid >> 3;
    const int h   = xcd + 8 * (j & 1);
    const int b   = (j >> 1) & 1;
    const int qt  = 31 - (j >> 2);

    const int tid  = threadIdx.x;
    const int wave = tid >> 6;
    const int lane = tid & 63;
    const int lg = lane >> 4;
    const int lr = lane & 15;

    __shared__ short Ks[2][64][LSTR];
    __shared__ short Vt[2][64][LSTR];

    const size_t base = ((size_t)(b * H_ + h) * T_) * D_;

    bf16x8 qf0, qf1;
    {
        const short* qp = (const short*)qg + base + (size_t)(qt * 64 + wave * 16 + lr) * D_;
        qf0 = *(const bf16x8*)&qp[lg * 8];
        qf1 = *(const bf16x8*)&qp[32 + lg * 8];
    }

    const int srr = tid >> 2;
    const int sc0 = (tid & 3) * 16;
    const int vrp = tid & 31;
    const int vcg = tid >> 5;
    const int kv0   = 2 * vrp;
    const int vslot = ((kv0 >> 5) << 5) + (((kv0 >> 2) & 3) << 3) +
                      (((kv0 >> 4) & 1) << 2) + (kv0 & 3);

    bf16x8 kreg0, kreg1, vreg0, vreg1;

    float m_run = -INFINITY, l_run = 0.f;
    f32x4 oacc[4];
#pragma unroll
    for (int r = 0; r < 4; r++) oacc[r] = (f32x4){0.f, 0.f, 0.f, 0.f};
    const int qrow_g = qt * 64 + wave * 16 + lr;

#define VPACK(buf)                                                              \
    {                                                                           \
        const unsigned* v0d = (const unsigned*)&vreg0;                          \
        const unsigned* v1d = (const unsigned*)&vreg1;                          \
        _Pragma("unroll")                                                       \
        for (int jj = 0; jj < 8; jj++) {                                        \
            const unsigned sel = (jj & 1) ? 0x07060302u : 0x05040100u;          \
            const unsigned dw = __builtin_amdgcn_perm(v1d[jj >> 1], v0d[jj >> 1], sel); \
            *(unsigned*)&Vt[buf][vcg * 8 + jj][vslot] = dw;                     \
        }                                                                       \
    }

    {
        const short* kp = (const short*)kg + base + (size_t)srr * D_ + sc0;
        kreg0 = *(const bf16x8*)kp;
        kreg1 = *(const bf16x8*)(kp + 8);
        const short* vp = (const short*)vg + base + (size_t)kv0 * D_ + vcg * 8;
        vreg0 = *(const bf16x8*)vp;
        vreg1 = *(const bf16x8*)(vp + D_);
    }
    {
        *(bf16x8*)&Ks[0][srr][sc0]     = kreg0;
        *(bf16x8*)&Ks[0][srr][sc0 + 8] = kreg1;
        VPACK(0)
    }
    if (qt >= 1) {
        const short* kp = (const short*)kg + base + (size_t)(64 + srr) * D_ + sc0;
        kreg0 = *(const bf16x8*)kp;
        kreg1 = *(const bf16x8*)(kp + 8);
        const short* vp = (const short*)vg + base + (size_t)(64 + kv0) * D_ + vcg * 8;
        vreg0 = *(const bf16x8*)vp;
        vreg1 = *(const bf16x8*)(vp + D_);
    }
    __syncthreads();

    for (int kt = 0; kt <= qt; ++kt) {
        const int cur = kt & 1;

        if (kt < qt) {
            *(bf16x8*)&Ks[cur ^ 1][srr][sc0]     = kreg0;
            *(bf16x8*)&Ks[cur ^ 1][srr][sc0 + 8] = kreg1;
            VPACK(cur ^ 1)
        }
        if (kt + 2 <= qt) {
            const short* kp = (const short*)kg + base + (size_t)((kt + 2) * 64 + srr) * D_ + sc0;
            kreg0 = *(const bf16x8*)kp;
            kreg1 = *(const bf16x8*)(kp + 8);
            const short* vp = (const short*)vg + base + (size_t)((kt + 2) * 64 + kv0) * D_ + vcg * 8;
            vreg0 = *(const bf16x8*)vp;
            vreg1 = *(const bf16x8*)(vp + D_);
        }

        // S^T = K @ Q^T (Q pre-scaled, log2 domain)
        f32x4 s[4];
        __builtin_amdgcn_s_setprio(1);
#pragma unroll
        for (int cb = 0; cb < 4; cb++) {
            bf16x8 kf0 = *(const bf16x8*)&Ks[cur][cb * 16 + lr][lg * 8];
            bf16x8 kf1 = *(const bf16x8*)&Ks[cur][cb * 16 + lr][32 + lg * 8];
            f32x4 acc = (f32x4){0.f, 0.f, 0.f, 0.f};
            acc = __builtin_amdgcn_mfma_f32_16x16x32_bf16(kf0, qf0, acc, 0, 0, 0);
            acc = __builtin_amdgcn_mfma_f32_16x16x32_bf16(kf1, qf1, acc, 0, 0, 0);
            s[cb] = acc;
        }
        __builtin_amdgcn_s_setprio(0);

        // causal mask, diagonal tile only (no scale needed)
        if (kt == qt) {
#pragma unroll
            for (int cb = 0; cb < 4; cb++)
#pragma unroll
                for (int r = 0; r < 4; r++)
                    if (kt * 64 + cb * 16 + lg * 4 + r > qrow_g) s[cb][r] = -INFINITY;
        }

        // row max (tree, depth 4) + 2 shuffles
        float rm;
        {
            const float t0 = fmaxf(fmaxf(s[0][0], s[0][1]), fmaxf(s[0][2], s[0][3]));
            const float t1 = fmaxf(fmaxf(s[1][0], s[1][1]), fmaxf(s[1][2], s[1][3]));
            const float t2 = fmaxf(fmaxf(s[2][0], s[2][1]), fmaxf(s[2][2], s[2][3]));
            const float t3 = fmaxf(fmaxf(s[3][0], s[3][1]), fmaxf(s[3][2], s[3][3]));
            rm = fmaxf(fmaxf(t0, t1), fmaxf(t2, t3));
        }
        rm = fmaxf(rm, __shfl_xor(rm, 16));
        rm = fmaxf(rm, __shfl_xor(rm, 32));

        // defer-max (THR=8 log2 units)
        if (!__all(rm <= m_run + 8.0f)) {
            const float mnew = fmaxf(m_run, rm);
            const float fsc  = exp2f(m_run - mnew);
            m_run = mnew;
            l_run *= fsc;
            float fr[4];
#pragma unroll
            for (int r = 0; r < 4; r++) fr[r] = __shfl(fsc, lg * 4 + r);
#pragma unroll
            for (int db = 0; db < 4; db++)
#pragma unroll
                for (int r = 0; r < 4; r++) oacc[db][r] *= fr[r];
        }

        // P = exp2(S - m); tree row-sum
        float p[4][4];
#pragma unroll
        for (int cb = 0; cb < 4; cb++)
#pragma unroll
            for (int r = 0; r < 4; r++)
                p[cb][r] = exp2f(s[cb][r] - m_run);
        float rs;
        {
            const float t0 = (p[0][0] + p[0][1]) + (p[0][2] + p[0][3]);
            const float t1 = (p[1][0] + p[1][1]) + (p[1][2] + p[1][3]);
            const float t2 = (p[2][0] + p[2][1]) + (p[2][2] + p[2][3]);
            const float t3 = (p[3][0] + p[3][1]) + (p[3][2] + p[3][3]);
            rs = (t0 + t1) + (t2 + t3);
        }
        rs += __shfl_xor(rs, 16);
        rs += __shfl_xor(rs, 32);
        l_run += rs;

        bf16x8 pf0, pf1;
#pragma unroll
        for (int r = 0; r < 4; r++) {
            pf0[r]     = (short)f2b(p[0][r]);
            pf0[4 + r] = (short)f2b(p[1][r]);
            pf1[r]     = (short)f2b(p[2][r]);
            pf1[4 + r] = (short)f2b(p[3][r]);
        }

        __builtin_amdgcn_s_setprio(1);
#pragma unroll
        for (int db = 0; db < 4; db++) {
            bf16x8 vf0 = *(const bf16x8*)&Vt[cur][db * 16 + lr][lg * 8];
            bf16x8 vf1 = *(const bf16x8*)&Vt[cur][db * 16 + lr][32 + lg * 8];
            oacc[db] = __builtin_amdgcn_mfma_f32_16x16x32_bf16(pf0, vf0, oacc[db], 0, 0, 0);
            oacc[db] = __builtin_amdgcn_mfma_f32_16x16x32_bf16(pf1, vf1, oacc[db], 0, 0, 0);
        }
        __builtin_amdgcn_s_setprio(0);

        __syncthreads();
    }
#undef VPACK

#pragma unroll
    for (int r = 0; r < 4; r++) {
        const float lrow = __shfl(l_run, lg * 4 + r);
        const float inv = 1.0f / lrow;
        const int trow = qt * 64 + wave * 16 + lg * 4 + r;
        unsigned short* yp = y + (size_t)(b * T_ + trow) * C_ + h * D_;
#pragma unroll
        for (int db = 0; db < 4; db++)
            yp[db * 16 + lr] = f2b(oacc[db][r] * inv);
    }
}

// ---------------------------------------------------------------------------
extern "C" void kernel_launch(void* const* d_in, const int* in_sizes, int n_in,
                              void* d_out, int out_size, void* d_ws, size_t ws_size,
                              hipStream_t stream)
{
    const float* x       = (const float*)d_in[0];
    const float* Wqkv    = (const float*)d_in[1];
    const float* bqkv    = (const float*)d_in[2];
    const float* Wproj   = (const float*)d_in[3];
    const float* bproj   = (const float*)d_in[4];
    const float* Wrouter = (const float*)d_in[5];
    const float* brouter = (const float*)d_in[6];
    const float* Wq_rt   = (const float*)d_in[7];
    const float* bq_rt   = (const float*)d_in[8];

    float* out = (float*)d_out;
    char*  ws  = (char*)d_ws;

    const size_t MT  = (size_t)B_ * T_;
    const size_t QKV = MT * C_;

    unsigned short* xb   = (unsigned short*)ws;
    unsigned short* Wqt  = xb  + QKV;
    unsigned short* Wpt  = Wqt + (size_t)3 * C_ * C_;
    unsigned short* q    = Wpt + (size_t)C_ * C_;
    unsigned short* k    = q + QKV;
    unsigned short* v    = k + QKV;
    unsigned short* yab  = v + QKV;
    float* cm   = (float*)(yab + QKV);
    float* qrt  = cm  + (size_t)B_ * NCH * C_;
    float* ren  = qrt + MT * RD;

    float* y_out   = out;
    float* idx_out = out + QKV;
    float* sc_out  = idx_out + MT * TOPB;
    float* emb_out = sc_out + MT * NCH;

    // 1) fused preprocessing (cast, W transposes, qrt, chunk means)
    prep_fused<<<4352, 256, 0, stream>>>(x, xb, Wqkv, Wqt, Wproj, Wpt,
                                         Wq_rt, bq_rt, qrt, cm);

    // 2) qkv projection (256^2 tri-buffered, Q pre-scaled)
    gemm_qkv_256<<<dim3(192), 512, 0, stream>>>(
        xb, Wqt, bqkv, q, k, v, (int)MT, 3 * C_, C_);

    // 3) routing embeds (+l2norm) and top-k
    embeds_kernel<<<8, 256, 0, stream>>>(cm, Wrouter, brouter, emb_out, ren);
    scores_topk<<<(int)(MT / 64), 64, 0, stream>>>(qrt, ren, sc_out, idx_out);

    // 4) MFMA flash attention -> bf16 ya [B,T,C]
    attn_mfma<<<dim3(1024), 256, 0, stream>>>(q, k, v, yab);

    // 5) output projection
    gemm_mfma_f32out<<<dim3(C_ / 128, MT / 128), 256, 0, stream>>>(
        yab, Wpt, bproj, y_out, (int)MT, C_, C_);
}

// Round 12
// 181.657 us; speedup vs baseline: 1.4702x; 1.0281x over previous
//
#include <hip/hip_runtime.h>
#include <hip/hip_bf16.h>
#include <math.h>

#define B_   2
#define T_   2048
#define C_   1024
#define H_   16
#define D_   64
#define NCH  32
#define RD   32
#define TOPB 8

typedef __attribute__((ext_vector_type(8))) short bf16x8;
typedef __attribute__((ext_vector_type(4))) float f32x4;

static __device__ __forceinline__ unsigned short f2b(float f) {
    return __bfloat16_as_ushort(__float2bfloat16(f));
}

#define SCALE2 0.18033688f   /* 0.125 * 1.44269504 (log2 domain) */

// ---------------------------------------------------------------------------
// prep_fused: all input-only preprocessing in ONE kernel (role by block range)
// ---------------------------------------------------------------------------
__global__ __launch_bounds__(256) void prep_fused(
    const float* __restrict__ x, unsigned short* __restrict__ xb,
    const float* __restrict__ Wqkv, unsigned short* __restrict__ Wqt,
    const float* __restrict__ Wproj, unsigned short* __restrict__ Wpt,
    const float* __restrict__ Wq_rt, const float* __restrict__ bq_rt,
    float* __restrict__ qrt, float* __restrict__ cm)
{
    __shared__ float smem[64 * 65];
    const int bid = blockIdx.x;
    const int tid = threadIdx.x;

    if (bid < 2048) {                      // ---- cast x -> bf16
        const int i = bid * 256 + tid;
        float4 a = ((const float4*)x)[i * 2];
        float4 b = ((const float4*)x)[i * 2 + 1];
        bf16x8 o;
        o[0] = (short)f2b(a.x); o[1] = (short)f2b(a.y);
        o[2] = (short)f2b(a.z); o[3] = (short)f2b(a.w);
        o[4] = (short)f2b(b.x); o[5] = (short)f2b(b.y);
        o[6] = (short)f2b(b.z); o[7] = (short)f2b(b.w);
        *(bf16x8*)&xb[(size_t)i * 8] = o;
    } else if (bid < 3072) {               // ---- weight transpose+cast
        const float* W; unsigned short* Wt; int N, local;
        if (bid < 2816) { W = Wqkv;  Wt = Wqt; N = 3072; local = bid - 2048; }
        else            { W = Wproj; Wt = Wpt; N = 1024; local = bid - 2816; }
        const int nblk = N >> 6;
        const int n0 = (local % nblk) * 64, k0 = (local / nblk) * 64;
        float (*t)[65] = (float(*)[65])smem;
#pragma unroll
        for (int i = 0; i < 4; i++) {
            const int f = tid + i * 256;
            const int r = f >> 4, c4 = (f & 15) * 4;
            float4 v = *(const float4*)&W[(size_t)(k0 + r) * N + n0 + c4];
            t[r][c4 + 0] = v.x; t[r][c4 + 1] = v.y;
            t[r][c4 + 2] = v.z; t[r][c4 + 3] = v.w;
        }
        __syncthreads();
#pragma unroll
        for (int i = 0; i < 2; i++) {
            const int s = tid + i * 256;
            const int rn = s >> 3, ck8 = (s & 7) * 8;
            bf16x8 o;
#pragma unroll
            for (int j = 0; j < 8; j++) o[j] = (short)f2b(t[ck8 + j][rn]);
            *(bf16x8*)&Wt[(size_t)(n0 + rn) * 1024 + k0 + ck8] = o;
        }
    } else if (bid < 4096) {               // ---- qrt projection + l2norm
        float (*part)[4][32] = (float(*)[4][32])smem;
        const int r0 = (bid - 3072) * 4;
        const int g = tid >> 5;
        const int n = tid & 31;
        const float* w  = Wq_rt + (size_t)(g * 128) * RD + n;
        const float* a0 = x + (size_t)(r0 + 0) * C_ + g * 128;
        const float* a1 = x + (size_t)(r0 + 1) * C_ + g * 128;
        const float* a2 = x + (size_t)(r0 + 2) * C_ + g * 128;
        const float* a3 = x + (size_t)(r0 + 3) * C_ + g * 128;
        float acc0 = 0.f, acc1 = 0.f, acc2 = 0.f, acc3 = 0.f;
#pragma unroll 8
        for (int i = 0; i < 128; i += 4) {
            const float w0 = w[(i + 0) * RD];
            const float w1 = w[(i + 1) * RD];
            const float w2 = w[(i + 2) * RD];
            const float w3 = w[(i + 3) * RD];
            float4 x0 = *(const float4*)&a0[i];
            float4 x1 = *(const float4*)&a1[i];
            float4 x2 = *(const float4*)&a2[i];
            float4 x3 = *(const float4*)&a3[i];
            acc0 += x0.x * w0; acc0 += x0.y * w1; acc0 += x0.z * w2; acc0 += x0.w * w3;
            acc1 += x1.x * w0; acc1 += x1.y * w1; acc1 += x1.z * w2; acc1 += x1.w * w3;
            acc2 += x2.x * w0; acc2 += x2.y * w1; acc2 += x2.z * w2; acc2 += x2.w * w3;
            acc3 += x3.x * w0; acc3 += x3.y * w1; acc3 += x3.z * w2; acc3 += x3.w * w3;
        }
        part[g][0][n] = acc0;
        part[g][1][n] = acc1;
        part[g][2][n] = acc2;
        part[g][3][n] = acc3;
        __syncthreads();
        if (g < 4) {
            float s = part[0][g][n];
#pragma unroll
            for (int gg = 1; gg < 8; gg++) s += part[gg][g][n];
            s += bq_rt[n];
            float ss = s * s;
#pragma unroll
            for (int off = 16; off >= 1; off >>= 1) ss += __shfl_xor(ss, off, 32);
            qrt[(size_t)(r0 + g) * RD + n] = s / fmaxf(sqrtf(ss), 1e-12f);
        }
    } else {                               // ---- chunk means
        const int local = bid - 4096;
        const int bc = local & 63;
        const int b = bc >> 5, n = bc & 31;
        const int c = (local >> 6) * 256 + tid;
        const float* xp = x + ((size_t)b * T_ + n * 64) * C_;
        float s = 0.f;
        for (int i = 0; i < 64; i++) s += xp[(size_t)i * C_ + c];
        cm[(size_t)bc * C_ + c] = s * (1.0f / 64.0f);
    }
}

// ---------------------------------------------------------------------------
// routing embeds + l2norm fused
// ---------------------------------------------------------------------------
__global__ void embeds_kernel(const float* __restrict__ cm, const float* __restrict__ W,
                              const float* __restrict__ bias,
                              float* __restrict__ emb_out, float* __restrict__ ren)
{
    const int row  = blockIdx.x * 8 + (threadIdx.x >> 5);
    const int lane = threadIdx.x & 31;
    if (row >= B_ * NCH) return;
    const float* a = cm + (size_t)row * C_;
    float acc = 0.f;
    for (int k = 0; k < C_; k += 4) {
        float4 a4 = *(const float4*)&a[k];
        acc += a4.x * W[(k + 0) * RD + lane];
        acc += a4.y * W[(k + 1) * RD + lane];
        acc += a4.z * W[(k + 2) * RD + lane];
        acc += a4.w * W[(k + 3) * RD + lane];
    }
    acc += bias[lane];
    emb_out[(size_t)row * RD + lane] = acc;
    float ss = acc * acc;
#pragma unroll
    for (int off = 16; off >= 1; off >>= 1) ss += __shfl_xor(ss, off, 32);
    ren[(size_t)row * RD + lane] = acc / fmaxf(sqrtf(ss), 1e-12f);
}

// ---------------------------------------------------------------------------
// qkv GEMM, 256x256 tile, tri-buffered + counted vmcnt (R10 proven)
// ---------------------------------------------------------------------------
__global__ __launch_bounds__(512, 1) void gemm_qkv_256(
    const unsigned short* __restrict__ A, const unsigned short* __restrict__ Bt,
    const float* __restrict__ bias,
    unsigned short* __restrict__ qp, unsigned short* __restrict__ kp,
    unsigned short* __restrict__ vp, int M, int N, int K)
{
    __shared__ unsigned short lds[3][2][8192];

    const int tid  = threadIdx.x;
    const int wid  = tid >> 6;
    const int lane = tid & 63;
    const int lr = lane & 15, lg = lane >> 4;
    const int wm = wid >> 2, wn = wid & 3;

    const int bid = blockIdx.x;
    const int swz = (bid & 7) * 24 + (bid >> 3);
    const int m0 = (swz & 15) << 8;
    const int n0 = (swz >> 4) << 8;

    const int srow = tid >> 2;
    const int sswz = (((srow & 3) ^ ((srow >> 2) & 3)) << 4);
    const int skel = (((tid & 3) << 4) ^ sswz) >> 1;
    const unsigned short* gA0 = A  + (size_t)(m0 + srow) * K + skel;
    const unsigned short* gA1 = A  + (size_t)(m0 + srow + 128) * K + skel;
    const unsigned short* gB0 = Bt + (size_t)(n0 + srow) * K + skel;
    const unsigned short* gB1 = Bt + (size_t)(n0 + srow + 128) * K + skel;
    const int lb0 = (wid * 64) * 8;
    const int lb1 = (wid * 64 + 512) * 8;

#define QSTAGE(sl, kofs)                                                          \
    __builtin_amdgcn_global_load_lds(                                             \
        (const __attribute__((address_space(1))) int*)(gA0 + (kofs)),             \
        (__attribute__((address_space(3))) int*)&lds[sl][0][lb0], 16, 0, 0);      \
    __builtin_amdgcn_global_load_lds(                                             \
        (const __attribute__((address_space(1))) int*)(gA1 + (kofs)),             \
        (__attribute__((address_space(3))) int*)&lds[sl][0][lb1], 16, 0, 0);      \
    __builtin_amdgcn_global_load_lds(                                             \
        (const __attribute__((address_space(1))) int*)(gB0 + (kofs)),             \
        (__attribute__((address_space(3))) int*)&lds[sl][1][lb0], 16, 0, 0);      \
    __builtin_amdgcn_global_load_lds(                                             \
        (const __attribute__((address_space(1))) int*)(gB1 + (kofs)),             \
        (__attribute__((address_space(3))) int*)&lds[sl][1][lb1], 16, 0, 0);

    const int rswz = (((lr & 3) ^ ((lr >> 2) & 3)) << 4);
    const int acol = (((lg << 4) ^ rswz) >> 1);

    f32x4 acc[8][4];
#pragma unroll
    for (int i = 0; i < 8; i++)
#pragma unroll
        for (int j = 0; j < 4; j++) acc[i][j] = (f32x4){0.f, 0.f, 0.f, 0.f};

    const int nt = K >> 5;

    QSTAGE(0, 0)
    QSTAGE(1, 32)
    asm volatile("s_waitcnt vmcnt(4)" ::: "memory");
    __builtin_amdgcn_s_barrier();

    int cur = 0;
    for (int t = 0; t < nt; ++t) {
        int s2 = cur + 2; if (s2 >= 3) s2 -= 3;
        if (t + 2 < nt) { QSTAGE(s2, (t + 2) << 5) }

        const unsigned short* sA = &lds[cur][0][0];
        const unsigned short* sB = &lds[cur][1][0];

        bf16x8 bfr[4];
#pragma unroll
        for (int ni = 0; ni < 4; ni++)
            bfr[ni] = *(const bf16x8*)&sB[(wn * 64 + ni * 16 + lr) * 32 + acol];

        __builtin_amdgcn_s_setprio(1);
#pragma unroll
        for (int mi = 0; mi < 8; mi++) {
            bf16x8 af = *(const bf16x8*)&sA[(wm * 128 + mi * 16 + lr) * 32 + acol];
#pragma unroll
            for (int ni = 0; ni < 4; ni++)
                acc[mi][ni] = __builtin_amdgcn_mfma_f32_16x16x32_bf16(
                    af, bfr[ni], acc[mi][ni], 0, 0, 0);
        }
        __builtin_amdgcn_s_setprio(0);

        if (t + 1 < nt) {
            if (t + 2 < nt) { asm volatile("s_waitcnt vmcnt(4)" ::: "memory"); }
            else            { asm volatile("s_waitcnt vmcnt(0)" ::: "memory"); }
            __builtin_amdgcn_s_barrier();
        }
        cur += 1; if (cur == 3) cur = 0;
    }
#undef QSTAGE

#pragma unroll
    for (int ni = 0; ni < 4; ni++) {
        const int col = n0 + wn * 64 + ni * 16 + lr;
        const float bv = bias[col];
        const int which = col >> 10;
        const int c  = col & 1023;
        const int hh = c >> 6;
        const int dd = c & 63;
        unsigned short* dst = (which == 0) ? qp : (which == 1) ? kp : vp;
        const float postmul = (which == 0) ? SCALE2 : 1.0f;
#pragma unroll
        for (int mi = 0; mi < 8; mi++) {
#pragma unroll
            for (int r = 0; r < 4; r++) {
                const int row = m0 + wm * 128 + mi * 16 + lg * 4 + r;
                const int bb = row >> 11, tt = row & 2047;
                dst[(((size_t)bb * H_ + hh) * T_ + tt) * D_ + dd] =
                    f2b((acc[mi][ni][r] + bv) * postmul);
            }
        }
    }
}

// ---------------------------------------------------------------------------
// proj GEMM, 128x128 tile, tri-buffered + counted vmcnt + swizzle
// (same 4-loads/tile pipeline as gemm_qkv_256; 1 block/CU so intra-wave
//  overlap is the only latency hiding — counted vmcnt provides it)
// ---------------------------------------------------------------------------
__global__ __launch_bounds__(256, 1) void gemm_proj_128(
    const unsigned short* __restrict__ A, const unsigned short* __restrict__ Bt,
    const float* __restrict__ bias, float* __restrict__ out, int M, int N, int K)
{
    __shared__ unsigned short lds[3][2][4096];

    const int tid  = threadIdx.x;
    const int lane = tid & 63;
    const int wave = tid >> 6;
    const int lr = lane & 15, lg = lane >> 4;
    const int wm = wave >> 1, wn = wave & 1;
    const int n0 = blockIdx.x * 128, m0 = blockIdx.y * 128;

    const int srow = tid >> 2;                                   // 0..63
    const int sswz = (((srow & 3) ^ ((srow >> 2) & 3)) << 4);
    const int skel = (((tid & 3) << 4) ^ sswz) >> 1;
    const unsigned short* gA0 = A  + (size_t)(m0 + srow) * K + skel;
    const unsigned short* gA1 = A  + (size_t)(m0 + srow + 64) * K + skel;
    const unsigned short* gB0 = Bt + (size_t)(n0 + srow) * K + skel;
    const unsigned short* gB1 = Bt + (size_t)(n0 + srow + 64) * K + skel;
    const int ldb = (tid & 0xC0) * 8;     // wave-uniform base

#define PSTAGE(sl, kofs)                                                          \
    __builtin_amdgcn_global_load_lds(                                             \
        (const __attribute__((address_space(1))) int*)(gA0 + (kofs)),             \
        (__attribute__((address_space(3))) int*)&lds[sl][0][ldb], 16, 0, 0);      \
    __builtin_amdgcn_global_load_lds(                                             \
        (const __attribute__((address_space(1))) int*)(gA1 + (kofs)),             \
        (__attribute__((address_space(3))) int*)&lds[sl][0][2048 + ldb], 16, 0, 0); \
    __builtin_amdgcn_global_load_lds(                                             \
        (const __attribute__((address_space(1))) int*)(gB0 + (kofs)),             \
        (__attribute__((address_space(3))) int*)&lds[sl][1][ldb], 16, 0, 0);      \
    __builtin_amdgcn_global_load_lds(                                             \
        (const __attribute__((address_space(1))) int*)(gB1 + (kofs)),             \
        (__attribute__((address_space(3))) int*)&lds[sl][1][2048 + ldb], 16, 0, 0);

    const int rswz = (((lr & 3) ^ ((lr >> 2) & 3)) << 4);
    const int acol = (((lg << 4) ^ rswz) >> 1);

    f32x4 acc[4][4];
#pragma unroll
    for (int i = 0; i < 4; i++)
#pragma unroll
        for (int j = 0; j < 4; j++) acc[i][j] = (f32x4){0.f, 0.f, 0.f, 0.f};

    const int nt = K >> 5;

    PSTAGE(0, 0)
    PSTAGE(1, 32)
    asm volatile("s_waitcnt vmcnt(4)" ::: "memory");
    __builtin_amdgcn_s_barrier();

    int cur = 0;
    for (int t = 0; t < nt; ++t) {
        int s2 = cur + 2; if (s2 >= 3) s2 -= 3;
        if (t + 2 < nt) { PSTAGE(s2, (t + 2) << 5) }

        const unsigned short* sA = &lds[cur][0][0];
        const unsigned short* sB = &lds[cur][1][0];

        bf16x8 af[4], bfr[4];
#pragma unroll
        for (int mi = 0; mi < 4; mi++)
            af[mi] = *(const bf16x8*)&sA[(wm * 64 + mi * 16 + lr) * 32 + acol];
#pragma unroll
        for (int ni = 0; ni < 4; ni++)
            bfr[ni] = *(const bf16x8*)&sB[(wn * 64 + ni * 16 + lr) * 32 + acol];

        __builtin_amdgcn_s_setprio(1);
#pragma unroll
        for (int mi = 0; mi < 4; mi++)
#pragma unroll
            for (int ni = 0; ni < 4; ni++)
                acc[mi][ni] = __builtin_amdgcn_mfma_f32_16x16x32_bf16(
                    af[mi], bfr[ni], acc[mi][ni], 0, 0, 0);
        __builtin_amdgcn_s_setprio(0);

        if (t + 1 < nt) {
            if (t + 2 < nt) { asm volatile("s_waitcnt vmcnt(4)" ::: "memory"); }
            else            { asm volatile("s_waitcnt vmcnt(0)" ::: "memory"); }
            __builtin_amdgcn_s_barrier();
        }
        cur += 1; if (cur == 3) cur = 0;
    }
#undef PSTAGE

#pragma unroll
    for (int ni = 0; ni < 4; ni++) {
        const int col = n0 + wn * 64 + ni * 16 + lr;
        const float bv = bias[col];
#pragma unroll
        for (int mi = 0; mi < 4; mi++) {
#pragma unroll
            for (int r = 0; r < 4; r++) {
                const int row = m0 + wm * 64 + mi * 16 + lg * 4 + r;
                out[(size_t)row * N + col] = acc[mi][ni][r] + bv;
            }
        }
    }
}

// ---------------------------------------------------------------------------
// routing scores + top-8
// ---------------------------------------------------------------------------
__global__ void scores_topk(const float* __restrict__ qrt, const float* __restrict__ ren,
                            float* __restrict__ sc_out, float* __restrict__ idx_out)
{
    const int row = blockIdx.x * 64 + threadIdx.x;
    if (row >= B_ * T_) return;
    const int b = row / T_;
    float q[RD];
#pragma unroll
    for (int i = 0; i < RD; i++) q[i] = qrt[(size_t)row * RD + i];
    const float* rb = ren + (size_t)b * NCH * RD;
    float s[NCH];
#pragma unroll 4
    for (int n = 0; n < NCH; n++) {
        float acc = 0.f;
#pragma unroll
        for (int i = 0; i < RD; i++) acc += q[i] * rb[n * RD + i];
        s[n] = acc;
        sc_out[(size_t)row * NCH + n] = acc;
    }
    unsigned mask = 0;
    for (int t = 0; t < TOPB; t++) {
        float best = -INFINITY;
        int bi = 0;
#pragma unroll
        for (int n = 0; n < NCH; n++) {
            const bool ok = !((mask >> n) & 1u) && (s[n] > best);
            if (ok) { best = s[n]; bi = n; }
        }
        mask |= (1u << bi);
        idx_out[(size_t)row * TOPB + t] = (float)bi;
    }
}

// ---------------------------------------------------------------------------
// MFMA bf16 flash attention v7: balanced per-CU qt assignment.
// Round-robin dispatch gives CU-slot group g the i-values {g, 8+g, 16+g, 24+g};
// Q[i] chosen so every group sums to 62 tile-iters (was 76-4g: 21% makespan
// inflation). XCD pinning unchanged.
// ---------------------------------------------------------------------------
#define LSTR 68

__global__ __launch_bounds__(256) void attn_mfma(
    const unsigned short* __restrict__ qg, const unsigned short* __restrict__ kg,
    const unsigned short* __restrict__ vg, unsigned short* __restrict__ y)
{
    const int bid = blockIdx.x;
    const int xcd = bid & 7;
    const int h   = xcd + 8 * ((bid >> 3) & 1);
    const int b   = (bid >> 4) & 1;
    const int i   = bid >> 5;                 // 0..31
    // balanced: {31-g, 16+g, 15-g, g} per CU-slot group -> 62 tiles each
    const int qt  = (i & 8) ? ((i & 16) ? (i - 24) : (i + 8)) : (31 - i);

    const int tid  = threadIdx.x;
    const int wave = tid >> 6;
    const int lane = tid & 63;
    const int lg = lane >> 4;
    const int lr = lane & 15;

    __shared__ short Ks[2][64][LSTR];
    __shared__ short Vt[2][64][LSTR];

    const size_t base = ((size_t)(b * H_ + h) * T_) * D_;

    bf16x8 qf0, qf1;
    {
        const short* qp = (const short*)qg + base + (size_t)(qt * 64 + wave * 16 + lr) * D_;
        qf0 = *(const bf16x8*)&qp[lg * 8];
        qf1 = *(const bf16x8*)&qp[32 + lg * 8];
    }

    const int srr = tid >> 2;
    const int sc0 = (tid & 3) * 16;
    const int vrp = tid & 31;
    const int vcg = tid >> 5;
    const int kv0   = 2 * vrp;
    const int vslot = ((kv0 >> 5) << 5) + (((kv0 >> 2) & 3) << 3) +
                      (((kv0 >> 4) & 1) << 2) + (kv0 & 3);

    bf16x8 kreg0, kreg1, vreg0, vreg1;

    float m_run = -INFINITY, l_run = 0.f;
    f32x4 oacc[4];
#pragma unroll
    for (int r = 0; r < 4; r++) oacc[r] = (f32x4){0.f, 0.f, 0.f, 0.f};
    const int qrow_g = qt * 64 + wave * 16 + lr;

#define VPACK(buf)                                                              \
    {                                                                           \
        const unsigned* v0d = (const unsigned*)&vreg0;                          \
        const unsigned* v1d = (const unsigned*)&vreg1;                          \
        _Pragma("unroll")                                                       \
        for (int jj = 0; jj < 8; jj++) {                                        \
            const unsigned sel = (jj & 1) ? 0x07060302u : 0x05040100u;          \
            const unsigned dw = __builtin_amdgcn_perm(v1d[jj >> 1], v0d[jj >> 1], sel); \
            *(unsigned*)&Vt[buf][vcg * 8 + jj][vslot] = dw;                     \
        }                                                                       \
    }

    {
        const short* kp = (const short*)kg + base + (size_t)srr * D_ + sc0;
        kreg0 = *(const bf16x8*)kp;
        kreg1 = *(const bf16x8*)(kp + 8);
        const short* vp = (const short*)vg + base + (size_t)kv0 * D_ + vcg * 8;
        vreg0 = *(const bf16x8*)vp;
        vreg1 = *(const bf16x8*)(vp + D_);
    }
    {
        *(bf16x8*)&Ks[0][srr][sc0]     = kreg0;
        *(bf16x8*)&Ks[0][srr][sc0 + 8] = kreg1;
        VPACK(0)
    }
    if (qt >= 1) {
        const short* kp = (const short*)kg + base + (size_t)(64 + srr) * D_ + sc0;
        kreg0 = *(const bf16x8*)kp;
        kreg1 = *(const bf16x8*)(kp + 8);
        const short* vp = (const short*)vg + base + (size_t)(64 + kv0) * D_ + vcg * 8;
        vreg0 = *(const bf16x8*)vp;
        vreg1 = *(const bf16x8*)(vp + D_);
    }
    __syncthreads();

    for (int kt = 0; kt <= qt; ++kt) {
        const int cur = kt & 1;

        if (kt < qt) {
            *(bf16x8*)&Ks[cur ^ 1][srr][sc0]     = kreg0;
            *(bf16x8*)&Ks[cur ^ 1][srr][sc0 + 8] = kreg1;
            VPACK(cur ^ 1)
        }
        if (kt + 2 <= qt) {
            const short* kp = (const short*)kg + base + (size_t)((kt + 2) * 64 + srr) * D_ + sc0;
            kreg0 = *(const bf16x8*)kp;
            kreg1 = *(const bf16x8*)(kp + 8);
            const short* vp = (const short*)vg + base + (size_t)((kt + 2) * 64 + kv0) * D_ + vcg * 8;
            vreg0 = *(const bf16x8*)vp;
            vreg1 = *(const bf16x8*)(vp + D_);
        }

        f32x4 s[4];
        __builtin_amdgcn_s_setprio(1);
#pragma unroll
        for (int cb = 0; cb < 4; cb++) {
            bf16x8 kf0 = *(const bf16x8*)&Ks[cur][cb * 16 + lr][lg * 8];
            bf16x8 kf1 = *(const bf16x8*)&Ks[cur][cb * 16 + lr][32 + lg * 8];
            f32x4 acc = (f32x4){0.f, 0.f, 0.f, 0.f};
            acc = __builtin_amdgcn_mfma_f32_16x16x32_bf16(kf0, qf0, acc, 0, 0, 0);
            acc = __builtin_amdgcn_mfma_f32_16x16x32_bf16(kf1, qf1, acc, 0, 0, 0);
            s[cb] = acc;
        }
        __builtin_amdgcn_s_setprio(0);

        if (kt == qt) {
#pragma unroll
            for (int cb = 0; cb < 4; cb++)
#pragma unroll
                for (int r = 0; r < 4; r++)
                    if (kt * 64 + cb * 16 + lg * 4 + r > qrow_g) s[cb][r] = -INFINITY;
        }

        float rm;
        {
            const float t0 = fmaxf(fmaxf(s[0][0], s[0][1]), fmaxf(s[0][2], s[0][3]));
            const float t1 = fmaxf(fmaxf(s[1][0], s[1][1]), fmaxf(s[1][2], s[1][3]));
            const float t2 = fmaxf(fmaxf(s[2][0], s[2][1]), fmaxf(s[2][2], s[2][3]));
            const float t3 = fmaxf(fmaxf(s[3][0], s[3][1]), fmaxf(s[3][2], s[3][3]));
            rm = fmaxf(fmaxf(t0, t1), fmaxf(t2, t3));
        }
        rm = fmaxf(rm, __shfl_xor(rm, 16));
        rm = fmaxf(rm, __shfl_xor(rm, 32));

        if (!__all(rm <= m_run + 8.0f)) {
            const float mnew = fmaxf(m_run, rm);
            const float fsc  = exp2f(m_run - mnew);
            m_run = mnew;
            l_run *= fsc;
            float fr[4];
#pragma unroll
            for (int r = 0; r < 4; r++) fr[r] = __shfl(fsc, lg * 4 + r);
#pragma unroll
            for (int db = 0; db < 4; db++)
#pragma unroll
                for (int r = 0; r < 4; r++) oacc[db][r] *= fr[r];
        }

        float p[4][4];
#pragma unroll
        for (int cb = 0; cb < 4; cb++)
#pragma unroll
            for (int r = 0; r < 4; r++)
                p[cb][r] = exp2f(s[cb][r] - m_run);
        float rs;
        {
            const float t0 = (p[0][0] + p[0][1]) + (p[0][2] + p[0][3]);
            const float t1 = (p[1][0] + p[1][1]) + (p[1][2] + p[1][3]);
            const float t2 = (p[2][0] + p[2][1]) + (p[2][2] + p[2][3]);
            const float t3 = (p[3][0] + p[3][1]) + (p[3][2] + p[3][3]);
            rs = (t0 + t1) + (t2 + t3);
        }
        rs += __shfl_xor(rs, 16);
        rs += __shfl_xor(rs, 32);
        l_run += rs;

        bf16x8 pf0, pf1;
#pragma unroll
        for (int r = 0; r < 4; r++) {
            pf0[r]     = (short)f2b(p[0][r]);
            pf0[4 + r] = (short)f2b(p[1][r]);
            pf1[r]     = (short)f2b(p[2][r]);
            pf1[4 + r] = (short)f2b(p[3][r]);
        }

        __builtin_amdgcn_s_setprio(1);
#pragma unroll
        for (int db = 0; db < 4; db++) {
            bf16x8 vf0 = *(const bf16x8*)&Vt[cur][db * 16 + lr][lg * 8];
            bf16x8 vf1 = *(const bf16x8*)&Vt[cur][db * 16 + lr][32 + lg * 8];
            oacc[db] = __builtin_amdgcn_mfma_f32_16x16x32_bf16(pf0, vf0, oacc[db], 0, 0, 0);
            oacc[db] = __builtin_amdgcn_mfma_f32_16x16x32_bf16(pf1, vf1, oacc[db], 0, 0, 0);
        }
        __builtin_amdgcn_s_setprio(0);

        __syncthreads();
    }
#undef VPACK

#pragma unroll
    for (int r = 0; r < 4; r++) {
        const float lrow = __shfl(l_run, lg * 4 + r);
        const float inv = 1.0f / lrow;
        const int trow = qt * 64 + wave * 16 + lg * 4 + r;
        unsigned short* yp = y + (size_t)(b * T_ + trow) * C_ + h * D_;
#pragma unroll
        for (int db = 0; db < 4; db++)
            yp[db * 16 + lr] = f2b(oacc[db][r] * inv);
    }
}

// ---------------------------------------------------------------------------
extern "C" void kernel_launch(void* const* d_in, const int* in_sizes, int n_in,
                              void* d_out, int out_size, void* d_ws, size_t ws_size,
                              hipStream_t stream)
{
    const float* x       = (const float*)d_in[0];
    const float* Wqkv    = (const float*)d_in[1];
    const float* bqkv    = (const float*)d_in[2];
    const float* Wproj   = (const float*)d_in[3];
    const float* bproj   = (const float*)d_in[4];
    const float* Wrouter = (const float*)d_in[5];
    const float* brouter = (const float*)d_in[6];
    const float* Wq_rt   = (const float*)d_in[7];
    const float* bq_rt   = (const float*)d_in[8];

    float* out = (float*)d_out;
    char*  ws  = (char*)d_ws;

    const size_t MT  = (size_t)B_ * T_;
    const size_t QKV = MT * C_;

    unsigned short* xb   = (unsigned short*)ws;
    unsigned short* Wqt  = xb  + QKV;
    unsigned short* Wpt  = Wqt + (size_t)3 * C_ * C_;
    unsigned short* q    = Wpt + (size_t)C_ * C_;
    unsigned short* k    = q + QKV;
    unsigned short* v    = k + QKV;
    unsigned short* yab  = v + QKV;
    float* cm   = (float*)(yab + QKV);
    float* qrt  = cm  + (size_t)B_ * NCH * C_;
    float* ren  = qrt + MT * RD;

    float* y_out   = out;
    float* idx_out = out + QKV;
    float* sc_out  = idx_out + MT * TOPB;
    float* emb_out = sc_out + MT * NCH;

    // 1) fused preprocessing
    prep_fused<<<4352, 256, 0, stream>>>(x, xb, Wqkv, Wqt, Wproj, Wpt,
                                         Wq_rt, bq_rt, qrt, cm);

    // 2) qkv projection (256^2 tri-buffered, Q pre-scaled)
    gemm_qkv_256<<<dim3(192), 512, 0, stream>>>(
        xb, Wqt, bqkv, q, k, v, (int)MT, 3 * C_, C_);

    // 3) routing embeds and top-k
    embeds_kernel<<<8, 256, 0, stream>>>(cm, Wrouter, brouter, emb_out, ren);
    scores_topk<<<(int)(MT / 64), 64, 0, stream>>>(qrt, ren, sc_out, idx_out);

    // 4) MFMA flash attention (balanced qt) -> bf16 ya [B,T,C]
    attn_mfma<<<dim3(1024), 256, 0, stream>>>(q, k, v, yab);

    // 5) output projection (tri-buffered counted-vmcnt)
    gemm_proj_128<<<dim3(C_ / 128, MT / 128), 256, 0, stream>>>(
        yab, Wpt, bproj, y_out, (int)MT, C_, C_);
}

// Round 13
// 180.796 us; speedup vs baseline: 1.4772x; 1.0048x over previous
//
#include <hip/hip_runtime.h>
#include <hip/hip_bf16.h>
#include <math.h>

#define B_   2
#define T_   2048
#define C_   1024
#define H_   16
#define D_   64
#define NCH  32
#define RD   32
#define TOPB 8

typedef __attribute__((ext_vector_type(8))) short bf16x8;
typedef __attribute__((ext_vector_type(4))) float f32x4;

static __device__ __forceinline__ unsigned short f2b(float f) {
    return __bfloat16_as_ushort(__float2bfloat16(f));
}

#define SCALE2 0.18033688f   /* 0.125 * 1.44269504 (log2 domain) */

// ---------------------------------------------------------------------------
// prep_fused: all input-only preprocessing in ONE kernel (role by block range)
// ---------------------------------------------------------------------------
__global__ __launch_bounds__(256) void prep_fused(
    const float* __restrict__ x, unsigned short* __restrict__ xb,
    const float* __restrict__ Wqkv, unsigned short* __restrict__ Wqt,
    const float* __restrict__ Wproj, unsigned short* __restrict__ Wpt,
    const float* __restrict__ Wq_rt, const float* __restrict__ bq_rt,
    float* __restrict__ qrt, float* __restrict__ cm)
{
    __shared__ float smem[64 * 65];
    const int bid = blockIdx.x;
    const int tid = threadIdx.x;

    if (bid < 2048) {                      // ---- cast x -> bf16
        const int i = bid * 256 + tid;
        float4 a = ((const float4*)x)[i * 2];
        float4 b = ((const float4*)x)[i * 2 + 1];
        bf16x8 o;
        o[0] = (short)f2b(a.x); o[1] = (short)f2b(a.y);
        o[2] = (short)f2b(a.z); o[3] = (short)f2b(a.w);
        o[4] = (short)f2b(b.x); o[5] = (short)f2b(b.y);
        o[6] = (short)f2b(b.z); o[7] = (short)f2b(b.w);
        *(bf16x8*)&xb[(size_t)i * 8] = o;
    } else if (bid < 3072) {               // ---- weight transpose+cast
        const float* W; unsigned short* Wt; int N, local;
        if (bid < 2816) { W = Wqkv;  Wt = Wqt; N = 3072; local = bid - 2048; }
        else            { W = Wproj; Wt = Wpt; N = 1024; local = bid - 2816; }
        const int nblk = N >> 6;
        const int n0 = (local % nblk) * 64, k0 = (local / nblk) * 64;
        float (*t)[65] = (float(*)[65])smem;
#pragma unroll
        for (int i = 0; i < 4; i++) {
            const int f = tid + i * 256;
            const int r = f >> 4, c4 = (f & 15) * 4;
            float4 v = *(const float4*)&W[(size_t)(k0 + r) * N + n0 + c4];
            t[r][c4 + 0] = v.x; t[r][c4 + 1] = v.y;
            t[r][c4 + 2] = v.z; t[r][c4 + 3] = v.w;
        }
        __syncthreads();
#pragma unroll
        for (int i = 0; i < 2; i++) {
            const int s = tid + i * 256;
            const int rn = s >> 3, ck8 = (s & 7) * 8;
            bf16x8 o;
#pragma unroll
            for (int j = 0; j < 8; j++) o[j] = (short)f2b(t[ck8 + j][rn]);
            *(bf16x8*)&Wt[(size_t)(n0 + rn) * 1024 + k0 + ck8] = o;
        }
    } else if (bid < 4096) {               // ---- qrt projection + l2norm
        float (*part)[4][32] = (float(*)[4][32])smem;
        const int r0 = (bid - 3072) * 4;
        const int g = tid >> 5;
        const int n = tid & 31;
        const float* w  = Wq_rt + (size_t)(g * 128) * RD + n;
        const float* a0 = x + (size_t)(r0 + 0) * C_ + g * 128;
        const float* a1 = x + (size_t)(r0 + 1) * C_ + g * 128;
        const float* a2 = x + (size_t)(r0 + 2) * C_ + g * 128;
        const float* a3 = x + (size_t)(r0 + 3) * C_ + g * 128;
        float acc0 = 0.f, acc1 = 0.f, acc2 = 0.f, acc3 = 0.f;
#pragma unroll 8
        for (int i = 0; i < 128; i += 4) {
            const float w0 = w[(i + 0) * RD];
            const float w1 = w[(i + 1) * RD];
            const float w2 = w[(i + 2) * RD];
            const float w3 = w[(i + 3) * RD];
            float4 x0 = *(const float4*)&a0[i];
            float4 x1 = *(const float4*)&a1[i];
            float4 x2 = *(const float4*)&a2[i];
            float4 x3 = *(const float4*)&a3[i];
            acc0 += x0.x * w0; acc0 += x0.y * w1; acc0 += x0.z * w2; acc0 += x0.w * w3;
            acc1 += x1.x * w0; acc1 += x1.y * w1; acc1 += x1.z * w2; acc1 += x1.w * w3;
            acc2 += x2.x * w0; acc2 += x2.y * w1; acc2 += x2.z * w2; acc2 += x2.w * w3;
            acc3 += x3.x * w0; acc3 += x3.y * w1; acc3 += x3.z * w2; acc3 += x3.w * w3;
        }
        part[g][0][n] = acc0;
        part[g][1][n] = acc1;
        part[g][2][n] = acc2;
        part[g][3][n] = acc3;
        __syncthreads();
        if (g < 4) {
            float s = part[0][g][n];
#pragma unroll
            for (int gg = 1; gg < 8; gg++) s += part[gg][g][n];
            s += bq_rt[n];
            float ss = s * s;
#pragma unroll
            for (int off = 16; off >= 1; off >>= 1) ss += __shfl_xor(ss, off, 32);
            qrt[(size_t)(r0 + g) * RD + n] = s / fmaxf(sqrtf(ss), 1e-12f);
        }
    } else {                               // ---- chunk means
        const int local = bid - 4096;
        const int bc = local & 63;
        const int b = bc >> 5, n = bc & 31;
        const int c = (local >> 6) * 256 + tid;
        const float* xp = x + ((size_t)b * T_ + n * 64) * C_;
        float s = 0.f;
        for (int i = 0; i < 64; i++) s += xp[(size_t)i * C_ + c];
        cm[(size_t)bc * C_ + c] = s * (1.0f / 64.0f);
    }
}

// ---------------------------------------------------------------------------
// routing embeds + l2norm fused
// ---------------------------------------------------------------------------
__global__ void embeds_kernel(const float* __restrict__ cm, const float* __restrict__ W,
                              const float* __restrict__ bias,
                              float* __restrict__ emb_out, float* __restrict__ ren)
{
    const int row  = blockIdx.x * 8 + (threadIdx.x >> 5);
    const int lane = threadIdx.x & 31;
    if (row >= B_ * NCH) return;
    const float* a = cm + (size_t)row * C_;
    float acc = 0.f;
    for (int k = 0; k < C_; k += 4) {
        float4 a4 = *(const float4*)&a[k];
        acc += a4.x * W[(k + 0) * RD + lane];
        acc += a4.y * W[(k + 1) * RD + lane];
        acc += a4.z * W[(k + 2) * RD + lane];
        acc += a4.w * W[(k + 3) * RD + lane];
    }
    acc += bias[lane];
    emb_out[(size_t)row * RD + lane] = acc;
    float ss = acc * acc;
#pragma unroll
    for (int off = 16; off >= 1; off >>= 1) ss += __shfl_xor(ss, off, 32);
    ren[(size_t)row * RD + lane] = acc / fmaxf(sqrtf(ss), 1e-12f);
}

// ---------------------------------------------------------------------------
// qkv GEMM, 256x256 tile, tri-buffered + counted vmcnt (R10 proven)
// ---------------------------------------------------------------------------
__global__ __launch_bounds__(512, 1) void gemm_qkv_256(
    const unsigned short* __restrict__ A, const unsigned short* __restrict__ Bt,
    const float* __restrict__ bias,
    unsigned short* __restrict__ qp, unsigned short* __restrict__ kp,
    unsigned short* __restrict__ vp, int M, int N, int K)
{
    __shared__ unsigned short lds[3][2][8192];

    const int tid  = threadIdx.x;
    const int wid  = tid >> 6;
    const int lane = tid & 63;
    const int lr = lane & 15, lg = lane >> 4;
    const int wm = wid >> 2, wn = wid & 3;

    const int bid = blockIdx.x;
    const int swz = (bid & 7) * 24 + (bid >> 3);
    const int m0 = (swz & 15) << 8;
    const int n0 = (swz >> 4) << 8;

    const int srow = tid >> 2;
    const int sswz = (((srow & 3) ^ ((srow >> 2) & 3)) << 4);
    const int skel = (((tid & 3) << 4) ^ sswz) >> 1;
    const unsigned short* gA0 = A  + (size_t)(m0 + srow) * K + skel;
    const unsigned short* gA1 = A  + (size_t)(m0 + srow + 128) * K + skel;
    const unsigned short* gB0 = Bt + (size_t)(n0 + srow) * K + skel;
    const unsigned short* gB1 = Bt + (size_t)(n0 + srow + 128) * K + skel;
    const int lb0 = (wid * 64) * 8;
    const int lb1 = (wid * 64 + 512) * 8;

#define QSTAGE(sl, kofs)                                                          \
    __builtin_amdgcn_global_load_lds(                                             \
        (const __attribute__((address_space(1))) int*)(gA0 + (kofs)),             \
        (__attribute__((address_space(3))) int*)&lds[sl][0][lb0], 16, 0, 0);      \
    __builtin_amdgcn_global_load_lds(                                             \
        (const __attribute__((address_space(1))) int*)(gA1 + (kofs)),             \
        (__attribute__((address_space(3))) int*)&lds[sl][0][lb1], 16, 0, 0);      \
    __builtin_amdgcn_global_load_lds(                                             \
        (const __attribute__((address_space(1))) int*)(gB0 + (kofs)),             \
        (__attribute__((address_space(3))) int*)&lds[sl][1][lb0], 16, 0, 0);      \
    __builtin_amdgcn_global_load_lds(                                             \
        (const __attribute__((address_space(1))) int*)(gB1 + (kofs)),             \
        (__attribute__((address_space(3))) int*)&lds[sl][1][lb1], 16, 0, 0);

    const int rswz = (((lr & 3) ^ ((lr >> 2) & 3)) << 4);
    const int acol = (((lg << 4) ^ rswz) >> 1);

    f32x4 acc[8][4];
#pragma unroll
    for (int i = 0; i < 8; i++)
#pragma unroll
        for (int j = 0; j < 4; j++) acc[i][j] = (f32x4){0.f, 0.f, 0.f, 0.f};

    const int nt = K >> 5;

    QSTAGE(0, 0)
    QSTAGE(1, 32)
    asm volatile("s_waitcnt vmcnt(4)" ::: "memory");
    __builtin_amdgcn_s_barrier();

    int cur = 0;
    for (int t = 0; t < nt; ++t) {
        int s2 = cur + 2; if (s2 >= 3) s2 -= 3;
        if (t + 2 < nt) { QSTAGE(s2, (t + 2) << 5) }

        const unsigned short* sA = &lds[cur][0][0];
        const unsigned short* sB = &lds[cur][1][0];

        bf16x8 bfr[4];
#pragma unroll
        for (int ni = 0; ni < 4; ni++)
            bfr[ni] = *(const bf16x8*)&sB[(wn * 64 + ni * 16 + lr) * 32 + acol];

        __builtin_amdgcn_s_setprio(1);
#pragma unroll
        for (int mi = 0; mi < 8; mi++) {
            bf16x8 af = *(const bf16x8*)&sA[(wm * 128 + mi * 16 + lr) * 32 + acol];
#pragma unroll
            for (int ni = 0; ni < 4; ni++)
                acc[mi][ni] = __builtin_amdgcn_mfma_f32_16x16x32_bf16(
                    af, bfr[ni], acc[mi][ni], 0, 0, 0);
        }
        __builtin_amdgcn_s_setprio(0);

        if (t + 1 < nt) {
            if (t + 2 < nt) { asm volatile("s_waitcnt vmcnt(4)" ::: "memory"); }
            else            { asm volatile("s_waitcnt vmcnt(0)" ::: "memory"); }
            __builtin_amdgcn_s_barrier();
        }
        cur += 1; if (cur == 3) cur = 0;
    }
#undef QSTAGE

#pragma unroll
    for (int ni = 0; ni < 4; ni++) {
        const int col = n0 + wn * 64 + ni * 16 + lr;
        const float bv = bias[col];
        const int which = col >> 10;
        const int c  = col & 1023;
        const int hh = c >> 6;
        const int dd = c & 63;
        unsigned short* dst = (which == 0) ? qp : (which == 1) ? kp : vp;
        const float postmul = (which == 0) ? SCALE2 : 1.0f;
#pragma unroll
        for (int mi = 0; mi < 8; mi++) {
#pragma unroll
            for (int r = 0; r < 4; r++) {
                const int row = m0 + wm * 128 + mi * 16 + lg * 4 + r;
                const int bb = row >> 11, tt = row & 2047;
                dst[(((size_t)bb * H_ + hh) * T_ + tt) * D_ + dd] =
                    f2b((acc[mi][ni][r] + bv) * postmul);
            }
        }
    }
}

// ---------------------------------------------------------------------------
// proj GEMM, 128x128 tile, tri-buffered + counted vmcnt + swizzle
// ---------------------------------------------------------------------------
__global__ __launch_bounds__(256, 1) void gemm_proj_128(
    const unsigned short* __restrict__ A, const unsigned short* __restrict__ Bt,
    const float* __restrict__ bias, float* __restrict__ out, int M, int N, int K)
{
    __shared__ unsigned short lds[3][2][4096];

    const int tid  = threadIdx.x;
    const int lane = tid & 63;
    const int wave = tid >> 6;
    const int lr = lane & 15, lg = lane >> 4;
    const int wm = wave >> 1, wn = wave & 1;
    const int n0 = blockIdx.x * 128, m0 = blockIdx.y * 128;

    const int srow = tid >> 2;
    const int sswz = (((srow & 3) ^ ((srow >> 2) & 3)) << 4);
    const int skel = (((tid & 3) << 4) ^ sswz) >> 1;
    const unsigned short* gA0 = A  + (size_t)(m0 + srow) * K + skel;
    const unsigned short* gA1 = A  + (size_t)(m0 + srow + 64) * K + skel;
    const unsigned short* gB0 = Bt + (size_t)(n0 + srow) * K + skel;
    const unsigned short* gB1 = Bt + (size_t)(n0 + srow + 64) * K + skel;
    const int ldb = (tid & 0xC0) * 8;

#define PSTAGE(sl, kofs)                                                          \
    __builtin_amdgcn_global_load_lds(                                             \
        (const __attribute__((address_space(1))) int*)(gA0 + (kofs)),             \
        (__attribute__((address_space(3))) int*)&lds[sl][0][ldb], 16, 0, 0);      \
    __builtin_amdgcn_global_load_lds(                                             \
        (const __attribute__((address_space(1))) int*)(gA1 + (kofs)),             \
        (__attribute__((address_space(3))) int*)&lds[sl][0][2048 + ldb], 16, 0, 0); \
    __builtin_amdgcn_global_load_lds(                                             \
        (const __attribute__((address_space(1))) int*)(gB0 + (kofs)),             \
        (__attribute__((address_space(3))) int*)&lds[sl][1][ldb], 16, 0, 0);      \
    __builtin_amdgcn_global_load_lds(                                             \
        (const __attribute__((address_space(1))) int*)(gB1 + (kofs)),             \
        (__attribute__((address_space(3))) int*)&lds[sl][1][2048 + ldb], 16, 0, 0);

    const int rswz = (((lr & 3) ^ ((lr >> 2) & 3)) << 4);
    const int acol = (((lg << 4) ^ rswz) >> 1);

    f32x4 acc[4][4];
#pragma unroll
    for (int i = 0; i < 4; i++)
#pragma unroll
        for (int j = 0; j < 4; j++) acc[i][j] = (f32x4){0.f, 0.f, 0.f, 0.f};

    const int nt = K >> 5;

    PSTAGE(0, 0)
    PSTAGE(1, 32)
    asm volatile("s_waitcnt vmcnt(4)" ::: "memory");
    __builtin_amdgcn_s_barrier();

    int cur = 0;
    for (int t = 0; t < nt; ++t) {
        int s2 = cur + 2; if (s2 >= 3) s2 -= 3;
        if (t + 2 < nt) { PSTAGE(s2, (t + 2) << 5) }

        const unsigned short* sA = &lds[cur][0][0];
        const unsigned short* sB = &lds[cur][1][0];

        bf16x8 af[4], bfr[4];
#pragma unroll
        for (int mi = 0; mi < 4; mi++)
            af[mi] = *(const bf16x8*)&sA[(wm * 64 + mi * 16 + lr) * 32 + acol];
#pragma unroll
        for (int ni = 0; ni < 4; ni++)
            bfr[ni] = *(const bf16x8*)&sB[(wn * 64 + ni * 16 + lr) * 32 + acol];

        __builtin_amdgcn_s_setprio(1);
#pragma unroll
        for (int mi = 0; mi < 4; mi++)
#pragma unroll
            for (int ni = 0; ni < 4; ni++)
                acc[mi][ni] = __builtin_amdgcn_mfma_f32_16x16x32_bf16(
                    af[mi], bfr[ni], acc[mi][ni], 0, 0, 0);
        __builtin_amdgcn_s_setprio(0);

        if (t + 1 < nt) {
            if (t + 2 < nt) { asm volatile("s_waitcnt vmcnt(4)" ::: "memory"); }
            else            { asm volatile("s_waitcnt vmcnt(0)" ::: "memory"); }
            __builtin_amdgcn_s_barrier();
        }
        cur += 1; if (cur == 3) cur = 0;
    }
#undef PSTAGE

#pragma unroll
    for (int ni = 0; ni < 4; ni++) {
        const int col = n0 + wn * 64 + ni * 16 + lr;
        const float bv = bias[col];
#pragma unroll
        for (int mi = 0; mi < 4; mi++) {
#pragma unroll
            for (int r = 0; r < 4; r++) {
                const int row = m0 + wm * 64 + mi * 16 + lg * 4 + r;
                out[(size_t)row * N + col] = acc[mi][ni][r] + bv;
            }
        }
    }
}

// ---------------------------------------------------------------------------
// routing scores + top-8
// ---------------------------------------------------------------------------
__global__ void scores_topk(const float* __restrict__ qrt, const float* __restrict__ ren,
                            float* __restrict__ sc_out, float* __restrict__ idx_out)
{
    const int row = blockIdx.x * 64 + threadIdx.x;
    if (row >= B_ * T_) return;
    const int b = row / T_;
    float q[RD];
#pragma unroll
    for (int i = 0; i < RD; i++) q[i] = qrt[(size_t)row * RD + i];
    const float* rb = ren + (size_t)b * NCH * RD;
    float s[NCH];
#pragma unroll 4
    for (int n = 0; n < NCH; n++) {
        float acc = 0.f;
#pragma unroll
        for (int i = 0; i < RD; i++) acc += q[i] * rb[n * RD + i];
        s[n] = acc;
        sc_out[(size_t)row * NCH + n] = acc;
    }
    unsigned mask = 0;
    for (int t = 0; t < TOPB; t++) {
        float best = -INFINITY;
        int bi = 0;
#pragma unroll
        for (int n = 0; n < NCH; n++) {
            const bool ok = !((mask >> n) & 1u) && (s[n] > best);
            if (ok) { best = s[n]; bi = n; }
        }
        mask |= (1u << bi);
        idx_out[(size_t)row * TOPB + t] = (float)bi;
    }
}

// ---------------------------------------------------------------------------
// MFMA bf16 flash attention v8:
//  - LDS exact-fit 32 KB (width-64 + XOR swizzle idx^=(row&7)<<3, shorts)
//    -> 5 blocks/CU (was 4 at 34.8 KB)  [T2/G4 recipe; involution verified]
//  - pointer-increment K/V staging (no per-iter 64-bit addr recompute)
//  - balanced qt map, XCD pinning, defer-max, exp2 softmax, setprio kept
// ---------------------------------------------------------------------------
#define SW(row, idx) ((idx) ^ (((row) & 7) << 3))

__global__ __launch_bounds__(256) void attn_mfma(
    const unsigned short* __restrict__ qg, const unsigned short* __restrict__ kg,
    const unsigned short* __restrict__ vg, unsigned short* __restrict__ y)
{
    const int bid = blockIdx.x;
    const int xcd = bid & 7;
    const int h   = xcd + 8 * ((bid >> 3) & 1);
    const int b   = (bid >> 4) & 1;
    const int i   = bid >> 5;
    const int qt  = (i & 8) ? ((i & 16) ? (i - 24) : (i + 8)) : (31 - i);

    const int tid  = threadIdx.x;
    const int wave = tid >> 6;
    const int lane = tid & 63;
    const int lg = lane >> 4;
    const int lr = lane & 15;

    __shared__ short Ks[2][64 * 64];
    __shared__ short Vt[2][64 * 64];

    const size_t base = ((size_t)(b * H_ + h) * T_) * D_;

    bf16x8 qf0, qf1;
    {
        const short* qp = (const short*)qg + base + (size_t)(qt * 64 + wave * 16 + lr) * D_;
        qf0 = *(const bf16x8*)&qp[lg * 8];
        qf1 = *(const bf16x8*)&qp[32 + lg * 8];
    }

    const int srr = tid >> 2;
    const int sc0 = (tid & 3) * 16;
    const int vrp = tid & 31;
    const int vcg = tid >> 5;
    const int kv0   = 2 * vrp;
    const int vslot = ((kv0 >> 5) << 5) + (((kv0 >> 2) & 3) << 3) +
                      (((kv0 >> 4) & 1) << 2) + (kv0 & 3);

    // loop-invariant swizzled store indices
    const int kst0 = SW(srr, srr * 64 + sc0);
    const int kst1 = SW(srr, srr * 64 + sc0 + 8);
    // read indices (per cb/db row = blk*16+lr; swizzle uses lr&7)
    const int rsw = (lr & 7) << 3;

    bf16x8 kreg0, kreg1, vreg0, vreg1;

    float m_run = -INFINITY, l_run = 0.f;
    f32x4 oacc[4];
#pragma unroll
    for (int r = 0; r < 4; r++) oacc[r] = (f32x4){0.f, 0.f, 0.f, 0.f};
    const int qrow_g = qt * 64 + wave * 16 + lr;

#define VPACK(buf)                                                              \
    {                                                                           \
        const unsigned* v0d = (const unsigned*)&vreg0;                          \
        const unsigned* v1d = (const unsigned*)&vreg1;                          \
        _Pragma("unroll")                                                       \
        for (int jj = 0; jj < 8; jj++) {                                        \
            const unsigned sel = (jj & 1) ? 0x07060302u : 0x05040100u;          \
            const unsigned dw = __builtin_amdgcn_perm(v1d[jj >> 1], v0d[jj >> 1], sel); \
            *(unsigned*)&Vt[buf][SW(jj, (vcg * 8 + jj) * 64 + vslot)] = dw;     \
        }                                                                       \
    }

    // pointer-increment staging (advance 64*D_ = 4096 shorts per tile)
    const short* kpn = (const short*)kg + base + (size_t)srr * D_ + sc0;
    const short* vpn = (const short*)vg + base + (size_t)kv0 * D_ + vcg * 8;

    kreg0 = *(const bf16x8*)kpn;
    kreg1 = *(const bf16x8*)(kpn + 8);
    vreg0 = *(const bf16x8*)vpn;
    vreg1 = *(const bf16x8*)(vpn + D_);
    kpn += 4096; vpn += 4096;

    *(bf16x8*)&Ks[0][kst0] = kreg0;
    *(bf16x8*)&Ks[0][kst1] = kreg1;
    VPACK(0)

    if (qt >= 1) {
        kreg0 = *(const bf16x8*)kpn;
        kreg1 = *(const bf16x8*)(kpn + 8);
        vreg0 = *(const bf16x8*)vpn;
        vreg1 = *(const bf16x8*)(vpn + D_);
        kpn += 4096; vpn += 4096;
    }
    __syncthreads();

    for (int kt = 0; kt <= qt; ++kt) {
        const int cur = kt & 1;

        if (kt < qt) {
            *(bf16x8*)&Ks[cur ^ 1][kst0] = kreg0;
            *(bf16x8*)&Ks[cur ^ 1][kst1] = kreg1;
            VPACK(cur ^ 1)
        }
        if (kt + 2 <= qt) {
            kreg0 = *(const bf16x8*)kpn;
            kreg1 = *(const bf16x8*)(kpn + 8);
            vreg0 = *(const bf16x8*)vpn;
            vreg1 = *(const bf16x8*)(vpn + D_);
            kpn += 4096; vpn += 4096;
        }

        f32x4 s[4];
        __builtin_amdgcn_s_setprio(1);
#pragma unroll
        for (int cb = 0; cb < 4; cb++) {
            const int row = cb * 16 + lr;
            bf16x8 kf0 = *(const bf16x8*)&Ks[cur][(row * 64 + lg * 8) ^ rsw];
            bf16x8 kf1 = *(const bf16x8*)&Ks[cur][(row * 64 + 32 + lg * 8) ^ rsw];
            f32x4 acc = (f32x4){0.f, 0.f, 0.f, 0.f};
            acc = __builtin_amdgcn_mfma_f32_16x16x32_bf16(kf0, qf0, acc, 0, 0, 0);
            acc = __builtin_amdgcn_mfma_f32_16x16x32_bf16(kf1, qf1, acc, 0, 0, 0);
            s[cb] = acc;
        }
        __builtin_amdgcn_s_setprio(0);

        if (kt == qt) {
#pragma unroll
            for (int cb = 0; cb < 4; cb++)
#pragma unroll
                for (int r = 0; r < 4; r++)
                    if (kt * 64 + cb * 16 + lg * 4 + r > qrow_g) s[cb][r] = -INFINITY;
        }

        float rm;
        {
            const float t0 = fmaxf(fmaxf(s[0][0], s[0][1]), fmaxf(s[0][2], s[0][3]));
            const float t1 = fmaxf(fmaxf(s[1][0], s[1][1]), fmaxf(s[1][2], s[1][3]));
            const float t2 = fmaxf(fmaxf(s[2][0], s[2][1]), fmaxf(s[2][2], s[2][3]));
            const float t3 = fmaxf(fmaxf(s[3][0], s[3][1]), fmaxf(s[3][2], s[3][3]));
            rm = fmaxf(fmaxf(t0, t1), fmaxf(t2, t3));
        }
        rm = fmaxf(rm, __shfl_xor(rm, 16));
        rm = fmaxf(rm, __shfl_xor(rm, 32));

        if (!__all(rm <= m_run + 8.0f)) {
            const float mnew = fmaxf(m_run, rm);
            const float fsc  = exp2f(m_run - mnew);
            m_run = mnew;
            l_run *= fsc;
            float fr[4];
#pragma unroll
            for (int r = 0; r < 4; r++) fr[r] = __shfl(fsc, lg * 4 + r);
#pragma unroll
            for (int db = 0; db < 4; db++)
#pragma unroll
                for (int r = 0; r < 4; r++) oacc[db][r] *= fr[r];
        }

        float p[4][4];
#pragma unroll
        for (int cb = 0; cb < 4; cb++)
#pragma unroll
            for (int r = 0; r < 4; r++)
                p[cb][r] = exp2f(s[cb][r] - m_run);
        float rs;
        {
            const float t0 = (p[0][0] + p[0][1]) + (p[0][2] + p[0][3]);
            const float t1 = (p[1][0] + p[1][1]) + (p[1][2] + p[1][3]);
            const float t2 = (p[2][0] + p[2][1]) + (p[2][2] + p[2][3]);
            const float t3 = (p[3][0] + p[3][1]) + (p[3][2] + p[3][3]);
            rs = (t0 + t1) + (t2 + t3);
        }
        rs += __shfl_xor(rs, 16);
        rs += __shfl_xor(rs, 32);
        l_run += rs;

        bf16x8 pf0, pf1;
#pragma unroll
        for (int r = 0; r < 4; r++) {
            pf0[r]     = (short)f2b(p[0][r]);
            pf0[4 + r] = (short)f2b(p[1][r]);
            pf1[r]     = (short)f2b(p[2][r]);
            pf1[4 + r] = (short)f2b(p[3][r]);
        }

        __builtin_amdgcn_s_setprio(1);
#pragma unroll
        for (int db = 0; db < 4; db++) {
            const int row = db * 16 + lr;
            bf16x8 vf0 = *(const bf16x8*)&Vt[cur][(row * 64 + lg * 8) ^ rsw];
            bf16x8 vf1 = *(const bf16x8*)&Vt[cur][(row * 64 + 32 + lg * 8) ^ rsw];
            oacc[db] = __builtin_amdgcn_mfma_f32_16x16x32_bf16(pf0, vf0, oacc[db], 0, 0, 0);
            oacc[db] = __builtin_amdgcn_mfma_f32_16x16x32_bf16(pf1, vf1, oacc[db], 0, 0, 0);
        }
        __builtin_amdgcn_s_setprio(0);

        __syncthreads();
    }
#undef VPACK

#pragma unroll
    for (int r = 0; r < 4; r++) {
        const float lrow = __shfl(l_run, lg * 4 + r);
        const float inv = 1.0f / lrow;
        const int trow = qt * 64 + wave * 16 + lg * 4 + r;
        unsigned short* yp = y + (size_t)(b * T_ + trow) * C_ + h * D_;
#pragma unroll
        for (int db = 0; db < 4; db++)
            yp[db * 16 + lr] = f2b(oacc[db][r] * inv);
    }
}

// ---------------------------------------------------------------------------
extern "C" void kernel_launch(void* const* d_in, const int* in_sizes, int n_in,
                              void* d_out, int out_size, void* d_ws, size_t ws_size,
                              hipStream_t stream)
{
    const float* x       = (const float*)d_in[0];
    const float* Wqkv    = (const float*)d_in[1];
    const float* bqkv    = (const float*)d_in[2];
    const float* Wproj   = (const float*)d_in[3];
    const float* bproj   = (const float*)d_in[4];
    const float* Wrouter = (const float*)d_in[5];
    const float* brouter = (const float*)d_in[6];
    const float* Wq_rt   = (const float*)d_in[7];
    const float* bq_rt   = (const float*)d_in[8];

    float* out = (float*)d_out;
    char*  ws  = (char*)d_ws;

    const size_t MT  = (size_t)B_ * T_;
    const size_t QKV = MT * C_;

    unsigned short* xb   = (unsigned short*)ws;
    unsigned short* Wqt  = xb  + QKV;
    unsigned short* Wpt  = Wqt + (size_t)3 * C_ * C_;
    unsigned short* q    = Wpt + (size_t)C_ * C_;
    unsigned short* k    = q + QKV;
    unsigned short* v    = k + QKV;
    unsigned short* yab  = v + QKV;
    float* cm   = (float*)(yab + QKV);
    float* qrt  = cm  + (size_t)B_ * NCH * C_;
    float* ren  = qrt + MT * RD;

    float* y_out   = out;
    float* idx_out = out + QKV;
    float* sc_out  = idx_out + MT * TOPB;
    float* emb_out = sc_out + MT * NCH;

    // 1) fused preprocessing
    prep_fused<<<4352, 256, 0, stream>>>(x, xb, Wqkv, Wqt, Wproj, Wpt,
                                         Wq_rt, bq_rt, qrt, cm);

    // 2) qkv projection (256^2 tri-buffered, Q pre-scaled)
    gemm_qkv_256<<<dim3(192), 512, 0, stream>>>(
        xb, Wqt, bqkv, q, k, v, (int)MT, 3 * C_, C_);

    // 3) routing embeds and top-k
    embeds_kernel<<<8, 256, 0, stream>>>(cm, Wrouter, brouter, emb_out, ren);
    scores_topk<<<(int)(MT / 64), 64, 0, stream>>>(qrt, ren, sc_out, idx_out);

    // 4) MFMA flash attention (5 blocks/CU) -> bf16 ya [B,T,C]
    attn_mfma<<<dim3(1024), 256, 0, stream>>>(q, k, v, yab);

    // 5) output projection (tri-buffered counted-vmcnt)
    gemm_proj_128<<<dim3(C_ / 128, MT / 128), 256, 0, stream>>>(
        yab, Wpt, bproj, y_out, (int)MT, C_, C_);
}

// Round 14
// 178.792 us; speedup vs baseline: 1.4938x; 1.0112x over previous
//
#include <hip/hip_runtime.h>
#include <hip/hip_bf16.h>
#include <math.h>

#define B_   2
#define T_   2048
#define C_   1024
#define H_   16
#define D_   64
#define NCH  32
#define RD   32
#define TOPB 8

typedef __attribute__((ext_vector_type(8))) short bf16x8;
typedef __attribute__((ext_vector_type(4))) float f32x4;

static __device__ __forceinline__ unsigned short f2b(float f) {
    return __bfloat16_as_ushort(__float2bfloat16(f));
}

#define SCALE2 0.18033688f   /* 0.125 * 1.44269504 (log2 domain) */

// ---------------------------------------------------------------------------
// prep_fused: all input-only preprocessing in ONE kernel (role by block range)
// ---------------------------------------------------------------------------
__global__ __launch_bounds__(256) void prep_fused(
    const float* __restrict__ x, unsigned short* __restrict__ xb,
    const float* __restrict__ Wqkv, unsigned short* __restrict__ Wqt,
    const float* __restrict__ Wproj, unsigned short* __restrict__ Wpt,
    const float* __restrict__ Wq_rt, const float* __restrict__ bq_rt,
    float* __restrict__ qrt, float* __restrict__ cm)
{
    __shared__ float smem[64 * 65];
    const int bid = blockIdx.x;
    const int tid = threadIdx.x;

    if (bid < 2048) {                      // ---- cast x -> bf16
        const int i = bid * 256 + tid;
        float4 a = ((const float4*)x)[i * 2];
        float4 b = ((const float4*)x)[i * 2 + 1];
        bf16x8 o;
        o[0] = (short)f2b(a.x); o[1] = (short)f2b(a.y);
        o[2] = (short)f2b(a.z); o[3] = (short)f2b(a.w);
        o[4] = (short)f2b(b.x); o[5] = (short)f2b(b.y);
        o[6] = (short)f2b(b.z); o[7] = (short)f2b(b.w);
        *(bf16x8*)&xb[(size_t)i * 8] = o;
    } else if (bid < 3072) {               // ---- weight transpose+cast
        const float* W; unsigned short* Wt; int N, local;
        if (bid < 2816) { W = Wqkv;  Wt = Wqt; N = 3072; local = bid - 2048; }
        else            { W = Wproj; Wt = Wpt; N = 1024; local = bid - 2816; }
        const int nblk = N >> 6;
        const int n0 = (local % nblk) * 64, k0 = (local / nblk) * 64;
        float (*t)[65] = (float(*)[65])smem;
#pragma unroll
        for (int i = 0; i < 4; i++) {
            const int f = tid + i * 256;
            const int r = f >> 4, c4 = (f & 15) * 4;
            float4 v = *(const float4*)&W[(size_t)(k0 + r) * N + n0 + c4];
            t[r][c4 + 0] = v.x; t[r][c4 + 1] = v.y;
            t[r][c4 + 2] = v.z; t[r][c4 + 3] = v.w;
        }
        __syncthreads();
#pragma unroll
        for (int i = 0; i < 2; i++) {
            const int s = tid + i * 256;
            const int rn = s >> 3, ck8 = (s & 7) * 8;
            bf16x8 o;
#pragma unroll
            for (int j = 0; j < 8; j++) o[j] = (short)f2b(t[ck8 + j][rn]);
            *(bf16x8*)&Wt[(size_t)(n0 + rn) * 1024 + k0 + ck8] = o;
        }
    } else if (bid < 4096) {               // ---- qrt projection + l2norm
        float (*part)[4][32] = (float(*)[4][32])smem;
        const int r0 = (bid - 3072) * 4;
        const int g = tid >> 5;
        const int n = tid & 31;
        const float* w  = Wq_rt + (size_t)(g * 128) * RD + n;
        const float* a0 = x + (size_t)(r0 + 0) * C_ + g * 128;
        const float* a1 = x + (size_t)(r0 + 1) * C_ + g * 128;
        const float* a2 = x + (size_t)(r0 + 2) * C_ + g * 128;
        const float* a3 = x + (size_t)(r0 + 3) * C_ + g * 128;
        float acc0 = 0.f, acc1 = 0.f, acc2 = 0.f, acc3 = 0.f;
#pragma unroll 8
        for (int i = 0; i < 128; i += 4) {
            const float w0 = w[(i + 0) * RD];
            const float w1 = w[(i + 1) * RD];
            const float w2 = w[(i + 2) * RD];
            const float w3 = w[(i + 3) * RD];
            float4 x0 = *(const float4*)&a0[i];
            float4 x1 = *(const float4*)&a1[i];
            float4 x2 = *(const float4*)&a2[i];
            float4 x3 = *(const float4*)&a3[i];
            acc0 += x0.x * w0; acc0 += x0.y * w1; acc0 += x0.z * w2; acc0 += x0.w * w3;
            acc1 += x1.x * w0; acc1 += x1.y * w1; acc1 += x1.z * w2; acc1 += x1.w * w3;
            acc2 += x2.x * w0; acc2 += x2.y * w1; acc2 += x2.z * w2; acc2 += x2.w * w3;
            acc3 += x3.x * w0; acc3 += x3.y * w1; acc3 += x3.z * w2; acc3 += x3.w * w3;
        }
        part[g][0][n] = acc0;
        part[g][1][n] = acc1;
        part[g][2][n] = acc2;
        part[g][3][n] = acc3;
        __syncthreads();
        if (g < 4) {
            float s = part[0][g][n];
#pragma unroll
            for (int gg = 1; gg < 8; gg++) s += part[gg][g][n];
            s += bq_rt[n];
            float ss = s * s;
#pragma unroll
            for (int off = 16; off >= 1; off >>= 1) ss += __shfl_xor(ss, off, 32);
            qrt[(size_t)(r0 + g) * RD + n] = s / fmaxf(sqrtf(ss), 1e-12f);
        }
    } else {                               // ---- chunk means
        const int local = bid - 4096;
        const int bc = local & 63;
        const int b = bc >> 5, n = bc & 31;
        const int c = (local >> 6) * 256 + tid;
        const float* xp = x + ((size_t)b * T_ + n * 64) * C_;
        float s = 0.f;
        for (int i = 0; i < 64; i++) s += xp[(size_t)i * C_ + c];
        cm[(size_t)bc * C_ + c] = s * (1.0f / 64.0f);
    }
}

// ---------------------------------------------------------------------------
// routing embeds + l2norm fused
// ---------------------------------------------------------------------------
__global__ void embeds_kernel(const float* __restrict__ cm, const float* __restrict__ W,
                              const float* __restrict__ bias,
                              float* __restrict__ emb_out, float* __restrict__ ren)
{
    const int row  = blockIdx.x * 8 + (threadIdx.x >> 5);
    const int lane = threadIdx.x & 31;
    if (row >= B_ * NCH) return;
    const float* a = cm + (size_t)row * C_;
    float acc = 0.f;
    for (int k = 0; k < C_; k += 4) {
        float4 a4 = *(const float4*)&a[k];
        acc += a4.x * W[(k + 0) * RD + lane];
        acc += a4.y * W[(k + 1) * RD + lane];
        acc += a4.z * W[(k + 2) * RD + lane];
        acc += a4.w * W[(k + 3) * RD + lane];
    }
    acc += bias[lane];
    emb_out[(size_t)row * RD + lane] = acc;
    float ss = acc * acc;
#pragma unroll
    for (int off = 16; off >= 1; off >>= 1) ss += __shfl_xor(ss, off, 32);
    ren[(size_t)row * RD + lane] = acc / fmaxf(sqrtf(ss), 1e-12f);
}

// ---------------------------------------------------------------------------
// qkv GEMM, 128x256 tile, 8 waves (2m x 4n), tri-buffered + counted vmcnt.
// 384 blocks (all 256 CUs busy, 2 blocks/CU at 72 KB LDS = 4 waves/SIMD).
// LDS layout per slot: A [128][32] at 0, B [256][32] at 4096 (shorts).
// 3 global_load_lds per tile -> boundary waits vmcnt(3).
// Q output pre-scaled by SCALE2.
// ---------------------------------------------------------------------------
__global__ __launch_bounds__(512, 4) void gemm_qkv_128x256(
    const unsigned short* __restrict__ A, const unsigned short* __restrict__ Bt,
    const float* __restrict__ bias,
    unsigned short* __restrict__ qp, unsigned short* __restrict__ kp,
    unsigned short* __restrict__ vp, int M, int N, int K)
{
    __shared__ unsigned short lds[3][12288];   // A 4096 + B 8192 shorts

    const int tid  = threadIdx.x;
    const int wid  = tid >> 6;
    const int lane = tid & 63;
    const int lr = lane & 15, lg = lane >> 4;
    const int wm = wid >> 2;      // 0..1  (64-row slice of 128)
    const int wn = wid & 3;       // 0..3  (64-col slice of 256)

    // bijective XCD swizzle over 384 blocks (384 % 8 == 0), n-major
    const int bid = blockIdx.x;
    const int swz = (bid & 7) * 48 + (bid >> 3);
    const int m0 = (swz & 31) << 7;       // 32 m-tiles of 128
    const int n0 = (swz >> 5) << 8;       // 12 n-tiles of 256

    // staging: A rows 0..127 (1 instr), B rows 0..255 (2 instrs)
    const int srow = tid >> 2;            // 0..127
    const int sswz = (((srow & 3) ^ ((srow >> 2) & 3)) << 4);
    const int skel = (((tid & 3) << 4) ^ sswz) >> 1;
    const unsigned short* gA  = A  + (size_t)(m0 + srow) * K + skel;
    const unsigned short* gB0 = Bt + (size_t)(n0 + srow) * K + skel;
    const unsigned short* gB1 = Bt + (size_t)(n0 + srow + 128) * K + skel;
    const int lb = wid * 512;             // wave-uniform LDS base (shorts)

#define QSTAGE(sl, kofs)                                                          \
    __builtin_amdgcn_global_load_lds(                                             \
        (const __attribute__((address_space(1))) int*)(gA + (kofs)),              \
        (__attribute__((address_space(3))) int*)&lds[sl][lb], 16, 0, 0);          \
    __builtin_amdgcn_global_load_lds(                                             \
        (const __attribute__((address_space(1))) int*)(gB0 + (kofs)),             \
        (__attribute__((address_space(3))) int*)&lds[sl][4096 + lb], 16, 0, 0);   \
    __builtin_amdgcn_global_load_lds(                                             \
        (const __attribute__((address_space(1))) int*)(gB1 + (kofs)),             \
        (__attribute__((address_space(3))) int*)&lds[sl][8192 + lb], 16, 0, 0);

    const int rswz = (((lr & 3) ^ ((lr >> 2) & 3)) << 4);
    const int acol = (((lg << 4) ^ rswz) >> 1);

    f32x4 acc[4][4];
#pragma unroll
    for (int i = 0; i < 4; i++)
#pragma unroll
        for (int j = 0; j < 4; j++) acc[i][j] = (f32x4){0.f, 0.f, 0.f, 0.f};

    const int nt = K >> 5;   // 32

    QSTAGE(0, 0)
    QSTAGE(1, 32)
    asm volatile("s_waitcnt vmcnt(3)" ::: "memory");
    __builtin_amdgcn_s_barrier();

    int cur = 0;
    for (int t = 0; t < nt; ++t) {
        int s2 = cur + 2; if (s2 >= 3) s2 -= 3;
        if (t + 2 < nt) { QSTAGE(s2, (t + 2) << 5) }

        const unsigned short* sA = &lds[cur][0];
        const unsigned short* sB = &lds[cur][4096];

        bf16x8 af[4], bfr[4];
#pragma unroll
        for (int mi = 0; mi < 4; mi++)
            af[mi] = *(const bf16x8*)&sA[(wm * 64 + mi * 16 + lr) * 32 + acol];
#pragma unroll
        for (int ni = 0; ni < 4; ni++)
            bfr[ni] = *(const bf16x8*)&sB[(wn * 64 + ni * 16 + lr) * 32 + acol];

        __builtin_amdgcn_s_setprio(1);
#pragma unroll
        for (int mi = 0; mi < 4; mi++)
#pragma unroll
            for (int ni = 0; ni < 4; ni++)
                acc[mi][ni] = __builtin_amdgcn_mfma_f32_16x16x32_bf16(
                    af[mi], bfr[ni], acc[mi][ni], 0, 0, 0);
        __builtin_amdgcn_s_setprio(0);

        if (t + 1 < nt) {
            if (t + 2 < nt) { asm volatile("s_waitcnt vmcnt(3)" ::: "memory"); }
            else            { asm volatile("s_waitcnt vmcnt(0)" ::: "memory"); }
            __builtin_amdgcn_s_barrier();
        }
        cur += 1; if (cur == 3) cur = 0;
    }
#undef QSTAGE

    // epilogue: scatter to q/k/v [B,H,T,D], pre-scale Q
#pragma unroll
    for (int ni = 0; ni < 4; ni++) {
        const int col = n0 + wn * 64 + ni * 16 + lr;
        const float bv = bias[col];
        const int which = col >> 10;
        const int c  = col & 1023;
        const int hh = c >> 6;
        const int dd = c & 63;
        unsigned short* dst = (which == 0) ? qp : (which == 1) ? kp : vp;
        const float postmul = (which == 0) ? SCALE2 : 1.0f;
#pragma unroll
        for (int mi = 0; mi < 4; mi++) {
#pragma unroll
            for (int r = 0; r < 4; r++) {
                const int row = m0 + wm * 64 + mi * 16 + lg * 4 + r;
                const int bb = row >> 11, tt = row & 2047;
                dst[(((size_t)bb * H_ + hh) * T_ + tt) * D_ + dd] =
                    f2b((acc[mi][ni][r] + bv) * postmul);
            }
        }
    }
}

// ---------------------------------------------------------------------------
// proj GEMM, 128x128 tile, tri-buffered + counted vmcnt + swizzle (R12 proven)
// ---------------------------------------------------------------------------
__global__ __launch_bounds__(256, 1) void gemm_proj_128(
    const unsigned short* __restrict__ A, const unsigned short* __restrict__ Bt,
    const float* __restrict__ bias, float* __restrict__ out, int M, int N, int K)
{
    __shared__ unsigned short lds[3][2][4096];

    const int tid  = threadIdx.x;
    const int lane = tid & 63;
    const int wave = tid >> 6;
    const int lr = lane & 15, lg = lane >> 4;
    const int wm = wave >> 1, wn = wave & 1;
    const int n0 = blockIdx.x * 128, m0 = blockIdx.y * 128;

    const int srow = tid >> 2;
    const int sswz = (((srow & 3) ^ ((srow >> 2) & 3)) << 4);
    const int skel = (((tid & 3) << 4) ^ sswz) >> 1;
    const unsigned short* gA0 = A  + (size_t)(m0 + srow) * K + skel;
    const unsigned short* gA1 = A  + (size_t)(m0 + srow + 64) * K + skel;
    const unsigned short* gB0 = Bt + (size_t)(n0 + srow) * K + skel;
    const unsigned short* gB1 = Bt + (size_t)(n0 + srow + 64) * K + skel;
    const int ldb = (tid & 0xC0) * 8;

#define PSTAGE(sl, kofs)                                                          \
    __builtin_amdgcn_global_load_lds(                                             \
        (const __attribute__((address_space(1))) int*)(gA0 + (kofs)),             \
        (__attribute__((address_space(3))) int*)&lds[sl][0][ldb], 16, 0, 0);      \
    __builtin_amdgcn_global_load_lds(                                             \
        (const __attribute__((address_space(1))) int*)(gA1 + (kofs)),             \
        (__attribute__((address_space(3))) int*)&lds[sl][0][2048 + ldb], 16, 0, 0); \
    __builtin_amdgcn_global_load_lds(                                             \
        (const __attribute__((address_space(1))) int*)(gB0 + (kofs)),             \
        (__attribute__((address_space(3))) int*)&lds[sl][1][ldb], 16, 0, 0);      \
    __builtin_amdgcn_global_load_lds(                                             \
        (const __attribute__((address_space(1))) int*)(gB1 + (kofs)),             \
        (__attribute__((address_space(3))) int*)&lds[sl][1][2048 + ldb], 16, 0, 0);

    const int rswz = (((lr & 3) ^ ((lr >> 2) & 3)) << 4);
    const int acol = (((lg << 4) ^ rswz) >> 1);

    f32x4 acc[4][4];
#pragma unroll
    for (int i = 0; i < 4; i++)
#pragma unroll
        for (int j = 0; j < 4; j++) acc[i][j] = (f32x4){0.f, 0.f, 0.f, 0.f};

    const int nt = K >> 5;

    PSTAGE(0, 0)
    PSTAGE(1, 32)
    asm volatile("s_waitcnt vmcnt(4)" ::: "memory");
    __builtin_amdgcn_s_barrier();

    int cur = 0;
    for (int t = 0; t < nt; ++t) {
        int s2 = cur + 2; if (s2 >= 3) s2 -= 3;
        if (t + 2 < nt) { PSTAGE(s2, (t + 2) << 5) }

        const unsigned short* sA = &lds[cur][0][0];
        const unsigned short* sB = &lds[cur][1][0];

        bf16x8 af[4], bfr[4];
#pragma unroll
        for (int mi = 0; mi < 4; mi++)
            af[mi] = *(const bf16x8*)&sA[(wm * 64 + mi * 16 + lr) * 32 + acol];
#pragma unroll
        for (int ni = 0; ni < 4; ni++)
            bfr[ni] = *(const bf16x8*)&sB[(wn * 64 + ni * 16 + lr) * 32 + acol];

        __builtin_amdgcn_s_setprio(1);
#pragma unroll
        for (int mi = 0; mi < 4; mi++)
#pragma unroll
            for (int ni = 0; ni < 4; ni++)
                acc[mi][ni] = __builtin_amdgcn_mfma_f32_16x16x32_bf16(
                    af[mi], bfr[ni], acc[mi][ni], 0, 0, 0);
        __builtin_amdgcn_s_setprio(0);

        if (t + 1 < nt) {
            if (t + 2 < nt) { asm volatile("s_waitcnt vmcnt(4)" ::: "memory"); }
            else            { asm volatile("s_waitcnt vmcnt(0)" ::: "memory"); }
            __builtin_amdgcn_s_barrier();
        }
        cur += 1; if (cur == 3) cur = 0;
    }
#undef PSTAGE

#pragma unroll
    for (int ni = 0; ni < 4; ni++) {
        const int col = n0 + wn * 64 + ni * 16 + lr;
        const float bv = bias[col];
#pragma unroll
        for (int mi = 0; mi < 4; mi++) {
#pragma unroll
            for (int r = 0; r < 4; r++) {
                const int row = m0 + wm * 64 + mi * 16 + lg * 4 + r;
                out[(size_t)row * N + col] = acc[mi][ni][r] + bv;
            }
        }
    }
}

// ---------------------------------------------------------------------------
// routing scores + top-8
// ---------------------------------------------------------------------------
__global__ void scores_topk(const float* __restrict__ qrt, const float* __restrict__ ren,
                            float* __restrict__ sc_out, float* __restrict__ idx_out)
{
    const int row = blockIdx.x * 64 + threadIdx.x;
    if (row >= B_ * T_) return;
    const int b = row / T_;
    float q[RD];
#pragma unroll
    for (int i = 0; i < RD; i++) q[i] = qrt[(size_t)row * RD + i];
    const float* rb = ren + (size_t)b * NCH * RD;
    float s[NCH];
#pragma unroll 4
    for (int n = 0; n < NCH; n++) {
        float acc = 0.f;
#pragma unroll
        for (int i = 0; i < RD; i++) acc += q[i] * rb[n * RD + i];
        s[n] = acc;
        sc_out[(size_t)row * NCH + n] = acc;
    }
    unsigned mask = 0;
    for (int t = 0; t < TOPB; t++) {
        float best = -INFINITY;
        int bi = 0;
#pragma unroll
        for (int n = 0; n < NCH; n++) {
            const bool ok = !((mask >> n) & 1u) && (s[n] > best);
            if (ok) { best = s[n]; bi = n; }
        }
        mask |= (1u << bi);
        idx_out[(size_t)row * TOPB + t] = (float)bi;
    }
}

// ---------------------------------------------------------------------------
// MFMA bf16 flash attention v8 (frozen from R13)
// ---------------------------------------------------------------------------
#define SW(row, idx) ((idx) ^ (((row) & 7) << 3))

__global__ __launch_bounds__(256) void attn_mfma(
    const unsigned short* __restrict__ qg, const unsigned short* __restrict__ kg,
    const unsigned short* __restrict__ vg, unsigned short* __restrict__ y)
{
    const int bid = blockIdx.x;
    const int xcd = bid & 7;
    const int h   = xcd + 8 * ((bid >> 3) & 1);
    const int b   = (bid >> 4) & 1;
    const int i   = bid >> 5;
    const int qt  = (i & 8) ? ((i & 16) ? (i - 24) : (i + 8)) : (31 - i);

    const int tid  = threadIdx.x;
    const int wave = tid >> 6;
    const int lane = tid & 63;
    const int lg = lane >> 4;
    const int lr = lane & 15;

    __shared__ short Ks[2][64 * 64];
    __shared__ short Vt[2][64 * 64];

    const size_t base = ((size_t)(b * H_ + h) * T_) * D_;

    bf16x8 qf0, qf1;
    {
        const short* qp = (const short*)qg + base + (size_t)(qt * 64 + wave * 16 + lr) * D_;
        qf0 = *(const bf16x8*)&qp[lg * 8];
        qf1 = *(const bf16x8*)&qp[32 + lg * 8];
    }

    const int srr = tid >> 2;
    const int sc0 = (tid & 3) * 16;
    const int vrp = tid & 31;
    const int vcg = tid >> 5;
    const int kv0   = 2 * vrp;
    const int vslot = ((kv0 >> 5) << 5) + (((kv0 >> 2) & 3) << 3) +
                      (((kv0 >> 4) & 1) << 2) + (kv0 & 3);

    const int kst0 = SW(srr, srr * 64 + sc0);
    const int kst1 = SW(srr, srr * 64 + sc0 + 8);
    const int rsw = (lr & 7) << 3;

    bf16x8 kreg0, kreg1, vreg0, vreg1;

    float m_run = -INFINITY, l_run = 0.f;
    f32x4 oacc[4];
#pragma unroll
    for (int r = 0; r < 4; r++) oacc[r] = (f32x4){0.f, 0.f, 0.f, 0.f};
    const int qrow_g = qt * 64 + wave * 16 + lr;

#define VPACK(buf)                                                              \
    {                                                                           \
        const unsigned* v0d = (const unsigned*)&vreg0;                          \
        const unsigned* v1d = (const unsigned*)&vreg1;                          \
        _Pragma("unroll")                                                       \
        for (int jj = 0; jj < 8; jj++) {                                        \
            const unsigned sel = (jj & 1) ? 0x07060302u : 0x05040100u;          \
            const unsigned dw = __builtin_amdgcn_perm(v1d[jj >> 1], v0d[jj >> 1], sel); \
            *(unsigned*)&Vt[buf][SW(jj, (vcg * 8 + jj) * 64 + vslot)] = dw;     \
        }                                                                       \
    }

    const short* kpn = (const short*)kg + base + (size_t)srr * D_ + sc0;
    const short* vpn = (const short*)vg + base + (size_t)kv0 * D_ + vcg * 8;

    kreg0 = *(const bf16x8*)kpn;
    kreg1 = *(const bf16x8*)(kpn + 8);
    vreg0 = *(const bf16x8*)vpn;
    vreg1 = *(const bf16x8*)(vpn + D_);
    kpn += 4096; vpn += 4096;

    *(bf16x8*)&Ks[0][kst0] = kreg0;
    *(bf16x8*)&Ks[0][kst1] = kreg1;
    VPACK(0)

    if (qt >= 1) {
        kreg0 = *(const bf16x8*)kpn;
        kreg1 = *(const bf16x8*)(kpn + 8);
        vreg0 = *(const bf16x8*)vpn;
        vreg1 = *(const bf16x8*)(vpn + D_);
        kpn += 4096; vpn += 4096;
    }
    __syncthreads();

    for (int kt = 0; kt <= qt; ++kt) {
        const int cur = kt & 1;

        if (kt < qt) {
            *(bf16x8*)&Ks[cur ^ 1][kst0] = kreg0;
            *(bf16x8*)&Ks[cur ^ 1][kst1] = kreg1;
            VPACK(cur ^ 1)
        }
        if (kt + 2 <= qt) {
            kreg0 = *(const bf16x8*)kpn;
            kreg1 = *(const bf16x8*)(kpn + 8);
            vreg0 = *(const bf16x8*)vpn;
            vreg1 = *(const bf16x8*)(vpn + D_);
            kpn += 4096; vpn += 4096;
        }

        f32x4 s[4];
        __builtin_amdgcn_s_setprio(1);
#pragma unroll
        for (int cb = 0; cb < 4; cb++) {
            const int row = cb * 16 + lr;
            bf16x8 kf0 = *(const bf16x8*)&Ks[cur][(row * 64 + lg * 8) ^ rsw];
            bf16x8 kf1 = *(const bf16x8*)&Ks[cur][(row * 64 + 32 + lg * 8) ^ rsw];
            f32x4 acc = (f32x4){0.f, 0.f, 0.f, 0.f};
            acc = __builtin_amdgcn_mfma_f32_16x16x32_bf16(kf0, qf0, acc, 0, 0, 0);
            acc = __builtin_amdgcn_mfma_f32_16x16x32_bf16(kf1, qf1, acc, 0, 0, 0);
            s[cb] = acc;
        }
        __builtin_amdgcn_s_setprio(0);

        if (kt == qt) {
#pragma unroll
            for (int cb = 0; cb < 4; cb++)
#pragma unroll
                for (int r = 0; r < 4; r++)
                    if (kt * 64 + cb * 16 + lg * 4 + r > qrow_g) s[cb][r] = -INFINITY;
        }

        float rm;
        {
            const float t0 = fmaxf(fmaxf(s[0][0], s[0][1]), fmaxf(s[0][2], s[0][3]));
            const float t1 = fmaxf(fmaxf(s[1][0], s[1][1]), fmaxf(s[1][2], s[1][3]));
            const float t2 = fmaxf(fmaxf(s[2][0], s[2][1]), fmaxf(s[2][2], s[2][3]));
            const float t3 = fmaxf(fmaxf(s[3][0], s[3][1]), fmaxf(s[3][2], s[3][3]));
            rm = fmaxf(fmaxf(t0, t1), fmaxf(t2, t3));
        }
        rm = fmaxf(rm, __shfl_xor(rm, 16));
        rm = fmaxf(rm, __shfl_xor(rm, 32));

        if (!__all(rm <= m_run + 8.0f)) {
            const float mnew = fmaxf(m_run, rm);
            const float fsc  = exp2f(m_run - mnew);
            m_run = mnew;
            l_run *= fsc;
            float fr[4];
#pragma unroll
            for (int r = 0; r < 4; r++) fr[r] = __shfl(fsc, lg * 4 + r);
#pragma unroll
            for (int db = 0; db < 4; db++)
#pragma unroll
                for (int r = 0; r < 4; r++) oacc[db][r] *= fr[r];
        }

        float p[4][4];
#pragma unroll
        for (int cb = 0; cb < 4; cb++)
#pragma unroll
            for (int r = 0; r < 4; r++)
                p[cb][r] = exp2f(s[cb][r] - m_run);
        float rs;
        {
            const float t0 = (p[0][0] + p[0][1]) + (p[0][2] + p[0][3]);
            const float t1 = (p[1][0] + p[1][1]) + (p[1][2] + p[1][3]);
            const float t2 = (p[2][0] + p[2][1]) + (p[2][2] + p[2][3]);
            const float t3 = (p[3][0] + p[3][1]) + (p[3][2] + p[3][3]);
            rs = (t0 + t1) + (t2 + t3);
        }
        rs += __shfl_xor(rs, 16);
        rs += __shfl_xor(rs, 32);
        l_run += rs;

        bf16x8 pf0, pf1;
#pragma unroll
        for (int r = 0; r < 4; r++) {
            pf0[r]     = (short)f2b(p[0][r]);
            pf0[4 + r] = (short)f2b(p[1][r]);
            pf1[r]     = (short)f2b(p[2][r]);
            pf1[4 + r] = (short)f2b(p[3][r]);
        }

        __builtin_amdgcn_s_setprio(1);
#pragma unroll
        for (int db = 0; db < 4; db++) {
            const int row = db * 16 + lr;
            bf16x8 vf0 = *(const bf16x8*)&Vt[cur][(row * 64 + lg * 8) ^ rsw];
            bf16x8 vf1 = *(const bf16x8*)&Vt[cur][(row * 64 + 32 + lg * 8) ^ rsw];
            oacc[db] = __builtin_amdgcn_mfma_f32_16x16x32_bf16(pf0, vf0, oacc[db], 0, 0, 0);
            oacc[db] = __builtin_amdgcn_mfma_f32_16x16x32_bf16(pf1, vf1, oacc[db], 0, 0, 0);
        }
        __builtin_amdgcn_s_setprio(0);

        __syncthreads();
    }
#undef VPACK

#pragma unroll
    for (int r = 0; r < 4; r++) {
        const float lrow = __shfl(l_run, lg * 4 + r);
        const float inv = 1.0f / lrow;
        const int trow = qt * 64 + wave * 16 + lg * 4 + r;
        unsigned short* yp = y + (size_t)(b * T_ + trow) * C_ + h * D_;
#pragma unroll
        for (int db = 0; db < 4; db++)
            yp[db * 16 + lr] = f2b(oacc[db][r] * inv);
    }
}

// ---------------------------------------------------------------------------
extern "C" void kernel_launch(void* const* d_in, const int* in_sizes, int n_in,
                              void* d_out, int out_size, void* d_ws, size_t ws_size,
                              hipStream_t stream)
{
    const float* x       = (const float*)d_in[0];
    const float* Wqkv    = (const float*)d_in[1];
    const float* bqkv    = (const float*)d_in[2];
    const float* Wproj   = (const float*)d_in[3];
    const float* bproj   = (const float*)d_in[4];
    const float* Wrouter = (const float*)d_in[5];
    const float* brouter = (const float*)d_in[6];
    const float* Wq_rt   = (const float*)d_in[7];
    const float* bq_rt   = (const float*)d_in[8];

    float* out = (float*)d_out;
    char*  ws  = (char*)d_ws;

    const size_t MT  = (size_t)B_ * T_;
    const size_t QKV = MT * C_;

    unsigned short* xb   = (unsigned short*)ws;
    unsigned short* Wqt  = xb  + QKV;
    unsigned short* Wpt  = Wqt + (size_t)3 * C_ * C_;
    unsigned short* q    = Wpt + (size_t)C_ * C_;
    unsigned short* k    = q + QKV;
    unsigned short* v    = k + QKV;
    unsigned short* yab  = v + QKV;
    float* cm   = (float*)(yab + QKV);
    float* qrt  = cm  + (size_t)B_ * NCH * C_;
    float* ren  = qrt + MT * RD;

    float* y_out   = out;
    float* idx_out = out + QKV;
    float* sc_out  = idx_out + MT * TOPB;
    float* emb_out = sc_out + MT * NCH;

    // 1) fused preprocessing
    prep_fused<<<4352, 256, 0, stream>>>(x, xb, Wqkv, Wqt, Wproj, Wpt,
                                         Wq_rt, bq_rt, qrt, cm);

    // 2) qkv projection: 128x256, 2 blocks/CU, all CUs busy
    gemm_qkv_128x256<<<dim3(384), 512, 0, stream>>>(
        xb, Wqt, bqkv, q, k, v, (int)MT, 3 * C_, C_);

    // 3) routing embeds and top-k
    embeds_kernel<<<8, 256, 0, stream>>>(cm, Wrouter, brouter, emb_out, ren);
    scores_topk<<<(int)(MT / 64), 64, 0, stream>>>(qrt, ren, sc_out, idx_out);

    // 4) MFMA flash attention -> bf16 ya [B,T,C]
    attn_mfma<<<dim3(1024), 256, 0, stream>>>(q, k, v, yab);

    // 5) output projection (tri-buffered counted-vmcnt)
    gemm_proj_128<<<dim3(C_ / 128, MT / 128), 256, 0, stream>>>(
        yab, Wpt, bproj, y_out, (int)MT, C_, C_);
}